// Round 1
// baseline (714.964 us; speedup 1.0000x reference)
//
#include <hip/hip_runtime.h>
#include <hip/hip_bf16.h>
#include <math.h>

// Problem constants
#define B_  4
#define S_  1024
#define D_  512
#define H_  8
#define HD_ 64
#define M_  2
#define EPS_ 1e-5f

// GEMM tiling
#define BM 64
#define BN 64
#define BK 32
#define LDT 68   // padded LDS leading dim (floats), 16B-aligned multiples of 4

// ---------------------------------------------------------------------------
// Kernel 1: fused projection GEMM.  Y = x @ [Wq;Wk;Wv;Wg]^T  (raw, no bias)
// x: (4096, 512) row-major.  Writes Qraw/Kraw/V (4096,512) and Graw (4096,32).
// ---------------------------------------------------------------------------
__global__ __launch_bounds__(256) void proj_gemm(
    const float* __restrict__ x,
    const float* __restrict__ Wq, const float* __restrict__ Wk,
    const float* __restrict__ Wv, const float* __restrict__ Wg,
    float* __restrict__ Qraw, float* __restrict__ Kraw,
    float* __restrict__ Vws,  float* __restrict__ Graw)
{
    __shared__ float As[BK][LDT];   // [k][m]
    __shared__ float Bs[BK][LDT];   // [k][n]
    const int tid = threadIdx.x;
    const int nt = blockIdx.x;      // 0..24
    const int mt = blockIdx.y;      // 0..63
    const int nbase = nt * BN;

    const float* W; float* dst; int dcols, nloc, nrow_lim;
    if (nbase < 512)       { W = Wq; dst = Qraw; dcols = 512; nloc = nbase;        nrow_lim = 512; }
    else if (nbase < 1024) { W = Wk; dst = Kraw; dcols = 512; nloc = nbase - 512;  nrow_lim = 512; }
    else if (nbase < 1536) { W = Wv; dst = Vws;  dcols = 512; nloc = nbase - 1024; nrow_lim = 512; }
    else                   { W = Wg; dst = Graw; dcols = 32;  nloc = 0;            nrow_lim = 32;  }

    const int m0 = mt * BM;
    const int tx = tid & 15, ty = tid >> 4;
    float acc[4][4] = {};

    for (int kt = 0; kt < 512; kt += BK) {
        #pragma unroll
        for (int half = 0; half < 2; ++half) {
            const int r  = (tid >> 3) + half * 32;   // 0..63
            const int c4 = (tid & 7) * 4;            // 0..28
            float4 a = *(const float4*)(x + (size_t)(m0 + r) * 512 + kt + c4);
            As[c4+0][r] = a.x; As[c4+1][r] = a.y; As[c4+2][r] = a.z; As[c4+3][r] = a.w;
            const int wr = nloc + r;
            float4 bv = make_float4(0.f, 0.f, 0.f, 0.f);
            if (wr < nrow_lim) bv = *(const float4*)(W + (size_t)wr * 512 + kt + c4);
            Bs[c4+0][r] = bv.x; Bs[c4+1][r] = bv.y; Bs[c4+2][r] = bv.z; Bs[c4+3][r] = bv.w;
        }
        __syncthreads();
        #pragma unroll
        for (int kk = 0; kk < BK; ++kk) {
            float4 a  = *(const float4*)(&As[kk][ty * 4]);
            float4 bv = *(const float4*)(&Bs[kk][tx * 4]);
            acc[0][0] = fmaf(a.x, bv.x, acc[0][0]); acc[0][1] = fmaf(a.x, bv.y, acc[0][1]);
            acc[0][2] = fmaf(a.x, bv.z, acc[0][2]); acc[0][3] = fmaf(a.x, bv.w, acc[0][3]);
            acc[1][0] = fmaf(a.y, bv.x, acc[1][0]); acc[1][1] = fmaf(a.y, bv.y, acc[1][1]);
            acc[1][2] = fmaf(a.y, bv.z, acc[1][2]); acc[1][3] = fmaf(a.y, bv.w, acc[1][3]);
            acc[2][0] = fmaf(a.z, bv.x, acc[2][0]); acc[2][1] = fmaf(a.z, bv.y, acc[2][1]);
            acc[2][2] = fmaf(a.z, bv.z, acc[2][2]); acc[2][3] = fmaf(a.z, bv.w, acc[2][3]);
            acc[3][0] = fmaf(a.w, bv.x, acc[3][0]); acc[3][1] = fmaf(a.w, bv.y, acc[3][1]);
            acc[3][2] = fmaf(a.w, bv.z, acc[3][2]); acc[3][3] = fmaf(a.w, bv.w, acc[3][3]);
        }
        __syncthreads();
    }

    const int col = nloc + tx * 4;
    if (col < nrow_lim) {
        #pragma unroll
        for (int mi = 0; mi < 4; ++mi) {
            const int row = m0 + ty * 4 + mi;
            float4 o = make_float4(acc[mi][0], acc[mi][1], acc[mi][2], acc[mi][3]);
            *(float4*)(dst + (size_t)row * dcols + col) = o;
        }
    }
}

// ---------------------------------------------------------------------------
// Kernel 2: RoPE (in-place on Qraw/Kraw) + gate scalars.
// One thread per (b,s,h,i), i = pair index 0..31.
// scal layout: ((b*H+h)*S + t)*8 + {ret0,ret1,ww0,ww1,wm0,wm1,0,0}
// ---------------------------------------------------------------------------
__global__ __launch_bounds__(256) void postproc(
    float* __restrict__ Qraw, float* __restrict__ Kraw,
    const float* __restrict__ Graw, const float* __restrict__ bg,
    const float* __restrict__ logit_alphas, float* __restrict__ scal)
{
    const int g = blockIdx.x * 256 + threadIdx.x;     // 0 .. 1048575
    const int i   = g & 31;
    const int bsh = g >> 5;        // (b*S+s)*H + h
    const int h   = bsh & 7;
    const int bs  = bsh >> 3;      // b*S + s
    const int s   = bs & (S_ - 1);

    // inv_freq = 10000^(-i/32) = 2^(-i/32 * log2(10000))
    const float inv = exp2f(-(float)i * (13.287712379549449f / 32.0f));
    const float fr = (float)s * inv;
    float sn, cs;
    sincosf(fr, &sn, &cs);

    float2* qp = (float2*)Qraw + (size_t)bsh * 32 + i;
    float2 q = *qp;
    *qp = make_float2(q.x * cs - q.y * sn, q.x * sn + q.y * cs);
    float2* kp = (float2*)Kraw + (size_t)bsh * 32 + i;
    float2 k = *kp;
    *kp = make_float2(k.x * cs - k.y * sn, k.x * sn + k.y * cs);

    if (i == 0) {
        const float4 gv = *(const float4*)(Graw + (size_t)bs * 32 + h * 4);
        const float g0 = gv.x + bg[h * 4 + 0];
        const float g1 = gv.y + bg[h * 4 + 1];
        const float g2 = gv.z + bg[h * 4 + 2];
        const float g3 = gv.w + bg[h * 4 + 3];
        const float gf  = 1.f / (1.f + expf(-g0));
        const float gu  = 1.f / (1.f + expf(-g1));
        const float wm0 = 1.f / (1.f + expf(-(g2 - g3)));
        const float wm1 = 1.f - wm0;
        const float a0 = 1.f / (1.f + expf(-logit_alphas[h * 2 + 0]));
        const float a1 = 1.f / (1.f + expf(-logit_alphas[h * 2 + 1]));
        const int b = bs >> 10;
        float* sp = scal + ((size_t)(b * H_ + h) * S_ + s) * 8;
        sp[0] = a0 * gf; sp[1] = a1 * gf;
        sp[2] = wm0 * gu; sp[3] = wm1 * gu;
        sp[4] = wm0; sp[5] = wm1;
        sp[6] = 0.f; sp[7] = 0.f;
    }
}

// ---------------------------------------------------------------------------
// Kernel 3: the sequential scan.  One wave per (b,h,e); lane = d.
// state[m][d][e] lives in 2 registers per lane.  1024 steps.
// ---------------------------------------------------------------------------
__global__ __launch_bounds__(64) void scan_kernel(
    const float* __restrict__ Q, const float* __restrict__ K,
    const float* __restrict__ V, const float* __restrict__ scal,
    float* __restrict__ O)
{
    const int wid = blockIdx.x;            // 0..2047
    const int e = wid & 63;
    const int h = (wid >> 6) & 7;
    const int b = wid >> 9;
    const int lane = threadIdx.x;          // d

    const size_t base = ((size_t)(b * S_) * H_ + h) * HD_;
    const float* Kp = K + base + lane;
    const float* Qp = Q + base + lane;
    const float* Vp = V + base + e;
    const float* Sp = scal + (size_t)(b * H_ + h) * S_ * 8;
    float* Op = O + base + e;

    float st0 = 0.f, st1 = 0.f;
    float kd = Kp[0], qd = Qp[0], ve = Vp[0];
    float4 sA = *(const float4*)(Sp);
    float2 sB = *(const float2*)(Sp + 4);

    for (int t = 0; t < S_; ++t) {
        const int tn = (t + 1 < S_) ? t + 1 : t;
        // prefetch next step
        float  kd_n = Kp[(size_t)tn * 512];
        float  qd_n = Qp[(size_t)tn * 512];
        float  ve_n = Vp[(size_t)tn * 512];
        float4 sA_n = *(const float4*)(Sp + (size_t)tn * 8);
        float2 sB_n = *(const float2*)(Sp + (size_t)tn * 8 + 4);

        // state update: st_m = ret_m * st_m + (ww_m * v_e) * k_d
        st0 = fmaf(sA.x, st0, (sA.z * ve) * kd);
        st1 = fmaf(sA.y, st1, (sA.w * ve) * kd);
        // o partial: q_d * (wm0*st0 + wm1*st1)
        float p = qd * fmaf(sB.x, st0, sB.y * st1);
        #pragma unroll
        for (int off = 32; off; off >>= 1) p += __shfl_xor(p, off);
        if (lane == 0) Op[(size_t)t * 512] = p;

        kd = kd_n; qd = qd_n; ve = ve_n; sA = sA_n; sB = sB_n;
    }
}

// ---------------------------------------------------------------------------
// Kernel 4: output GEMM:  Y = O @ Wo^T + bo + x   (residual fused)
// ---------------------------------------------------------------------------
__global__ __launch_bounds__(256) void out_gemm(
    const float* __restrict__ A, const float* __restrict__ W,
    const float* __restrict__ bo, const float* __restrict__ xres,
    float* __restrict__ Y)
{
    __shared__ float As[BK][LDT];
    __shared__ float Bs[BK][LDT];
    const int tid = threadIdx.x;
    const int nt = blockIdx.x;   // 0..7
    const int mt = blockIdx.y;   // 0..63
    const int nbase = nt * BN;
    const int m0 = mt * BM;
    const int tx = tid & 15, ty = tid >> 4;
    float acc[4][4] = {};

    for (int kt = 0; kt < 512; kt += BK) {
        #pragma unroll
        for (int half = 0; half < 2; ++half) {
            const int r  = (tid >> 3) + half * 32;
            const int c4 = (tid & 7) * 4;
            float4 a = *(const float4*)(A + (size_t)(m0 + r) * 512 + kt + c4);
            As[c4+0][r] = a.x; As[c4+1][r] = a.y; As[c4+2][r] = a.z; As[c4+3][r] = a.w;
            float4 bv = *(const float4*)(W + (size_t)(nbase + r) * 512 + kt + c4);
            Bs[c4+0][r] = bv.x; Bs[c4+1][r] = bv.y; Bs[c4+2][r] = bv.z; Bs[c4+3][r] = bv.w;
        }
        __syncthreads();
        #pragma unroll
        for (int kk = 0; kk < BK; ++kk) {
            float4 a  = *(const float4*)(&As[kk][ty * 4]);
            float4 bv = *(const float4*)(&Bs[kk][tx * 4]);
            acc[0][0] = fmaf(a.x, bv.x, acc[0][0]); acc[0][1] = fmaf(a.x, bv.y, acc[0][1]);
            acc[0][2] = fmaf(a.x, bv.z, acc[0][2]); acc[0][3] = fmaf(a.x, bv.w, acc[0][3]);
            acc[1][0] = fmaf(a.y, bv.x, acc[1][0]); acc[1][1] = fmaf(a.y, bv.y, acc[1][1]);
            acc[1][2] = fmaf(a.y, bv.z, acc[1][2]); acc[1][3] = fmaf(a.y, bv.w, acc[1][3]);
            acc[2][0] = fmaf(a.z, bv.x, acc[2][0]); acc[2][1] = fmaf(a.z, bv.y, acc[2][1]);
            acc[2][2] = fmaf(a.z, bv.z, acc[2][2]); acc[2][3] = fmaf(a.z, bv.w, acc[2][3]);
            acc[3][0] = fmaf(a.w, bv.x, acc[3][0]); acc[3][1] = fmaf(a.w, bv.y, acc[3][1]);
            acc[3][2] = fmaf(a.w, bv.z, acc[3][2]); acc[3][3] = fmaf(a.w, bv.w, acc[3][3]);
        }
        __syncthreads();
    }

    const int col = nbase + tx * 4;
    const float4 bb = *(const float4*)(bo + col);
    #pragma unroll
    for (int mi = 0; mi < 4; ++mi) {
        const int row = m0 + ty * 4 + mi;
        const float4 r = *(const float4*)(xres + (size_t)row * 512 + col);
        float4 o;
        o.x = acc[mi][0] + bb.x + r.x;
        o.y = acc[mi][1] + bb.y + r.y;
        o.z = acc[mi][2] + bb.z + r.z;
        o.w = acc[mi][3] + bb.w + r.w;
        *(float4*)(Y + (size_t)row * 512 + col) = o;
    }
}

// ---------------------------------------------------------------------------
// Kernel 5: LayerNorm over D=512. One wave per row; 8 elems per lane.
// ---------------------------------------------------------------------------
__global__ __launch_bounds__(256) void ln_kernel(
    const float* __restrict__ Y, const float* __restrict__ ln_w,
    const float* __restrict__ ln_b, float* __restrict__ out)
{
    const int wave = threadIdx.x >> 6;
    const int lane = threadIdx.x & 63;
    const int row = blockIdx.x * 4 + wave;   // 0..4095
    const float* yp = Y + (size_t)row * 512;

    float4 v0 = *(const float4*)(yp + lane * 8);
    float4 v1 = *(const float4*)(yp + lane * 8 + 4);
    float s  = v0.x + v0.y + v0.z + v0.w + v1.x + v1.y + v1.z + v1.w;
    float sq = v0.x*v0.x + v0.y*v0.y + v0.z*v0.z + v0.w*v0.w
             + v1.x*v1.x + v1.y*v1.y + v1.z*v1.z + v1.w*v1.w;
    #pragma unroll
    for (int off = 32; off; off >>= 1) {
        s  += __shfl_xor(s,  off);
        sq += __shfl_xor(sq, off);
    }
    const float mu  = s * (1.f / 512.f);
    const float var = sq * (1.f / 512.f) - mu * mu;
    const float inv = rsqrtf(var + EPS_);

    float4 w0 = *(const float4*)(ln_w + lane * 8);
    float4 w1 = *(const float4*)(ln_w + lane * 8 + 4);
    float4 b0 = *(const float4*)(ln_b + lane * 8);
    float4 b1 = *(const float4*)(ln_b + lane * 8 + 4);
    float4 o0, o1;
    o0.x = (v0.x - mu) * inv * w0.x + b0.x;
    o0.y = (v0.y - mu) * inv * w0.y + b0.y;
    o0.z = (v0.z - mu) * inv * w0.z + b0.z;
    o0.w = (v0.w - mu) * inv * w0.w + b0.w;
    o1.x = (v1.x - mu) * inv * w1.x + b1.x;
    o1.y = (v1.y - mu) * inv * w1.y + b1.y;
    o1.z = (v1.z - mu) * inv * w1.z + b1.z;
    o1.w = (v1.w - mu) * inv * w1.w + b1.w;
    *(float4*)(out + (size_t)row * 512 + lane * 8)     = o0;
    *(float4*)(out + (size_t)row * 512 + lane * 8 + 4) = o1;
}

// ---------------------------------------------------------------------------
extern "C" void kernel_launch(void* const* d_in, const int* in_sizes, int n_in,
                              void* d_out, int out_size, void* d_ws, size_t ws_size,
                              hipStream_t stream)
{
    const float* x   = (const float*)d_in[0];
    const float* Wq  = (const float*)d_in[1];
    const float* Wk  = (const float*)d_in[2];
    const float* Wv  = (const float*)d_in[3];
    const float* Wo  = (const float*)d_in[4];
    const float* bo  = (const float*)d_in[5];
    const float* Wg  = (const float*)d_in[6];
    const float* bg  = (const float*)d_in[7];
    const float* la  = (const float*)d_in[8];
    const float* lnw = (const float*)d_in[9];
    const float* lnb = (const float*)d_in[10];

    float* ws = (float*)d_ws;
    const size_t NQ = (size_t)B_ * S_ * D_;          // 2,097,152
    float* Qraw = ws;
    float* Kraw = Qraw + NQ;
    float* Vws  = Kraw + NQ;
    float* Graw = Vws + NQ;                          // B*S*32 = 131072
    float* SCAL = Graw + (size_t)B_ * S_ * 32;       // B*H*S*8 = 262144
    float* Obuf = SCAL + (size_t)B_ * H_ * S_ * 8;
    float* Ybuf = Obuf + NQ;

    // 1) projections
    proj_gemm<<<dim3(25, 64), 256, 0, stream>>>(x, Wq, Wk, Wv, Wg, Qraw, Kraw, Vws, Graw);
    // 2) rope + gates
    postproc<<<4096, 256, 0, stream>>>(Qraw, Kraw, Graw, bg, la, SCAL);
    // 3) scan
    scan_kernel<<<2048, 64, 0, stream>>>(Qraw, Kraw, Vws, SCAL, Obuf);
    // 4) output projection + residual
    out_gemm<<<dim3(8, 64), 256, 0, stream>>>(Obuf, Wo, bo, x, Ybuf);
    // 5) layernorm
    ln_kernel<<<1024, 256, 0, stream>>>(Ybuf, lnw, lnb, (float*)d_out);
}

// Round 2
// 333.756 us; speedup vs baseline: 2.1422x; 2.1422x over previous
//
#include <hip/hip_runtime.h>
#include <hip/hip_bf16.h>
#include <math.h>

// Problem constants
#define B_  4
#define S_  1024
#define D_  512
#define H_  8
#define HD_ 64
#define M_  2
#define EPS_ 1e-5f

// GEMM tiling
#define BM 64
#define BN 64
#define BK 32
#define LDT 68   // padded LDS leading dim (floats)

typedef __attribute__((ext_vector_type(8))) short  bf16x8;
typedef __attribute__((ext_vector_type(4))) short  bf16x4;
typedef __attribute__((ext_vector_type(4))) float  f32x4;

#define MFMA16(a, b, c) __builtin_amdgcn_mfma_f32_16x16x32_bf16((a), (b), (c), 0, 0, 0)

__device__ __forceinline__ float bf2f(short u) {
    union { unsigned int i; float f; } v;
    v.i = ((unsigned int)(unsigned short)u) << 16;
    return v.f;
}
__device__ __forceinline__ short f2bf(float f) {
    __hip_bfloat16 h = __float2bfloat16(f);
    return *reinterpret_cast<short*>(&h);
}

// ---------------------------------------------------------------------------
// Kernel 1: fused projection GEMM.  Y = x @ [Wq;Wk;Wv;Wg]^T  (raw, no bias)
// ---------------------------------------------------------------------------
__global__ __launch_bounds__(256) void proj_gemm(
    const float* __restrict__ x,
    const float* __restrict__ Wq, const float* __restrict__ Wk,
    const float* __restrict__ Wv, const float* __restrict__ Wg,
    float* __restrict__ Qraw, float* __restrict__ Kraw,
    float* __restrict__ Vws,  float* __restrict__ Graw)
{
    __shared__ float As[BK][LDT];   // [k][m]
    __shared__ float Bs[BK][LDT];   // [k][n]
    const int tid = threadIdx.x;
    const int nt = blockIdx.x;      // 0..24
    const int mt = blockIdx.y;      // 0..63
    const int nbase = nt * BN;

    const float* W; float* dst; int dcols, nloc, nrow_lim;
    if (nbase < 512)       { W = Wq; dst = Qraw; dcols = 512; nloc = nbase;        nrow_lim = 512; }
    else if (nbase < 1024) { W = Wk; dst = Kraw; dcols = 512; nloc = nbase - 512;  nrow_lim = 512; }
    else if (nbase < 1536) { W = Wv; dst = Vws;  dcols = 512; nloc = nbase - 1024; nrow_lim = 512; }
    else                   { W = Wg; dst = Graw; dcols = 32;  nloc = 0;            nrow_lim = 32;  }

    const int m0 = mt * BM;
    const int tx = tid & 15, ty = tid >> 4;
    float acc[4][4] = {};

    for (int kt = 0; kt < 512; kt += BK) {
        #pragma unroll
        for (int half = 0; half < 2; ++half) {
            const int r  = (tid >> 3) + half * 32;   // 0..63
            const int c4 = (tid & 7) * 4;            // 0..28
            float4 a = *(const float4*)(x + (size_t)(m0 + r) * 512 + kt + c4);
            As[c4+0][r] = a.x; As[c4+1][r] = a.y; As[c4+2][r] = a.z; As[c4+3][r] = a.w;
            const int wr = nloc + r;
            float4 bv = make_float4(0.f, 0.f, 0.f, 0.f);
            if (wr < nrow_lim) bv = *(const float4*)(W + (size_t)wr * 512 + kt + c4);
            Bs[c4+0][r] = bv.x; Bs[c4+1][r] = bv.y; Bs[c4+2][r] = bv.z; Bs[c4+3][r] = bv.w;
        }
        __syncthreads();
        #pragma unroll
        for (int kk = 0; kk < BK; ++kk) {
            float4 a  = *(const float4*)(&As[kk][ty * 4]);
            float4 bv = *(const float4*)(&Bs[kk][tx * 4]);
            acc[0][0] = fmaf(a.x, bv.x, acc[0][0]); acc[0][1] = fmaf(a.x, bv.y, acc[0][1]);
            acc[0][2] = fmaf(a.x, bv.z, acc[0][2]); acc[0][3] = fmaf(a.x, bv.w, acc[0][3]);
            acc[1][0] = fmaf(a.y, bv.x, acc[1][0]); acc[1][1] = fmaf(a.y, bv.y, acc[1][1]);
            acc[1][2] = fmaf(a.y, bv.z, acc[1][2]); acc[1][3] = fmaf(a.y, bv.w, acc[1][3]);
            acc[2][0] = fmaf(a.z, bv.x, acc[2][0]); acc[2][1] = fmaf(a.z, bv.y, acc[2][1]);
            acc[2][2] = fmaf(a.z, bv.z, acc[2][2]); acc[2][3] = fmaf(a.z, bv.w, acc[2][3]);
            acc[3][0] = fmaf(a.w, bv.x, acc[3][0]); acc[3][1] = fmaf(a.w, bv.y, acc[3][1]);
            acc[3][2] = fmaf(a.w, bv.z, acc[3][2]); acc[3][3] = fmaf(a.w, bv.w, acc[3][3]);
        }
        __syncthreads();
    }

    const int col = nloc + tx * 4;
    if (col < nrow_lim) {
        #pragma unroll
        for (int mi = 0; mi < 4; ++mi) {
            const int row = m0 + ty * 4 + mi;
            float4 o = make_float4(acc[mi][0], acc[mi][1], acc[mi][2], acc[mi][3]);
            *(float4*)(dst + (size_t)row * dcols + col) = o;
        }
    }
}

// ---------------------------------------------------------------------------
// Kernel 2: RoPE (in-place on Qraw/Kraw) + gate scalars.
// scal layout: ((b*H+h)*S + t)*8 + {ret0,ret1,ww0,ww1,wm0,wm1,0,0}
// ---------------------------------------------------------------------------
__global__ __launch_bounds__(256) void postproc(
    float* __restrict__ Qraw, float* __restrict__ Kraw,
    const float* __restrict__ Graw, const float* __restrict__ bg,
    const float* __restrict__ logit_alphas, float* __restrict__ scal)
{
    const int g = blockIdx.x * 256 + threadIdx.x;     // 0 .. 1048575
    const int i   = g & 31;
    const int bsh = g >> 5;        // (b*S+s)*H + h
    const int h   = bsh & 7;
    const int bs  = bsh >> 3;      // b*S + s
    const int s   = bs & (S_ - 1);

    const float inv = exp2f(-(float)i * (13.287712379549449f / 32.0f));
    const float fr = (float)s * inv;
    float sn, cs;
    sincosf(fr, &sn, &cs);

    float2* qp = (float2*)Qraw + (size_t)bsh * 32 + i;
    float2 q = *qp;
    *qp = make_float2(q.x * cs - q.y * sn, q.x * sn + q.y * cs);
    float2* kp = (float2*)Kraw + (size_t)bsh * 32 + i;
    float2 k = *kp;
    *kp = make_float2(k.x * cs - k.y * sn, k.x * sn + k.y * cs);

    if (i == 0) {
        const float4 gv = *(const float4*)(Graw + (size_t)bs * 32 + h * 4);
        const float g0 = gv.x + bg[h * 4 + 0];
        const float g1 = gv.y + bg[h * 4 + 1];
        const float g2 = gv.z + bg[h * 4 + 2];
        const float g3 = gv.w + bg[h * 4 + 3];
        const float gf  = 1.f / (1.f + expf(-g0));
        const float gu  = 1.f / (1.f + expf(-g1));
        const float wm0 = 1.f / (1.f + expf(-(g2 - g3)));
        const float wm1 = 1.f - wm0;
        const float a0 = 1.f / (1.f + expf(-logit_alphas[h * 2 + 0]));
        const float a1 = 1.f / (1.f + expf(-logit_alphas[h * 2 + 1]));
        const int b = bs >> 10;
        float* sp = scal + ((size_t)(b * H_ + h) * S_ + s) * 8;
        sp[0] = a0 * gf; sp[1] = a1 * gf;
        sp[2] = wm0 * gu; sp[3] = wm1 * gu;
        sp[4] = wm0; sp[5] = wm1;
        sp[6] = 0.f; sp[7] = 0.f;
    }
}

// ---------------------------------------------------------------------------
// Kernel 3: chunked linear-attention scan.  One block per (b,h); 4 waves;
// 16 sequential chunks of C=64.  State (2 x 64 x 64 fp32, stored transposed
// [m][e][d]) lives in LDS.  All per-chunk GEMMs via mfma_f32_16x16x32_bf16.
// Decay ratios handled in log2 space (underflow-safe).
// ---------------------------------------------------------------------------
__global__ __launch_bounds__(256) void chunk_scan(
    const float* __restrict__ Q, const float* __restrict__ K,
    const float* __restrict__ V, const float* __restrict__ scal,
    float* __restrict__ O)
{
    // bf16 tiles, row stride 72 shorts (144 B) -> 2-way bank aliasing (free)
    __shared__ __align__(16) short sQ [64 * 72];
    __shared__ __align__(16) short sK [64 * 72];
    __shared__ __align__(16) short sVT[64 * 72];       // VT[e][tau]
    __shared__ __align__(16) short sP [64 * 72];
    __shared__ __align__(16) short sKscT[2][64 * 72];  // KscT[m][d][tau]
    __shared__ __align__(16) float stateT[2][64 * 68]; // stateT[m][e][d]
    __shared__ float sScal[64][8];
    __shared__ float sLc[2][64];   // log2 cumulative retain (inclusive)
    __shared__ float sKs[2][64];   // ww * exp2(lR - lc)       (K scale)
    __shared__ float sQs[2][64];   // wm * exp2(lc)            (Q scale)
    __shared__ float sR[2];        // exp2(lR) = total chunk decay

    const int tid  = threadIdx.x;
    const int wave = tid >> 6, lane = tid & 63;
    const int lrow = lane & 15, lgrp = lane >> 4;
    const int h = blockIdx.x & 7, b = blockIdx.x >> 3;
    const int row0 = wave * 16;

    // zero initial state
    for (int i = tid; i < 2 * 64 * 68; i += 256) (&stateT[0][0])[i] = 0.f;

    for (int c = 0; c < 16; ++c) {
        __syncthreads();   // state update / prior-chunk reads complete
        const int s0 = c * 64;

        // ---- load chunk: Q,K row-major bf16; V transposed; scalars ----
        for (int i = tid; i < 1024; i += 256) {
            const int r = i >> 4, c4 = (i & 15) * 4;
            const size_t g = ((size_t)(b * S_ + s0 + r)) * D_ + h * HD_ + c4;
            float4 q4 = *(const float4*)(Q + g);
            float4 k4 = *(const float4*)(K + g);
            float4 v4 = *(const float4*)(V + g);
            bf16x4 qs = { f2bf(q4.x), f2bf(q4.y), f2bf(q4.z), f2bf(q4.w) };
            bf16x4 ks = { f2bf(k4.x), f2bf(k4.y), f2bf(k4.z), f2bf(k4.w) };
            *(bf16x4*)&sQ[r * 72 + c4] = qs;
            *(bf16x4*)&sK[r * 72 + c4] = ks;
            sVT[(c4 + 0) * 72 + r] = f2bf(v4.x);
            sVT[(c4 + 1) * 72 + r] = f2bf(v4.y);
            sVT[(c4 + 2) * 72 + r] = f2bf(v4.z);
            sVT[(c4 + 3) * 72 + r] = f2bf(v4.w);
        }
        if (tid < 128) {
            const int r = tid >> 1, p = tid & 1;
            const float* sp = scal + ((size_t)(b * H_ + h) * S_ + s0 + r) * 8 + p * 4;
            *(float4*)&sScal[r][p * 4] = *(const float4*)sp;
        }
        __syncthreads();

        // ---- phase B: per-m log2-cumprod of retain + scale vectors ----
        if (wave < 2) {
            const int m = wave;
            const float ret = sScal[lane][m];
            float pre = log2f(ret);
            #pragma unroll
            for (int off = 1; off < 64; off <<= 1) {
                const float u = __shfl_up(pre, off);
                if (lane >= off) pre += u;
            }
            sLc[m][lane] = pre;
            const float lR = __shfl(pre, 63);
            sKs[m][lane] = sScal[lane][2 + m] * exp2f(lR - pre);
            sQs[m][lane] = sScal[lane][4 + m] * exp2f(pre);
            if (lane == 63) sR[m] = exp2f(lR);
        }
        __syncthreads();

        // ---- B2: build scaled-K transpose  KscT[m][d][tau] ----
        {
            const int task = tid >> 1, halfd = tid & 1;
            const int m = task >> 6, tau = task & 63;
            const float ksc = sKs[m][tau];
            #pragma unroll
            for (int dd = halfd * 32; dd < halfd * 32 + 32; dd += 8) {
                bf16x8 kr = *(const bf16x8*)&sK[tau * 72 + dd];
                #pragma unroll
                for (int j = 0; j < 8; ++j)
                    sKscT[m][(dd + j) * 72 + tau] = f2bf(bf2f(kr[j]) * ksc);
            }
        }

        // ---- QK^T (S tiles stay in registers) ----
        f32x4 accS[4], accO[4];
        #pragma unroll
        for (int cb = 0; cb < 4; ++cb) { accS[cb] = (f32x4)0.f; accO[cb] = (f32x4)0.f; }
        #pragma unroll
        for (int kk = 0; kk < 2; ++kk) {
            const int kb = kk * 32 + lgrp * 8;
            bf16x8 a = *(const bf16x8*)&sQ[(row0 + lrow) * 72 + kb];
            #pragma unroll
            for (int cb = 0; cb < 4; ++cb) {
                bf16x8 bb = *(const bf16x8*)&sK[(cb * 16 + lrow) * 72 + kb];
                accS[cb] = MFMA16(a, bb, accS[cb]);
            }
        }

        // ---- O_inter = [qs0|qs1] (64x128) @ [state0;state1] (128x64) ----
        #pragma unroll
        for (int kk = 0; kk < 4; ++kk) {
            const int k0 = kk * 32 + lgrp * 8;
            const int m = k0 >> 6, d0 = k0 & 63;
            const float qs = sQs[m][row0 + lrow];
            bf16x8 qr = *(const bf16x8*)&sQ[(row0 + lrow) * 72 + d0];
            bf16x8 a;
            #pragma unroll
            for (int j = 0; j < 8; ++j) a[j] = f2bf(bf2f(qr[j]) * qs);
            #pragma unroll
            for (int cb = 0; cb < 4; ++cb) {
                const float* spt = &stateT[m][(cb * 16 + lrow) * 68 + d0];
                f32x4 x0 = *(const f32x4*)spt;
                f32x4 x1 = *(const f32x4*)(spt + 4);
                bf16x8 bb;
                #pragma unroll
                for (int j = 0; j < 4; ++j) { bb[j] = f2bf(x0[j]); bb[4 + j] = f2bf(x1[j]); }
                accO[cb] = MFMA16(a, bb, accO[cb]);
            }
        }

        // ---- P build: decay/mask/gate scaling (log-space ratios) ----
        #pragma unroll
        for (int r = 0; r < 4; ++r) {
            const int t = row0 + lgrp * 4 + r;
            const float wm0 = sScal[t][4], wm1 = sScal[t][5];
            const float lc0t = sLc[0][t],  lc1t = sLc[1][t];
            #pragma unroll
            for (int cb = 0; cb < 4; ++cb) {
                const int tau = cb * 16 + lrow;
                float p = 0.f;
                if (tau <= t) {
                    const float c0 = wm0 * sScal[tau][2] * exp2f(lc0t - sLc[0][tau]);
                    const float c1 = wm1 * sScal[tau][3] * exp2f(lc1t - sLc[1][tau]);
                    p = accS[cb][r] * (c0 + c1);
                }
                sP[t * 72 + tau] = f2bf(p);
            }
        }

        // ---- O_intra = P @ V   (sP rows are wave-local; in-wave LDS order) ----
        #pragma unroll
        for (int kk = 0; kk < 2; ++kk) {
            const int kb = kk * 32 + lgrp * 8;
            bf16x8 a = *(const bf16x8*)&sP[(row0 + lrow) * 72 + kb];
            #pragma unroll
            for (int cb = 0; cb < 4; ++cb) {
                bf16x8 bb = *(const bf16x8*)&sVT[(cb * 16 + lrow) * 72 + kb];
                accO[cb] = MFMA16(a, bb, accO[cb]);
            }
        }

        // ---- store O chunk ----
        #pragma unroll
        for (int cb = 0; cb < 4; ++cb) {
            #pragma unroll
            for (int r = 0; r < 4; ++r) {
                const int t = row0 + lgrp * 4 + r;
                O[((size_t)(b * S_ + s0 + t)) * D_ + h * HD_ + cb * 16 + lrow] = accO[cb][r];
            }
        }

        __syncthreads();   // O_inter stateT reads + sKscT writes done

        // ---- state update: stateT[m] = R_m * stateT[m] + VT @ Ksc ----
        #pragma unroll
        for (int m = 0; m < 2; ++m) {
            f32x4 accU[4];
            #pragma unroll
            for (int db = 0; db < 4; ++db) accU[db] = (f32x4)0.f;
            #pragma unroll
            for (int kk = 0; kk < 2; ++kk) {
                const int kb = kk * 32 + lgrp * 8;
                bf16x8 a = *(const bf16x8*)&sVT[(row0 + lrow) * 72 + kb];
                #pragma unroll
                for (int db = 0; db < 4; ++db) {
                    bf16x8 bb = *(const bf16x8*)&sKscT[m][(db * 16 + lrow) * 72 + kb];
                    accU[db] = MFMA16(a, bb, accU[db]);
                }
            }
            const float Rm = sR[m];
            #pragma unroll
            for (int db = 0; db < 4; ++db) {
                #pragma unroll
                for (int r = 0; r < 4; ++r) {
                    const int e = row0 + lgrp * 4 + r;
                    float* sp = &stateT[m][e * 68 + db * 16 + lrow];
                    *sp = Rm * (*sp) + accU[db][r];
                }
            }
        }
    }
}

// ---------------------------------------------------------------------------
// Kernel 4: output GEMM:  Y = O @ Wo^T + bo + x   (residual fused)
// ---------------------------------------------------------------------------
__global__ __launch_bounds__(256) void out_gemm(
    const float* __restrict__ A, const float* __restrict__ W,
    const float* __restrict__ bo, const float* __restrict__ xres,
    float* __restrict__ Y)
{
    __shared__ float As[BK][LDT];
    __shared__ float Bs[BK][LDT];
    const int tid = threadIdx.x;
    const int nt = blockIdx.x;   // 0..7
    const int mt = blockIdx.y;   // 0..63
    const int nbase = nt * BN;
    const int m0 = mt * BM;
    const int tx = tid & 15, ty = tid >> 4;
    float acc[4][4] = {};

    for (int kt = 0; kt < 512; kt += BK) {
        #pragma unroll
        for (int half = 0; half < 2; ++half) {
            const int r  = (tid >> 3) + half * 32;
            const int c4 = (tid & 7) * 4;
            float4 a = *(const float4*)(A + (size_t)(m0 + r) * 512 + kt + c4);
            As[c4+0][r] = a.x; As[c4+1][r] = a.y; As[c4+2][r] = a.z; As[c4+3][r] = a.w;
            float4 bv = *(const float4*)(W + (size_t)(nbase + r) * 512 + kt + c4);
            Bs[c4+0][r] = bv.x; Bs[c4+1][r] = bv.y; Bs[c4+2][r] = bv.z; Bs[c4+3][r] = bv.w;
        }
        __syncthreads();
        #pragma unroll
        for (int kk = 0; kk < BK; ++kk) {
            float4 a  = *(const float4*)(&As[kk][ty * 4]);
            float4 bv = *(const float4*)(&Bs[kk][tx * 4]);
            acc[0][0] = fmaf(a.x, bv.x, acc[0][0]); acc[0][1] = fmaf(a.x, bv.y, acc[0][1]);
            acc[0][2] = fmaf(a.x, bv.z, acc[0][2]); acc[0][3] = fmaf(a.x, bv.w, acc[0][3]);
            acc[1][0] = fmaf(a.y, bv.x, acc[1][0]); acc[1][1] = fmaf(a.y, bv.y, acc[1][1]);
            acc[1][2] = fmaf(a.y, bv.z, acc[1][2]); acc[1][3] = fmaf(a.y, bv.w, acc[1][3]);
            acc[2][0] = fmaf(a.z, bv.x, acc[2][0]); acc[2][1] = fmaf(a.z, bv.y, acc[2][1]);
            acc[2][2] = fmaf(a.z, bv.z, acc[2][2]); acc[2][3] = fmaf(a.z, bv.w, acc[2][3]);
            acc[3][0] = fmaf(a.w, bv.x, acc[3][0]); acc[3][1] = fmaf(a.w, bv.y, acc[3][1]);
            acc[3][2] = fmaf(a.w, bv.z, acc[3][2]); acc[3][3] = fmaf(a.w, bv.w, acc[3][3]);
        }
        __syncthreads();
    }

    const int col = nbase + tx * 4;
    const float4 bb = *(const float4*)(bo + col);
    #pragma unroll
    for (int mi = 0; mi < 4; ++mi) {
        const int row = m0 + ty * 4 + mi;
        const float4 r = *(const float4*)(xres + (size_t)row * 512 + col);
        float4 o;
        o.x = acc[mi][0] + bb.x + r.x;
        o.y = acc[mi][1] + bb.y + r.y;
        o.z = acc[mi][2] + bb.z + r.z;
        o.w = acc[mi][3] + bb.w + r.w;
        *(float4*)(Y + (size_t)row * 512 + col) = o;
    }
}

// ---------------------------------------------------------------------------
// Kernel 5: LayerNorm over D=512. One wave per row; 8 elems per lane.
// ---------------------------------------------------------------------------
__global__ __launch_bounds__(256) void ln_kernel(
    const float* __restrict__ Y, const float* __restrict__ ln_w,
    const float* __restrict__ ln_b, float* __restrict__ out)
{
    const int wave = threadIdx.x >> 6;
    const int lane = threadIdx.x & 63;
    const int row = blockIdx.x * 4 + wave;   // 0..4095
    const float* yp = Y + (size_t)row * 512;

    float4 v0 = *(const float4*)(yp + lane * 8);
    float4 v1 = *(const float4*)(yp + lane * 8 + 4);
    float s  = v0.x + v0.y + v0.z + v0.w + v1.x + v1.y + v1.z + v1.w;
    float sq = v0.x*v0.x + v0.y*v0.y + v0.z*v0.z + v0.w*v0.w
             + v1.x*v1.x + v1.y*v1.y + v1.z*v1.z + v1.w*v1.w;
    #pragma unroll
    for (int off = 32; off; off >>= 1) {
        s  += __shfl_xor(s,  off);
        sq += __shfl_xor(sq, off);
    }
    const float mu  = s * (1.f / 512.f);
    const float var = sq * (1.f / 512.f) - mu * mu;
    const float inv = rsqrtf(var + EPS_);

    float4 w0 = *(const float4*)(ln_w + lane * 8);
    float4 w1 = *(const float4*)(ln_w + lane * 8 + 4);
    float4 b0 = *(const float4*)(ln_b + lane * 8);
    float4 b1 = *(const float4*)(ln_b + lane * 8 + 4);
    float4 o0, o1;
    o0.x = (v0.x - mu) * inv * w0.x + b0.x;
    o0.y = (v0.y - mu) * inv * w0.y + b0.y;
    o0.z = (v0.z - mu) * inv * w0.z + b0.z;
    o0.w = (v0.w - mu) * inv * w0.w + b0.w;
    o1.x = (v1.x - mu) * inv * w1.x + b1.x;
    o1.y = (v1.y - mu) * inv * w1.y + b1.y;
    o1.z = (v1.z - mu) * inv * w1.z + b1.z;
    o1.w = (v1.w - mu) * inv * w1.w + b1.w;
    *(float4*)(out + (size_t)row * 512 + lane * 8)     = o0;
    *(float4*)(out + (size_t)row * 512 + lane * 8 + 4) = o1;
}

// ---------------------------------------------------------------------------
extern "C" void kernel_launch(void* const* d_in, const int* in_sizes, int n_in,
                              void* d_out, int out_size, void* d_ws, size_t ws_size,
                              hipStream_t stream)
{
    const float* x   = (const float*)d_in[0];
    const float* Wq  = (const float*)d_in[1];
    const float* Wk  = (const float*)d_in[2];
    const float* Wv  = (const float*)d_in[3];
    const float* Wo  = (const float*)d_in[4];
    const float* bo  = (const float*)d_in[5];
    const float* Wg  = (const float*)d_in[6];
    const float* bg  = (const float*)d_in[7];
    const float* la  = (const float*)d_in[8];
    const float* lnw = (const float*)d_in[9];
    const float* lnb = (const float*)d_in[10];

    float* ws = (float*)d_ws;
    const size_t NQ = (size_t)B_ * S_ * D_;          // 2,097,152
    float* Qraw = ws;
    float* Kraw = Qraw + NQ;
    float* Vws  = Kraw + NQ;
    float* Graw = Vws + NQ;                          // B*S*32 = 131072
    float* SCAL = Graw + (size_t)B_ * S_ * 32;       // B*H*S*8 = 262144
    float* Obuf = SCAL + (size_t)B_ * H_ * S_ * 8;
    float* Ybuf = Obuf + NQ;

    // 1) projections
    proj_gemm<<<dim3(25, 64), 256, 0, stream>>>(x, Wq, Wk, Wv, Wg, Qraw, Kraw, Vws, Graw);
    // 2) rope + gates
    postproc<<<4096, 256, 0, stream>>>(Qraw, Kraw, Graw, bg, la, SCAL);
    // 3) chunked scan (MFMA)
    chunk_scan<<<32, 256, 0, stream>>>(Qraw, Kraw, Vws, SCAL, Obuf);
    // 4) output projection + residual
    out_gemm<<<dim3(8, 64), 256, 0, stream>>>(Obuf, Wo, bo, x, Ybuf);
    // 5) layernorm
    ln_kernel<<<1024, 256, 0, stream>>>(Ybuf, lnw, lnb, (float*)d_out);
}

// Round 3
// 270.221 us; speedup vs baseline: 2.6459x; 1.2351x over previous
//
#include <hip/hip_runtime.h>
#include <hip/hip_bf16.h>
#include <math.h>

// Problem constants
#define B_  4
#define S_  1024
#define D_  512
#define H_  8
#define HD_ 64
#define M_  2
#define EPS_ 1e-5f

typedef __attribute__((ext_vector_type(8))) short  bf16x8;
typedef __attribute__((ext_vector_type(4))) short  bf16x4;
typedef __attribute__((ext_vector_type(4))) float  f32x4;

#define MFMA16(a, b, c) __builtin_amdgcn_mfma_f32_16x16x32_bf16((a), (b), (c), 0, 0, 0)

__device__ __forceinline__ float bf2f(short u) {
    union { unsigned int i; float f; } v;
    v.i = ((unsigned int)(unsigned short)u) << 16;
    return v.f;
}
__device__ __forceinline__ short f2bf(float f) {
    __hip_bfloat16 h = __float2bfloat16(f);
    return *reinterpret_cast<short*>(&h);
}

// ---------------------------------------------------------------------------
// Kernel 0: convert x -> bf16, pack [Wq;Wk;Wv;Wg] -> Wcat bf16 (1664x512,
// zero-padded rows 1568..1663), Wo -> bf16.
// ---------------------------------------------------------------------------
__global__ __launch_bounds__(256) void convert_inputs(
    const float* __restrict__ x,
    const float* __restrict__ Wq, const float* __restrict__ Wk,
    const float* __restrict__ Wv, const float* __restrict__ Wg,
    const float* __restrict__ Wo,
    short* __restrict__ xbf, short* __restrict__ Wcat, short* __restrict__ Wobf)
{
    const int id = blockIdx.x * 256 + threadIdx.x;   // each handles 8 elems
    if (id < 262144) {                               // x: 2,097,152 elems
        const size_t e = (size_t)id * 8;
        float4 v0 = *(const float4*)(x + e);
        float4 v1 = *(const float4*)(x + e + 4);
        bf16x8 o = { f2bf(v0.x), f2bf(v0.y), f2bf(v0.z), f2bf(v0.w),
                     f2bf(v1.x), f2bf(v1.y), f2bf(v1.z), f2bf(v1.w) };
        *(bf16x8*)(xbf + e) = o;
    } else if (id < 368640) {                        // Wcat: 1664*512 elems
        const int i2 = id - 262144;
        const int row = i2 >> 6;
        const int c8 = (i2 & 63) * 8;
        const float* s = nullptr;
        if (row < 512)       s = Wq + (size_t)row * 512 + c8;
        else if (row < 1024) s = Wk + (size_t)(row - 512) * 512 + c8;
        else if (row < 1536) s = Wv + (size_t)(row - 1024) * 512 + c8;
        else if (row < 1568) s = Wg + (size_t)(row - 1536) * 512 + c8;
        bf16x8 o = (bf16x8)0;
        if (s) {
            float4 v0 = *(const float4*)(s);
            float4 v1 = *(const float4*)(s + 4);
            o = bf16x8{ f2bf(v0.x), f2bf(v0.y), f2bf(v0.z), f2bf(v0.w),
                        f2bf(v1.x), f2bf(v1.y), f2bf(v1.z), f2bf(v1.w) };
        }
        *(bf16x8*)(Wcat + (size_t)row * 512 + c8) = o;
    } else {                                         // Wo: 262,144 elems
        const int i3 = id - 368640;
        const size_t e = (size_t)i3 * 8;
        float4 v0 = *(const float4*)(Wo + e);
        float4 v1 = *(const float4*)(Wo + e + 4);
        bf16x8 o = { f2bf(v0.x), f2bf(v0.y), f2bf(v0.z), f2bf(v0.w),
                     f2bf(v1.x), f2bf(v1.y), f2bf(v1.z), f2bf(v1.w) };
        *(bf16x8*)(Wobf + e) = o;
    }
}

// ---------------------------------------------------------------------------
// Kernel 1: MFMA projection GEMM.  Y = xbf @ Wcat^T  (raw, no bias)
// 128x128 tile, 4 waves (2x2), BK=64, reg-prefetch -> LDS (stride-72 rows).
// Grid (13, 32): n-tiles 0-3 -> Qraw, 4-7 -> Kraw, 8-11 -> Vws, 12 -> Graw.
// ---------------------------------------------------------------------------
__global__ __launch_bounds__(256) void mfma_proj(
    const short* __restrict__ Abf, const short* __restrict__ Wcat,
    float* __restrict__ Qraw, float* __restrict__ Kraw,
    float* __restrict__ Vws,  float* __restrict__ Graw)
{
    __shared__ __align__(16) short sA[128 * 72];
    __shared__ __align__(16) short sB[128 * 72];
    const int tid = threadIdx.x;
    const int lane = tid & 63;
    const int wave = tid >> 6;
    const int lrow = lane & 15, lgrp = lane >> 4;
    const int wr = wave >> 1, wc = wave & 1;
    const int n0 = blockIdx.x * 128, m0 = blockIdx.y * 128;
    const int srow = tid >> 3, sseg = tid & 7;

    f32x4 acc[4][4];
    #pragma unroll
    for (int i = 0; i < 4; ++i)
        #pragma unroll
        for (int j = 0; j < 4; ++j) acc[i][j] = (f32x4)0.f;

    float4 pa[4], pb[4];
    #pragma unroll
    for (int i = 0; i < 4; ++i) {
        pa[i] = *(const float4*)(Abf  + (size_t)(m0 + srow + i * 32) * 512 + sseg * 8);
        pb[i] = *(const float4*)(Wcat + (size_t)(n0 + srow + i * 32) * 512 + sseg * 8);
    }

    for (int step = 0; step < 8; ++step) {
        #pragma unroll
        for (int i = 0; i < 4; ++i) {
            *(float4*)&sA[(srow + i * 32) * 72 + sseg * 8] = pa[i];
            *(float4*)&sB[(srow + i * 32) * 72 + sseg * 8] = pb[i];
        }
        __syncthreads();
        if (step < 7) {
            const int kt = (step + 1) * 64;
            #pragma unroll
            for (int i = 0; i < 4; ++i) {
                pa[i] = *(const float4*)(Abf  + (size_t)(m0 + srow + i * 32) * 512 + kt + sseg * 8);
                pb[i] = *(const float4*)(Wcat + (size_t)(n0 + srow + i * 32) * 512 + kt + sseg * 8);
            }
        }
        #pragma unroll
        for (int kk = 0; kk < 2; ++kk) {
            const int kb = kk * 32 + lgrp * 8;
            bf16x8 af[4], bfr[4];
            #pragma unroll
            for (int mi = 0; mi < 4; ++mi)
                af[mi] = *(const bf16x8*)&sA[(wr * 64 + mi * 16 + lrow) * 72 + kb];
            #pragma unroll
            for (int ni = 0; ni < 4; ++ni)
                bfr[ni] = *(const bf16x8*)&sB[(wc * 64 + ni * 16 + lrow) * 72 + kb];
            #pragma unroll
            for (int mi = 0; mi < 4; ++mi)
                #pragma unroll
                for (int ni = 0; ni < 4; ++ni)
                    acc[mi][ni] = MFMA16(af[mi], bfr[ni], acc[mi][ni]);
        }
        __syncthreads();
    }

    float* dst; int dcols, coff;
    if (n0 < 512)       { dst = Qraw; dcols = 512; coff = 0; }
    else if (n0 < 1024) { dst = Kraw; dcols = 512; coff = 512; }
    else if (n0 < 1536) { dst = Vws;  dcols = 512; coff = 1024; }
    else                { dst = Graw; dcols = 32;  coff = 1536; }

    #pragma unroll
    for (int mi = 0; mi < 4; ++mi) {
        #pragma unroll
        for (int ni = 0; ni < 4; ++ni) {
            const int col = n0 + wc * 64 + ni * 16 + lrow - coff;
            if (col < dcols) {
                #pragma unroll
                for (int j = 0; j < 4; ++j) {
                    const int row = m0 + wr * 64 + mi * 16 + lgrp * 4 + j;
                    dst[(size_t)row * dcols + col] = acc[mi][ni][j];
                }
            }
        }
    }
}

// ---------------------------------------------------------------------------
// Kernel 4: MFMA output GEMM:  Y = Obf @ Wobf^T + bo + x   (residual fused)
// ---------------------------------------------------------------------------
__global__ __launch_bounds__(256) void mfma_out(
    const short* __restrict__ Abf, const short* __restrict__ Wobf,
    const float* __restrict__ bo, const float* __restrict__ xres,
    float* __restrict__ Y)
{
    __shared__ __align__(16) short sA[128 * 72];
    __shared__ __align__(16) short sB[128 * 72];
    const int tid = threadIdx.x;
    const int lane = tid & 63;
    const int wave = tid >> 6;
    const int lrow = lane & 15, lgrp = lane >> 4;
    const int wr = wave >> 1, wc = wave & 1;
    const int n0 = blockIdx.x * 128, m0 = blockIdx.y * 128;
    const int srow = tid >> 3, sseg = tid & 7;

    f32x4 acc[4][4];
    #pragma unroll
    for (int i = 0; i < 4; ++i)
        #pragma unroll
        for (int j = 0; j < 4; ++j) acc[i][j] = (f32x4)0.f;

    float4 pa[4], pb[4];
    #pragma unroll
    for (int i = 0; i < 4; ++i) {
        pa[i] = *(const float4*)(Abf  + (size_t)(m0 + srow + i * 32) * 512 + sseg * 8);
        pb[i] = *(const float4*)(Wobf + (size_t)(n0 + srow + i * 32) * 512 + sseg * 8);
    }

    for (int step = 0; step < 8; ++step) {
        #pragma unroll
        for (int i = 0; i < 4; ++i) {
            *(float4*)&sA[(srow + i * 32) * 72 + sseg * 8] = pa[i];
            *(float4*)&sB[(srow + i * 32) * 72 + sseg * 8] = pb[i];
        }
        __syncthreads();
        if (step < 7) {
            const int kt = (step + 1) * 64;
            #pragma unroll
            for (int i = 0; i < 4; ++i) {
                pa[i] = *(const float4*)(Abf  + (size_t)(m0 + srow + i * 32) * 512 + kt + sseg * 8);
                pb[i] = *(const float4*)(Wobf + (size_t)(n0 + srow + i * 32) * 512 + kt + sseg * 8);
            }
        }
        #pragma unroll
        for (int kk = 0; kk < 2; ++kk) {
            const int kb = kk * 32 + lgrp * 8;
            bf16x8 af[4], bfr[4];
            #pragma unroll
            for (int mi = 0; mi < 4; ++mi)
                af[mi] = *(const bf16x8*)&sA[(wr * 64 + mi * 16 + lrow) * 72 + kb];
            #pragma unroll
            for (int ni = 0; ni < 4; ++ni)
                bfr[ni] = *(const bf16x8*)&sB[(wc * 64 + ni * 16 + lrow) * 72 + kb];
            #pragma unroll
            for (int mi = 0; mi < 4; ++mi)
                #pragma unroll
                for (int ni = 0; ni < 4; ++ni)
                    acc[mi][ni] = MFMA16(af[mi], bfr[ni], acc[mi][ni]);
        }
        __syncthreads();
    }

    #pragma unroll
    for (int mi = 0; mi < 4; ++mi) {
        #pragma unroll
        for (int ni = 0; ni < 4; ++ni) {
            const int col = n0 + wc * 64 + ni * 16 + lrow;
            const float bb = bo[col];
            #pragma unroll
            for (int j = 0; j < 4; ++j) {
                const int row = m0 + wr * 64 + mi * 16 + lgrp * 4 + j;
                Y[(size_t)row * 512 + col] = acc[mi][ni][j] + bb + xres[(size_t)row * 512 + col];
            }
        }
    }
}

// ---------------------------------------------------------------------------
// Kernel 2: RoPE (in-place on Qraw/Kraw) + gate scalars.
// scal layout: ((b*H+h)*S + t)*8 + {ret0,ret1,ww0,ww1,wm0,wm1,0,0}
// ---------------------------------------------------------------------------
__global__ __launch_bounds__(256) void postproc(
    float* __restrict__ Qraw, float* __restrict__ Kraw,
    const float* __restrict__ Graw, const float* __restrict__ bg,
    const float* __restrict__ logit_alphas, float* __restrict__ scal)
{
    const int g = blockIdx.x * 256 + threadIdx.x;     // 0 .. 1048575
    const int i   = g & 31;
    const int bsh = g >> 5;        // (b*S+s)*H + h
    const int h   = bsh & 7;
    const int bs  = bsh >> 3;      // b*S + s
    const int s   = bs & (S_ - 1);

    const float inv = exp2f(-(float)i * (13.287712379549449f / 32.0f));
    const float fr = (float)s * inv;
    float sn, cs;
    sincosf(fr, &sn, &cs);

    float2* qp = (float2*)Qraw + (size_t)bsh * 32 + i;
    float2 q = *qp;
    *qp = make_float2(q.x * cs - q.y * sn, q.x * sn + q.y * cs);
    float2* kp = (float2*)Kraw + (size_t)bsh * 32 + i;
    float2 k = *kp;
    *kp = make_float2(k.x * cs - k.y * sn, k.x * sn + k.y * cs);

    if (i == 0) {
        const float4 gv = *(const float4*)(Graw + (size_t)bs * 32 + h * 4);
        const float g0 = gv.x + bg[h * 4 + 0];
        const float g1 = gv.y + bg[h * 4 + 1];
        const float g2 = gv.z + bg[h * 4 + 2];
        const float g3 = gv.w + bg[h * 4 + 3];
        const float gf  = 1.f / (1.f + expf(-g0));
        const float gu  = 1.f / (1.f + expf(-g1));
        const float wm0 = 1.f / (1.f + expf(-(g2 - g3)));
        const float wm1 = 1.f - wm0;
        const float a0 = 1.f / (1.f + expf(-logit_alphas[h * 2 + 0]));
        const float a1 = 1.f / (1.f + expf(-logit_alphas[h * 2 + 1]));
        const int b = bs >> 10;
        float* sp = scal + ((size_t)(b * H_ + h) * S_ + s) * 8;
        sp[0] = a0 * gf; sp[1] = a1 * gf;
        sp[2] = wm0 * gu; sp[3] = wm1 * gu;
        sp[4] = wm0; sp[5] = wm1;
        sp[6] = 0.f; sp[7] = 0.f;
    }
}

// ---------------------------------------------------------------------------
// Kernel 3: chunked linear-attention scan.  One block per (b,h); 4 waves;
// 16 sequential chunks of C=64.  Output written directly as bf16.
// ---------------------------------------------------------------------------
__global__ __launch_bounds__(256) void chunk_scan(
    const float* __restrict__ Q, const float* __restrict__ K,
    const float* __restrict__ V, const float* __restrict__ scal,
    short* __restrict__ Obf)
{
    __shared__ __align__(16) short sQ [64 * 72];
    __shared__ __align__(16) short sK [64 * 72];
    __shared__ __align__(16) short sVT[64 * 72];       // VT[e][tau]
    __shared__ __align__(16) short sP [64 * 72];
    __shared__ __align__(16) short sKscT[2][64 * 72];  // KscT[m][d][tau]
    __shared__ __align__(16) float stateT[2][64 * 68]; // stateT[m][e][d]
    __shared__ float sScal[64][8];
    __shared__ float sLc[2][64];   // log2 cumulative retain (inclusive)
    __shared__ float sKs[2][64];   // ww * exp2(lR - lc)
    __shared__ float sQs[2][64];   // wm * exp2(lc)
    __shared__ float sR[2];        // exp2(lR)

    const int tid  = threadIdx.x;
    const int wave = tid >> 6, lane = tid & 63;
    const int lrow = lane & 15, lgrp = lane >> 4;
    const int h = blockIdx.x & 7, b = blockIdx.x >> 3;
    const int row0 = wave * 16;

    for (int i = tid; i < 2 * 64 * 68; i += 256) (&stateT[0][0])[i] = 0.f;

    for (int c = 0; c < 16; ++c) {
        __syncthreads();
        const int s0 = c * 64;

        for (int i = tid; i < 1024; i += 256) {
            const int r = i >> 4, c4 = (i & 15) * 4;
            const size_t g = ((size_t)(b * S_ + s0 + r)) * D_ + h * HD_ + c4;
            float4 q4 = *(const float4*)(Q + g);
            float4 k4 = *(const float4*)(K + g);
            float4 v4 = *(const float4*)(V + g);
            bf16x4 qs = { f2bf(q4.x), f2bf(q4.y), f2bf(q4.z), f2bf(q4.w) };
            bf16x4 ks = { f2bf(k4.x), f2bf(k4.y), f2bf(k4.z), f2bf(k4.w) };
            *(bf16x4*)&sQ[r * 72 + c4] = qs;
            *(bf16x4*)&sK[r * 72 + c4] = ks;
            sVT[(c4 + 0) * 72 + r] = f2bf(v4.x);
            sVT[(c4 + 1) * 72 + r] = f2bf(v4.y);
            sVT[(c4 + 2) * 72 + r] = f2bf(v4.z);
            sVT[(c4 + 3) * 72 + r] = f2bf(v4.w);
        }
        if (tid < 128) {
            const int r = tid >> 1, p = tid & 1;
            const float* sp = scal + ((size_t)(b * H_ + h) * S_ + s0 + r) * 8 + p * 4;
            *(float4*)&sScal[r][p * 4] = *(const float4*)sp;
        }
        __syncthreads();

        if (wave < 2) {
            const int m = wave;
            const float ret = sScal[lane][m];
            float pre = log2f(ret);
            #pragma unroll
            for (int off = 1; off < 64; off <<= 1) {
                const float u = __shfl_up(pre, off);
                if (lane >= off) pre += u;
            }
            sLc[m][lane] = pre;
            const float lR = __shfl(pre, 63);
            sKs[m][lane] = sScal[lane][2 + m] * exp2f(lR - pre);
            sQs[m][lane] = sScal[lane][4 + m] * exp2f(pre);
            if (lane == 63) sR[m] = exp2f(lR);
        }
        __syncthreads();

        {
            const int task = tid >> 1, halfd = tid & 1;
            const int m = task >> 6, tau = task & 63;
            const float ksc = sKs[m][tau];
            #pragma unroll
            for (int dd = halfd * 32; dd < halfd * 32 + 32; dd += 8) {
                bf16x8 kr = *(const bf16x8*)&sK[tau * 72 + dd];
                #pragma unroll
                for (int j = 0; j < 8; ++j)
                    sKscT[m][(dd + j) * 72 + tau] = f2bf(bf2f(kr[j]) * ksc);
            }
        }

        f32x4 accS[4], accO[4];
        #pragma unroll
        for (int cb = 0; cb < 4; ++cb) { accS[cb] = (f32x4)0.f; accO[cb] = (f32x4)0.f; }
        #pragma unroll
        for (int kk = 0; kk < 2; ++kk) {
            const int kb = kk * 32 + lgrp * 8;
            bf16x8 a = *(const bf16x8*)&sQ[(row0 + lrow) * 72 + kb];
            #pragma unroll
            for (int cb = 0; cb < 4; ++cb) {
                bf16x8 bb = *(const bf16x8*)&sK[(cb * 16 + lrow) * 72 + kb];
                accS[cb] = MFMA16(a, bb, accS[cb]);
            }
        }

        #pragma unroll
        for (int kk = 0; kk < 4; ++kk) {
            const int k0 = kk * 32 + lgrp * 8;
            const int m = k0 >> 6, d0 = k0 & 63;
            const float qs = sQs[m][row0 + lrow];
            bf16x8 qr = *(const bf16x8*)&sQ[(row0 + lrow) * 72 + d0];
            bf16x8 a;
            #pragma unroll
            for (int j = 0; j < 8; ++j) a[j] = f2bf(bf2f(qr[j]) * qs);
            #pragma unroll
            for (int cb = 0; cb < 4; ++cb) {
                const float* spt = &stateT[m][(cb * 16 + lrow) * 68 + d0];
                f32x4 x0 = *(const f32x4*)spt;
                f32x4 x1 = *(const f32x4*)(spt + 4);
                bf16x8 bb;
                #pragma unroll
                for (int j = 0; j < 4; ++j) { bb[j] = f2bf(x0[j]); bb[4 + j] = f2bf(x1[j]); }
                accO[cb] = MFMA16(a, bb, accO[cb]);
            }
        }

        #pragma unroll
        for (int r = 0; r < 4; ++r) {
            const int t = row0 + lgrp * 4 + r;
            const float wm0 = sScal[t][4], wm1 = sScal[t][5];
            const float lc0t = sLc[0][t],  lc1t = sLc[1][t];
            #pragma unroll
            for (int cb = 0; cb < 4; ++cb) {
                const int tau = cb * 16 + lrow;
                float p = 0.f;
                if (tau <= t) {
                    const float c0 = wm0 * sScal[tau][2] * exp2f(lc0t - sLc[0][tau]);
                    const float c1 = wm1 * sScal[tau][3] * exp2f(lc1t - sLc[1][tau]);
                    p = accS[cb][r] * (c0 + c1);
                }
                sP[t * 72 + tau] = f2bf(p);
            }
        }

        #pragma unroll
        for (int kk = 0; kk < 2; ++kk) {
            const int kb = kk * 32 + lgrp * 8;
            bf16x8 a = *(const bf16x8*)&sP[(row0 + lrow) * 72 + kb];
            #pragma unroll
            for (int cb = 0; cb < 4; ++cb) {
                bf16x8 bb = *(const bf16x8*)&sVT[(cb * 16 + lrow) * 72 + kb];
                accO[cb] = MFMA16(a, bb, accO[cb]);
            }
        }

        #pragma unroll
        for (int cb = 0; cb < 4; ++cb) {
            #pragma unroll
            for (int r = 0; r < 4; ++r) {
                const int t = row0 + lgrp * 4 + r;
                Obf[((size_t)(b * S_ + s0 + t)) * D_ + h * HD_ + cb * 16 + lrow] = f2bf(accO[cb][r]);
            }
        }

        __syncthreads();

        #pragma unroll
        for (int m = 0; m < 2; ++m) {
            f32x4 accU[4];
            #pragma unroll
            for (int db = 0; db < 4; ++db) accU[db] = (f32x4)0.f;
            #pragma unroll
            for (int kk = 0; kk < 2; ++kk) {
                const int kb = kk * 32 + lgrp * 8;
                bf16x8 a = *(const bf16x8*)&sVT[(row0 + lrow) * 72 + kb];
                #pragma unroll
                for (int db = 0; db < 4; ++db) {
                    bf16x8 bb = *(const bf16x8*)&sKscT[m][(db * 16 + lrow) * 72 + kb];
                    accU[db] = MFMA16(a, bb, accU[db]);
                }
            }
            const float Rm = sR[m];
            #pragma unroll
            for (int db = 0; db < 4; ++db) {
                #pragma unroll
                for (int r = 0; r < 4; ++r) {
                    const int e = row0 + lgrp * 4 + r;
                    float* sp = &stateT[m][e * 68 + db * 16 + lrow];
                    *sp = Rm * (*sp) + accU[db][r];
                }
            }
        }
    }
}

// ---------------------------------------------------------------------------
// Kernel 5: LayerNorm over D=512. One wave per row; 8 elems per lane.
// ---------------------------------------------------------------------------
__global__ __launch_bounds__(256) void ln_kernel(
    const float* __restrict__ Y, const float* __restrict__ ln_w,
    const float* __restrict__ ln_b, float* __restrict__ out)
{
    const int wave = threadIdx.x >> 6;
    const int lane = threadIdx.x & 63;
    const int row = blockIdx.x * 4 + wave;   // 0..4095
    const float* yp = Y + (size_t)row * 512;

    float4 v0 = *(const float4*)(yp + lane * 8);
    float4 v1 = *(const float4*)(yp + lane * 8 + 4);
    float s  = v0.x + v0.y + v0.z + v0.w + v1.x + v1.y + v1.z + v1.w;
    float sq = v0.x*v0.x + v0.y*v0.y + v0.z*v0.z + v0.w*v0.w
             + v1.x*v1.x + v1.y*v1.y + v1.z*v1.z + v1.w*v1.w;
    #pragma unroll
    for (int off = 32; off; off >>= 1) {
        s  += __shfl_xor(s,  off);
        sq += __shfl_xor(sq, off);
    }
    const float mu  = s * (1.f / 512.f);
    const float var = sq * (1.f / 512.f) - mu * mu;
    const float inv = rsqrtf(var + EPS_);

    float4 w0 = *(const float4*)(ln_w + lane * 8);
    float4 w1 = *(const float4*)(ln_w + lane * 8 + 4);
    float4 b0 = *(const float4*)(ln_b + lane * 8);
    float4 b1 = *(const float4*)(ln_b + lane * 8 + 4);
    float4 o0, o1;
    o0.x = (v0.x - mu) * inv * w0.x + b0.x;
    o0.y = (v0.y - mu) * inv * w0.y + b0.y;
    o0.z = (v0.z - mu) * inv * w0.z + b0.z;
    o0.w = (v0.w - mu) * inv * w0.w + b0.w;
    o1.x = (v1.x - mu) * inv * w1.x + b1.x;
    o1.y = (v1.y - mu) * inv * w1.y + b1.y;
    o1.z = (v1.z - mu) * inv * w1.z + b1.z;
    o1.w = (v1.w - mu) * inv * w1.w + b1.w;
    *(float4*)(out + (size_t)row * 512 + lane * 8)     = o0;
    *(float4*)(out + (size_t)row * 512 + lane * 8 + 4) = o1;
}

// ---------------------------------------------------------------------------
extern "C" void kernel_launch(void* const* d_in, const int* in_sizes, int n_in,
                              void* d_out, int out_size, void* d_ws, size_t ws_size,
                              hipStream_t stream)
{
    const float* x   = (const float*)d_in[0];
    const float* Wq  = (const float*)d_in[1];
    const float* Wk  = (const float*)d_in[2];
    const float* Wv  = (const float*)d_in[3];
    const float* Wo  = (const float*)d_in[4];
    const float* bo  = (const float*)d_in[5];
    const float* Wg  = (const float*)d_in[6];
    const float* bg  = (const float*)d_in[7];
    const float* la  = (const float*)d_in[8];
    const float* lnw = (const float*)d_in[9];
    const float* lnb = (const float*)d_in[10];

    const size_t NQ = (size_t)B_ * S_ * D_;          // 2,097,152
    float* Qraw = (float*)d_ws;
    float* Kraw = Qraw + NQ;
    float* Vws  = Kraw + NQ;
    float* Graw = Vws + NQ;                          // 4096*32 = 131072
    float* SCAL = Graw + (size_t)B_ * S_ * 32;       // 262144
    float* Ybuf = SCAL + (size_t)B_ * H_ * S_ * 8;
    short* xbf  = (short*)(Ybuf + NQ);
    short* Wcat = xbf + NQ;                          // 1664*512 = 851968
    short* Wobf = Wcat + (size_t)1664 * 512;
    short* Obf  = Wobf + (size_t)512 * 512;

    // 0) dtype conversion / weight packing
    convert_inputs<<<1568, 256, 0, stream>>>(x, Wq, Wk, Wv, Wg, Wo, xbf, Wcat, Wobf);
    // 1) projections (MFMA)
    mfma_proj<<<dim3(13, 32), 256, 0, stream>>>(xbf, Wcat, Qraw, Kraw, Vws, Graw);
    // 2) rope + gates
    postproc<<<4096, 256, 0, stream>>>(Qraw, Kraw, Graw, bg, la, SCAL);
    // 3) chunked scan (MFMA)
    chunk_scan<<<32, 256, 0, stream>>>(Qraw, Kraw, Vws, SCAL, Obf);
    // 4) output projection + residual (MFMA)
    mfma_out<<<dim3(4, 32), 256, 0, stream>>>(Obf, Wobf, bo, x, Ybuf);
    // 5) layernorm
    ln_kernel<<<1024, 256, 0, stream>>>(Ybuf, lnw, lnb, (float*)d_out);
}

// Round 4
// 184.460 us; speedup vs baseline: 3.8760x; 1.4649x over previous
//
#include <hip/hip_runtime.h>
#include <hip/hip_bf16.h>
#include <math.h>

// Problem constants
#define B_  4
#define S_  1024
#define D_  512
#define H_  8
#define HD_ 64
#define M_  2
#define EPS_ 1e-5f

typedef __attribute__((ext_vector_type(8))) short  bf16x8;
typedef __attribute__((ext_vector_type(4))) short  bf16x4;
typedef __attribute__((ext_vector_type(4))) float  f32x4;

#define MFMA16(a, b, c) __builtin_amdgcn_mfma_f32_16x16x32_bf16((a), (b), (c), 0, 0, 0)

__device__ __forceinline__ float bf2f(short u) {
    union { unsigned int i; float f; } v;
    v.i = ((unsigned int)(unsigned short)u) << 16;
    return v.f;
}
__device__ __forceinline__ short f2bf(float f) {
    __hip_bfloat16 h = __float2bfloat16(f);
    return *reinterpret_cast<short*>(&h);
}

// ---------------------------------------------------------------------------
// Kernel 0a: convert x -> bf16, pack [Wq;Wk;Wv;Wg] -> Wcat bf16 (1664x512,
// zero-padded rows 1568..1663), Wo -> bf16.
// ---------------------------------------------------------------------------
__global__ __launch_bounds__(256) void convert_inputs(
    const float* __restrict__ x,
    const float* __restrict__ Wq, const float* __restrict__ Wk,
    const float* __restrict__ Wv, const float* __restrict__ Wg,
    const float* __restrict__ Wo,
    short* __restrict__ xbf, short* __restrict__ Wcat, short* __restrict__ Wobf)
{
    const int id = blockIdx.x * 256 + threadIdx.x;   // each handles 8 elems
    if (id < 262144) {                               // x: 2,097,152 elems
        const size_t e = (size_t)id * 8;
        float4 v0 = *(const float4*)(x + e);
        float4 v1 = *(const float4*)(x + e + 4);
        bf16x8 o = { f2bf(v0.x), f2bf(v0.y), f2bf(v0.z), f2bf(v0.w),
                     f2bf(v1.x), f2bf(v1.y), f2bf(v1.z), f2bf(v1.w) };
        *(bf16x8*)(xbf + e) = o;
    } else if (id < 368640) {                        // Wcat: 1664*512 elems
        const int i2 = id - 262144;
        const int row = i2 >> 6;
        const int c8 = (i2 & 63) * 8;
        const float* s = nullptr;
        if (row < 512)       s = Wq + (size_t)row * 512 + c8;
        else if (row < 1024) s = Wk + (size_t)(row - 512) * 512 + c8;
        else if (row < 1536) s = Wv + (size_t)(row - 1024) * 512 + c8;
        else if (row < 1568) s = Wg + (size_t)(row - 1536) * 512 + c8;
        bf16x8 o = (bf16x8)0;
        if (s) {
            float4 v0 = *(const float4*)(s);
            float4 v1 = *(const float4*)(s + 4);
            o = bf16x8{ f2bf(v0.x), f2bf(v0.y), f2bf(v0.z), f2bf(v0.w),
                        f2bf(v1.x), f2bf(v1.y), f2bf(v1.z), f2bf(v1.w) };
        }
        *(bf16x8*)(Wcat + (size_t)row * 512 + c8) = o;
    } else {                                         // Wo: 262,144 elems
        const int i3 = id - 368640;
        const size_t e = (size_t)i3 * 8;
        float4 v0 = *(const float4*)(Wo + e);
        float4 v1 = *(const float4*)(Wo + e + 4);
        bf16x8 o = { f2bf(v0.x), f2bf(v0.y), f2bf(v0.z), f2bf(v0.w),
                     f2bf(v1.x), f2bf(v1.y), f2bf(v1.z), f2bf(v1.w) };
        *(bf16x8*)(Wobf + e) = o;
    }
}

// ---------------------------------------------------------------------------
// Kernel 0b: RoPE table  (1024 positions x 32 pair-freqs) -> float2 {cos,sin}
// ---------------------------------------------------------------------------
__global__ __launch_bounds__(256) void rope_table(float2* __restrict__ rope)
{
    const int id = blockIdx.x * 256 + threadIdx.x;   // 0..32767
    const int s = id >> 5, i = id & 31;
    const float inv = exp2f(-(float)i * (13.287712379549449f / 32.0f));
    float sn, cs;
    sincosf((float)s * inv, &sn, &cs);
    rope[id] = make_float2(cs, sn);
}

// ---------------------------------------------------------------------------
// Kernel 1: MFMA projection GEMM.  Y = xbf @ Wcat^T  (raw, no bias)
// ---------------------------------------------------------------------------
__global__ __launch_bounds__(256) void mfma_proj(
    const short* __restrict__ Abf, const short* __restrict__ Wcat,
    float* __restrict__ Qraw, float* __restrict__ Kraw,
    float* __restrict__ Vws,  float* __restrict__ Graw)
{
    __shared__ __align__(16) short sA[128 * 72];
    __shared__ __align__(16) short sB[128 * 72];
    const int tid = threadIdx.x;
    const int lane = tid & 63;
    const int wave = tid >> 6;
    const int lrow = lane & 15, lgrp = lane >> 4;
    const int wr = wave >> 1, wc = wave & 1;
    const int n0 = blockIdx.x * 128, m0 = blockIdx.y * 128;
    const int srow = tid >> 3, sseg = tid & 7;

    f32x4 acc[4][4];
    #pragma unroll
    for (int i = 0; i < 4; ++i)
        #pragma unroll
        for (int j = 0; j < 4; ++j) acc[i][j] = (f32x4)0.f;

    float4 pa[4], pb[4];
    #pragma unroll
    for (int i = 0; i < 4; ++i) {
        pa[i] = *(const float4*)(Abf  + (size_t)(m0 + srow + i * 32) * 512 + sseg * 8);
        pb[i] = *(const float4*)(Wcat + (size_t)(n0 + srow + i * 32) * 512 + sseg * 8);
    }

    for (int step = 0; step < 8; ++step) {
        #pragma unroll
        for (int i = 0; i < 4; ++i) {
            *(float4*)&sA[(srow + i * 32) * 72 + sseg * 8] = pa[i];
            *(float4*)&sB[(srow + i * 32) * 72 + sseg * 8] = pb[i];
        }
        __syncthreads();
        if (step < 7) {
            const int kt = (step + 1) * 64;
            #pragma unroll
            for (int i = 0; i < 4; ++i) {
                pa[i] = *(const float4*)(Abf  + (size_t)(m0 + srow + i * 32) * 512 + kt + sseg * 8);
                pb[i] = *(const float4*)(Wcat + (size_t)(n0 + srow + i * 32) * 512 + kt + sseg * 8);
            }
        }
        #pragma unroll
        for (int kk = 0; kk < 2; ++kk) {
            const int kb = kk * 32 + lgrp * 8;
            bf16x8 af[4], bfr[4];
            #pragma unroll
            for (int mi = 0; mi < 4; ++mi)
                af[mi] = *(const bf16x8*)&sA[(wr * 64 + mi * 16 + lrow) * 72 + kb];
            #pragma unroll
            for (int ni = 0; ni < 4; ++ni)
                bfr[ni] = *(const bf16x8*)&sB[(wc * 64 + ni * 16 + lrow) * 72 + kb];
            #pragma unroll
            for (int mi = 0; mi < 4; ++mi)
                #pragma unroll
                for (int ni = 0; ni < 4; ++ni)
                    acc[mi][ni] = MFMA16(af[mi], bfr[ni], acc[mi][ni]);
        }
        __syncthreads();
    }

    float* dst; int dcols, coff;
    if (n0 < 512)       { dst = Qraw; dcols = 512; coff = 0; }
    else if (n0 < 1024) { dst = Kraw; dcols = 512; coff = 512; }
    else if (n0 < 1536) { dst = Vws;  dcols = 512; coff = 1024; }
    else                { dst = Graw; dcols = 32;  coff = 1536; }

    #pragma unroll
    for (int mi = 0; mi < 4; ++mi) {
        #pragma unroll
        for (int ni = 0; ni < 4; ++ni) {
            const int col = n0 + wc * 64 + ni * 16 + lrow - coff;
            if (col < dcols) {
                #pragma unroll
                for (int j = 0; j < 4; ++j) {
                    const int row = m0 + wr * 64 + mi * 16 + lgrp * 4 + j;
                    dst[(size_t)row * dcols + col] = acc[mi][ni][j];
                }
            }
        }
    }
}

// ---------------------------------------------------------------------------
// Kernel A: per-chunk intra work.  Grid 512 = (b,h,chunk).  Computes gate
// scalars, RoPE'd Q/K, O_intra = P@V (to OI fp32), state delta U_m = VT@Ksc_m
// (to Ubuf fp32), chunk decay R_m (to SRb), Q-scales (to SQS).
// ---------------------------------------------------------------------------
__global__ __launch_bounds__(256) void chunk_intra(
    const float* __restrict__ Q, const float* __restrict__ K,
    const float* __restrict__ V, const float* __restrict__ Graw,
    const float* __restrict__ bg, const float* __restrict__ logit_alphas,
    const float2* __restrict__ rope,
    float* __restrict__ OI, float* __restrict__ Ubuf,
    float* __restrict__ SQS, float* __restrict__ SRb)
{
    __shared__ __align__(16) short sQ [64 * 72];
    __shared__ __align__(16) short sK [64 * 72];
    __shared__ __align__(16) short sVT[64 * 72];       // VT[e][tau]
    __shared__ __align__(16) short sP [64 * 72];
    __shared__ __align__(16) short sKscT[2][64 * 72];  // KscT[m][d][tau]
    __shared__ float sScal[64][8];
    __shared__ float sLc[2][64];
    __shared__ float sKs[2][64];
    __shared__ float sQs[2][64];

    const int tid  = threadIdx.x;
    const int wave = tid >> 6, lane = tid & 63;
    const int lrow = lane & 15, lgrp = lane >> 4;
    const int c  = blockIdx.x & 15;
    const int bh = blockIdx.x >> 4;
    const int h = bh & 7, b = bh >> 3;
    const int row0 = wave * 16;
    const int s0 = c * 64;

    // gate scalars for this chunk
    if (tid < 64) {
        const int bs = b * S_ + s0 + tid;
        const float4 gv = *(const float4*)(Graw + (size_t)bs * 32 + h * 4);
        const float g0 = gv.x + bg[h * 4 + 0];
        const float g1 = gv.y + bg[h * 4 + 1];
        const float g2 = gv.z + bg[h * 4 + 2];
        const float g3 = gv.w + bg[h * 4 + 3];
        const float gf  = 1.f / (1.f + expf(-g0));
        const float gu  = 1.f / (1.f + expf(-g1));
        const float wm0 = 1.f / (1.f + expf(-(g2 - g3)));
        const float wm1 = 1.f - wm0;
        const float a0 = 1.f / (1.f + expf(-logit_alphas[h * 2 + 0]));
        const float a1 = 1.f / (1.f + expf(-logit_alphas[h * 2 + 1]));
        sScal[tid][0] = a0 * gf; sScal[tid][1] = a1 * gf;
        sScal[tid][2] = wm0 * gu; sScal[tid][3] = wm1 * gu;
        sScal[tid][4] = wm0; sScal[tid][5] = wm1;
    }

    // load Q,K (+RoPE), V (transposed)
    for (int i = tid; i < 1024; i += 256) {
        const int r = i >> 4, c4 = (i & 15) * 4;
        const int s = s0 + r;
        const size_t g = ((size_t)(b * S_ + s)) * D_ + h * HD_ + c4;
        float4 q4 = *(const float4*)(Q + g);
        float4 k4 = *(const float4*)(K + g);
        float4 v4 = *(const float4*)(V + g);
        const float2 t0 = rope[s * 32 + (c4 >> 1)];
        const float2 t1 = rope[s * 32 + (c4 >> 1) + 1];
        bf16x4 qs = { f2bf(q4.x * t0.x - q4.y * t0.y), f2bf(q4.x * t0.y + q4.y * t0.x),
                      f2bf(q4.z * t1.x - q4.w * t1.y), f2bf(q4.z * t1.y + q4.w * t1.x) };
        bf16x4 ks = { f2bf(k4.x * t0.x - k4.y * t0.y), f2bf(k4.x * t0.y + k4.y * t0.x),
                      f2bf(k4.z * t1.x - k4.w * t1.y), f2bf(k4.z * t1.y + k4.w * t1.x) };
        *(bf16x4*)&sQ[r * 72 + c4] = qs;
        *(bf16x4*)&sK[r * 72 + c4] = ks;
        sVT[(c4 + 0) * 72 + r] = f2bf(v4.x);
        sVT[(c4 + 1) * 72 + r] = f2bf(v4.y);
        sVT[(c4 + 2) * 72 + r] = f2bf(v4.z);
        sVT[(c4 + 3) * 72 + r] = f2bf(v4.w);
    }
    __syncthreads();

    // per-m log2-cumprod + scale vectors; export qs/R
    if (wave < 2) {
        const int m = wave;
        const float ret = sScal[lane][m];
        float pre = log2f(ret);
        #pragma unroll
        for (int off = 1; off < 64; off <<= 1) {
            const float u = __shfl_up(pre, off);
            if (lane >= off) pre += u;
        }
        sLc[m][lane] = pre;
        const float lR = __shfl(pre, 63);
        const float ks = sScal[lane][2 + m] * exp2f(lR - pre);
        const float qs = sScal[lane][4 + m] * exp2f(pre);
        sKs[m][lane] = ks;
        sQs[m][lane] = qs;
        SQS[(size_t)blockIdx.x * 128 + m * 64 + lane] = qs;
        if (lane == 63) SRb[blockIdx.x * 2 + m] = exp2f(lR);
    }
    __syncthreads();

    // scaled-K transpose
    {
        const int task = tid >> 1, halfd = tid & 1;
        const int m = task >> 6, tau = task & 63;
        const float ksc = sKs[m][tau];
        #pragma unroll
        for (int dd = halfd * 32; dd < halfd * 32 + 32; dd += 8) {
            bf16x8 kr = *(const bf16x8*)&sK[tau * 72 + dd];
            #pragma unroll
            for (int j = 0; j < 8; ++j)
                sKscT[m][(dd + j) * 72 + tau] = f2bf(bf2f(kr[j]) * ksc);
        }
    }

    // QK^T
    f32x4 accS[4], accO[4];
    #pragma unroll
    for (int cb = 0; cb < 4; ++cb) { accS[cb] = (f32x4)0.f; accO[cb] = (f32x4)0.f; }
    #pragma unroll
    for (int kk = 0; kk < 2; ++kk) {
        const int kb = kk * 32 + lgrp * 8;
        bf16x8 a = *(const bf16x8*)&sQ[(row0 + lrow) * 72 + kb];
        #pragma unroll
        for (int cb = 0; cb < 4; ++cb) {
            bf16x8 bb = *(const bf16x8*)&sK[(cb * 16 + lrow) * 72 + kb];
            accS[cb] = MFMA16(a, bb, accS[cb]);
        }
    }

    // P build (log-space decay ratios, causal mask, gates)
    #pragma unroll
    for (int r = 0; r < 4; ++r) {
        const int t = row0 + lgrp * 4 + r;
        const float wm0 = sScal[t][4], wm1 = sScal[t][5];
        const float lc0t = sLc[0][t],  lc1t = sLc[1][t];
        #pragma unroll
        for (int cb = 0; cb < 4; ++cb) {
            const int tau = cb * 16 + lrow;
            float p = 0.f;
            if (tau <= t) {
                const float c0 = wm0 * sScal[tau][2] * exp2f(lc0t - sLc[0][tau]);
                const float c1 = wm1 * sScal[tau][3] * exp2f(lc1t - sLc[1][tau]);
                p = accS[cb][r] * (c0 + c1);
            }
            sP[t * 72 + tau] = f2bf(p);
        }
    }

    // O_intra = P @ V  -> OI (fp32)
    #pragma unroll
    for (int kk = 0; kk < 2; ++kk) {
        const int kb = kk * 32 + lgrp * 8;
        bf16x8 a = *(const bf16x8*)&sP[(row0 + lrow) * 72 + kb];
        #pragma unroll
        for (int cb = 0; cb < 4; ++cb) {
            bf16x8 bb = *(const bf16x8*)&sVT[(cb * 16 + lrow) * 72 + kb];
            accO[cb] = MFMA16(a, bb, accO[cb]);
        }
    }
    #pragma unroll
    for (int cb = 0; cb < 4; ++cb) {
        #pragma unroll
        for (int r = 0; r < 4; ++r) {
            const int t = row0 + lgrp * 4 + r;
            OI[((size_t)(b * S_ + s0 + t)) * D_ + h * HD_ + cb * 16 + lrow] = accO[cb][r];
        }
    }

    __syncthreads();   // sKscT writes complete (cross-wave)

    // U_m = VT @ Ksc_m  -> Ubuf (fp32), layout [bhc][m][e*64+d]
    #pragma unroll
    for (int m = 0; m < 2; ++m) {
        f32x4 accU[4];
        #pragma unroll
        for (int db = 0; db < 4; ++db) accU[db] = (f32x4)0.f;
        #pragma unroll
        for (int kk = 0; kk < 2; ++kk) {
            const int kb = kk * 32 + lgrp * 8;
            bf16x8 a = *(const bf16x8*)&sVT[(row0 + lrow) * 72 + kb];
            #pragma unroll
            for (int db = 0; db < 4; ++db) {
                bf16x8 bb = *(const bf16x8*)&sKscT[m][(db * 16 + lrow) * 72 + kb];
                accU[db] = MFMA16(a, bb, accU[db]);
            }
        }
        float* ub = Ubuf + ((size_t)blockIdx.x * 2 + m) * 4096;
        #pragma unroll
        for (int db = 0; db < 4; ++db) {
            #pragma unroll
            for (int r = 0; r < 4; ++r) {
                const int e = row0 + lgrp * 4 + r;
                ub[e * 64 + db * 16 + lrow] = accU[db][r];
            }
        }
    }
}

// ---------------------------------------------------------------------------
// Kernel B: state prefix scan.  Elementwise over (bh,m,e,d); each thread runs
// the 16-step chain, replacing Ubuf[c] with the EXCLUSIVE prefix state.
// ---------------------------------------------------------------------------
__global__ __launch_bounds__(256) void state_prefix(
    float* __restrict__ Ubuf, const float* __restrict__ SRb)
{
    const int idx = blockIdx.x * 256 + threadIdx.x;  // 0..262143
    const int ed = idx & 4095;
    const int m  = (idx >> 12) & 1;
    const int bh = idx >> 13;
    float s = 0.f;
    #pragma unroll
    for (int c = 0; c < 16; ++c) {
        const int bhc = bh * 16 + c;
        float* p = Ubuf + ((size_t)bhc * 2 + m) * 4096 + ed;
        const float u = *p;
        *p = s;
        s = SRb[bhc * 2 + m] * s + u;
    }
}

// ---------------------------------------------------------------------------
// Kernel C: O = OI + (qs-scaled Q) @ [S0;S1]  -> Obf (bf16)
// ---------------------------------------------------------------------------
__global__ __launch_bounds__(256) void chunk_inter(
    const float* __restrict__ Q, const float2* __restrict__ rope,
    const float* __restrict__ Ubuf, const float* __restrict__ SQS,
    const float* __restrict__ OI, short* __restrict__ Obf)
{
    __shared__ __align__(16) short sQ [64 * 72];
    __shared__ __align__(16) short sST[2][64 * 72];   // state^T [m][e][d] bf16
    __shared__ float sQs[2][64];

    const int tid  = threadIdx.x;
    const int wave = tid >> 6, lane = tid & 63;
    const int lrow = lane & 15, lgrp = lane >> 4;
    const int c  = blockIdx.x & 15;
    const int bh = blockIdx.x >> 4;
    const int h = bh & 7, b = bh >> 3;
    const int row0 = wave * 16;
    const int s0 = c * 64;

    if (tid < 128) sQs[tid >> 6][tid & 63] = SQS[(size_t)blockIdx.x * 128 + tid];

    // load Q with RoPE
    for (int i = tid; i < 1024; i += 256) {
        const int r = i >> 4, c4 = (i & 15) * 4;
        const int s = s0 + r;
        const size_t g = ((size_t)(b * S_ + s)) * D_ + h * HD_ + c4;
        float4 q4 = *(const float4*)(Q + g);
        const float2 t0 = rope[s * 32 + (c4 >> 1)];
        const float2 t1 = rope[s * 32 + (c4 >> 1) + 1];
        bf16x4 qs = { f2bf(q4.x * t0.x - q4.y * t0.y), f2bf(q4.x * t0.y + q4.y * t0.x),
                      f2bf(q4.z * t1.x - q4.w * t1.y), f2bf(q4.z * t1.y + q4.w * t1.x) };
        *(bf16x4*)&sQ[r * 72 + c4] = qs;
    }
    // load exclusive-prefix state -> bf16 LDS
    for (int i = tid; i < 2048; i += 256) {
        const int m = i >> 10, rem = i & 1023;
        const int e = rem >> 4, d4 = (rem & 15) * 4;
        float4 v = *(const float4*)(Ubuf + ((size_t)blockIdx.x * 2 + m) * 4096 + e * 64 + d4);
        bf16x4 o = { f2bf(v.x), f2bf(v.y), f2bf(v.z), f2bf(v.w) };
        *(bf16x4*)&sST[m][e * 72 + d4] = o;
    }
    __syncthreads();

    f32x4 accO[4];
    #pragma unroll
    for (int cb = 0; cb < 4; ++cb) accO[cb] = (f32x4)0.f;
    #pragma unroll
    for (int kk = 0; kk < 4; ++kk) {
        const int k0 = kk * 32 + lgrp * 8;
        const int m = k0 >> 6, d0 = k0 & 63;
        const float qs = sQs[m][row0 + lrow];
        bf16x8 qr = *(const bf16x8*)&sQ[(row0 + lrow) * 72 + d0];
        bf16x8 a;
        #pragma unroll
        for (int j = 0; j < 8; ++j) a[j] = f2bf(bf2f(qr[j]) * qs);
        #pragma unroll
        for (int cb = 0; cb < 4; ++cb) {
            bf16x8 bb = *(const bf16x8*)&sST[m][(cb * 16 + lrow) * 72 + d0];
            accO[cb] = MFMA16(a, bb, accO[cb]);
        }
    }

    #pragma unroll
    for (int cb = 0; cb < 4; ++cb) {
        #pragma unroll
        for (int r = 0; r < 4; ++r) {
            const int t = row0 + lgrp * 4 + r;
            const size_t addr = ((size_t)(b * S_ + s0 + t)) * D_ + h * HD_ + cb * 16 + lrow;
            Obf[addr] = f2bf(OI[addr] + accO[cb][r]);
        }
    }
}

// ---------------------------------------------------------------------------
// Kernel 4: MFMA output GEMM:  Y = Obf @ Wobf^T + bo + x   (residual fused)
// ---------------------------------------------------------------------------
__global__ __launch_bounds__(256) void mfma_out(
    const short* __restrict__ Abf, const short* __restrict__ Wobf,
    const float* __restrict__ bo, const float* __restrict__ xres,
    float* __restrict__ Y)
{
    __shared__ __align__(16) short sA[128 * 72];
    __shared__ __align__(16) short sB[128 * 72];
    const int tid = threadIdx.x;
    const int lane = tid & 63;
    const int wave = tid >> 6;
    const int lrow = lane & 15, lgrp = lane >> 4;
    const int wr = wave >> 1, wc = wave & 1;
    const int n0 = blockIdx.x * 128, m0 = blockIdx.y * 128;
    const int srow = tid >> 3, sseg = tid & 7;

    f32x4 acc[4][4];
    #pragma unroll
    for (int i = 0; i < 4; ++i)
        #pragma unroll
        for (int j = 0; j < 4; ++j) acc[i][j] = (f32x4)0.f;

    float4 pa[4], pb[4];
    #pragma unroll
    for (int i = 0; i < 4; ++i) {
        pa[i] = *(const float4*)(Abf  + (size_t)(m0 + srow + i * 32) * 512 + sseg * 8);
        pb[i] = *(const float4*)(Wobf + (size_t)(n0 + srow + i * 32) * 512 + sseg * 8);
    }

    for (int step = 0; step < 8; ++step) {
        #pragma unroll
        for (int i = 0; i < 4; ++i) {
            *(float4*)&sA[(srow + i * 32) * 72 + sseg * 8] = pa[i];
            *(float4*)&sB[(srow + i * 32) * 72 + sseg * 8] = pb[i];
        }
        __syncthreads();
        if (step < 7) {
            const int kt = (step + 1) * 64;
            #pragma unroll
            for (int i = 0; i < 4; ++i) {
                pa[i] = *(const float4*)(Abf  + (size_t)(m0 + srow + i * 32) * 512 + kt + sseg * 8);
                pb[i] = *(const float4*)(Wobf + (size_t)(n0 + srow + i * 32) * 512 + kt + sseg * 8);
            }
        }
        #pragma unroll
        for (int kk = 0; kk < 2; ++kk) {
            const int kb = kk * 32 + lgrp * 8;
            bf16x8 af[4], bfr[4];
            #pragma unroll
            for (int mi = 0; mi < 4; ++mi)
                af[mi] = *(const bf16x8*)&sA[(wr * 64 + mi * 16 + lrow) * 72 + kb];
            #pragma unroll
            for (int ni = 0; ni < 4; ++ni)
                bfr[ni] = *(const bf16x8*)&sB[(wc * 64 + ni * 16 + lrow) * 72 + kb];
            #pragma unroll
            for (int mi = 0; mi < 4; ++mi)
                #pragma unroll
                for (int ni = 0; ni < 4; ++ni)
                    acc[mi][ni] = MFMA16(af[mi], bfr[ni], acc[mi][ni]);
        }
        __syncthreads();
    }

    #pragma unroll
    for (int mi = 0; mi < 4; ++mi) {
        #pragma unroll
        for (int ni = 0; ni < 4; ++ni) {
            const int col = n0 + wc * 64 + ni * 16 + lrow;
            const float bb = bo[col];
            #pragma unroll
            for (int j = 0; j < 4; ++j) {
                const int row = m0 + wr * 64 + mi * 16 + lgrp * 4 + j;
                Y[(size_t)row * 512 + col] = acc[mi][ni][j] + bb + xres[(size_t)row * 512 + col];
            }
        }
    }
}

// ---------------------------------------------------------------------------
// Kernel 5: LayerNorm over D=512. One wave per row; 8 elems per lane.
// ---------------------------------------------------------------------------
__global__ __launch_bounds__(256) void ln_kernel(
    const float* __restrict__ Y, const float* __restrict__ ln_w,
    const float* __restrict__ ln_b, float* __restrict__ out)
{
    const int wave = threadIdx.x >> 6;
    const int lane = threadIdx.x & 63;
    const int row = blockIdx.x * 4 + wave;   // 0..4095
    const float* yp = Y + (size_t)row * 512;

    float4 v0 = *(const float4*)(yp + lane * 8);
    float4 v1 = *(const float4*)(yp + lane * 8 + 4);
    float s  = v0.x + v0.y + v0.z + v0.w + v1.x + v1.y + v1.z + v1.w;
    float sq = v0.x*v0.x + v0.y*v0.y + v0.z*v0.z + v0.w*v0.w
             + v1.x*v1.x + v1.y*v1.y + v1.z*v1.z + v1.w*v1.w;
    #pragma unroll
    for (int off = 32; off; off >>= 1) {
        s  += __shfl_xor(s,  off);
        sq += __shfl_xor(sq, off);
    }
    const float mu  = s * (1.f / 512.f);
    const float var = sq * (1.f / 512.f) - mu * mu;
    const float inv = rsqrtf(var + EPS_);

    float4 w0 = *(const float4*)(ln_w + lane * 8);
    float4 w1 = *(const float4*)(ln_w + lane * 8 + 4);
    float4 b0 = *(const float4*)(ln_b + lane * 8);
    float4 b1 = *(const float4*)(ln_b + lane * 8 + 4);
    float4 o0, o1;
    o0.x = (v0.x - mu) * inv * w0.x + b0.x;
    o0.y = (v0.y - mu) * inv * w0.y + b0.y;
    o0.z = (v0.z - mu) * inv * w0.z + b0.z;
    o0.w = (v0.w - mu) * inv * w0.w + b0.w;
    o1.x = (v1.x - mu) * inv * w1.x + b1.x;
    o1.y = (v1.y - mu) * inv * w1.y + b1.y;
    o1.z = (v1.z - mu) * inv * w1.z + b1.z;
    o1.w = (v1.w - mu) * inv * w1.w + b1.w;
    *(float4*)(out + (size_t)row * 512 + lane * 8)     = o0;
    *(float4*)(out + (size_t)row * 512 + lane * 8 + 4) = o1;
}

// ---------------------------------------------------------------------------
extern "C" void kernel_launch(void* const* d_in, const int* in_sizes, int n_in,
                              void* d_out, int out_size, void* d_ws, size_t ws_size,
                              hipStream_t stream)
{
    const float* x   = (const float*)d_in[0];
    const float* Wq  = (const float*)d_in[1];
    const float* Wk  = (const float*)d_in[2];
    const float* Wv  = (const float*)d_in[3];
    const float* Wo  = (const float*)d_in[4];
    const float* bo  = (const float*)d_in[5];
    const float* Wg  = (const float*)d_in[6];
    const float* bg  = (const float*)d_in[7];
    const float* la  = (const float*)d_in[8];
    const float* lnw = (const float*)d_in[9];
    const float* lnb = (const float*)d_in[10];

    const size_t NQ = (size_t)B_ * S_ * D_;          // 2,097,152
    float* Qraw = (float*)d_ws;
    float* Kraw = Qraw + NQ;
    float* Vws  = Kraw + NQ;
    float* Graw = Vws + NQ;                          // 131072
    float* Ybuf = Graw + (size_t)B_ * S_ * 32;       // 2,097,152 (also OI)
    float* ROPE = Ybuf + NQ;                         // 65536 (float2 x 32768)
    float* Ubuf = ROPE + 65536;                      // 512*2*4096 = 4,194,304
    float* SQS  = Ubuf + (size_t)512 * 2 * 4096;     // 512*128 = 65536
    float* SRb  = SQS + 65536;                       // 1024
    short* xbf  = (short*)(SRb + 1024);
    short* Wcat = xbf + NQ;                          // 1664*512
    short* Wobf = Wcat + (size_t)1664 * 512;
    short* Obf  = Wobf + (size_t)512 * 512;

    // 0) dtype conversion / weight packing + rope table
    convert_inputs<<<1568, 256, 0, stream>>>(x, Wq, Wk, Wv, Wg, Wo, xbf, Wcat, Wobf);
    rope_table<<<128, 256, 0, stream>>>((float2*)ROPE);
    // 1) projections (MFMA)
    mfma_proj<<<dim3(13, 32), 256, 0, stream>>>(xbf, Wcat, Qraw, Kraw, Vws, Graw);
    // 2) per-chunk intra + state deltas
    chunk_intra<<<512, 256, 0, stream>>>(Qraw, Kraw, Vws, Graw, bg, la,
                                         (const float2*)ROPE, Ybuf, Ubuf, SQS, SRb);
    // 3) state prefix scan (exclusive)
    state_prefix<<<1024, 256, 0, stream>>>(Ubuf, SRb);
    // 4) inter-chunk output
    chunk_inter<<<512, 256, 0, stream>>>(Qraw, (const float2*)ROPE, Ubuf, SQS, Ybuf, Obf);
    // 5) output projection + residual (MFMA)
    mfma_out<<<dim3(4, 32), 256, 0, stream>>>(Obf, Wobf, bo, x, Ybuf);
    // 6) layernorm
    ln_kernel<<<1024, 256, 0, stream>>>(Ybuf, lnw, lnb, (float*)d_out);
}

// Round 6
// 173.867 us; speedup vs baseline: 4.1121x; 1.0609x over previous
//
#include <hip/hip_runtime.h>
#include <hip/hip_bf16.h>
#include <math.h>

// Problem constants
#define B_  4
#define S_  1024
#define D_  512
#define H_  8
#define HD_ 64
#define EPS_ 1e-5f

typedef __attribute__((ext_vector_type(8))) short  bf16x8;
typedef __attribute__((ext_vector_type(4))) short  bf16x4;
typedef __attribute__((ext_vector_type(4))) float  f32x4;

#define MFMA16(a, b, c) __builtin_amdgcn_mfma_f32_16x16x32_bf16((a), (b), (c), 0, 0, 0)

__device__ __forceinline__ float bf2f(short u) {
    union { unsigned int i; float f; } v;
    v.i = ((unsigned int)(unsigned short)u) << 16;
    return v.f;
}
__device__ __forceinline__ short f2bf(float f) {
    __hip_bfloat16 h = __float2bfloat16(f);
    return *reinterpret_cast<short*>(&h);
}

// ---------------------------------------------------------------------------
// Kernel 0: convert x -> bf16, pack [Wq;Wk;Wv;Wg] -> Wcat bf16 (1664x512,
// zero-padded), Wo -> bf16, build rope table {cos,sin}.
// ---------------------------------------------------------------------------
__global__ __launch_bounds__(256) void convert_inputs(
    const float* __restrict__ x,
    const float* __restrict__ Wq, const float* __restrict__ Wk,
    const float* __restrict__ Wv, const float* __restrict__ Wg,
    const float* __restrict__ Wo,
    short* __restrict__ xbf, short* __restrict__ Wcat, short* __restrict__ Wobf,
    float2* __restrict__ rope)
{
    const int id = blockIdx.x * 256 + threadIdx.x;   // 0..434175
    if (id < 262144) {                               // x: 2,097,152 elems
        const size_t e = (size_t)id * 8;
        float4 v0 = *(const float4*)(x + e);
        float4 v1 = *(const float4*)(x + e + 4);
        bf16x8 o = { f2bf(v0.x), f2bf(v0.y), f2bf(v0.z), f2bf(v0.w),
                     f2bf(v1.x), f2bf(v1.y), f2bf(v1.z), f2bf(v1.w) };
        *(bf16x8*)(xbf + e) = o;
    } else if (id < 368640) {                        // Wcat: 1664*512 elems
        const int i2 = id - 262144;
        const int row = i2 >> 6;
        const int c8 = (i2 & 63) * 8;
        const float* s = nullptr;
        if (row < 512)       s = Wq + (size_t)row * 512 + c8;
        else if (row < 1024) s = Wk + (size_t)(row - 512) * 512 + c8;
        else if (row < 1536) s = Wv + (size_t)(row - 1024) * 512 + c8;
        else if (row < 1568) s = Wg + (size_t)(row - 1536) * 512 + c8;
        bf16x8 o = (bf16x8)0;
        if (s) {
            float4 v0 = *(const float4*)(s);
            float4 v1 = *(const float4*)(s + 4);
            o = bf16x8{ f2bf(v0.x), f2bf(v0.y), f2bf(v0.z), f2bf(v0.w),
                        f2bf(v1.x), f2bf(v1.y), f2bf(v1.z), f2bf(v1.w) };
        }
        *(bf16x8*)(Wcat + (size_t)row * 512 + c8) = o;
    } else if (id < 401408) {                        // Wo: 262,144 elems
        const int i3 = id - 368640;
        const size_t e = (size_t)i3 * 8;
        float4 v0 = *(const float4*)(Wo + e);
        float4 v1 = *(const float4*)(Wo + e + 4);
        bf16x8 o = { f2bf(v0.x), f2bf(v0.y), f2bf(v0.z), f2bf(v0.w),
                     f2bf(v1.x), f2bf(v1.y), f2bf(v1.z), f2bf(v1.w) };
        *(bf16x8*)(Wobf + e) = o;
    } else {                                         // rope: 32768 entries
        const int i4 = id - 401408;
        const int s = i4 >> 5, i = i4 & 31;
        const float inv = exp2f(-(float)i * (13.287712379549449f / 32.0f));
        float sn, cs;
        sincosf((float)s * inv, &sn, &cs);
        rope[i4] = make_float2(cs, sn);
    }
}

// ---------------------------------------------------------------------------
// Kernel 1: MFMA projection GEMM.  [Qbf|Kbf|Vbf] (bf16, LDS-staged coalesced
// writes) + Graw (fp32, tiny).  XCD-affine swizzle: all 13 n-tiles of an
// m-panel land on one XCD (p%8) so the A-panel is fetched once per XCD group.
// ---------------------------------------------------------------------------
__global__ __launch_bounds__(256) void mfma_proj(
    const short* __restrict__ Abf, const short* __restrict__ Wcat,
    short* __restrict__ Qbf, short* __restrict__ Kbf,
    short* __restrict__ Vbf, float* __restrict__ Graw)
{
    __shared__ __align__(16) short sAB[2 * 128 * 72];  // also output staging
    short* sA = sAB;
    short* sB = sAB + 128 * 72;

    const int p = blockIdx.x;              // 0..415
    const int xcd = p & 7, slot = p >> 3;  // 52 slots per XCD = 4 m-panels x 13
    const int by = xcd + 8 * (slot / 13);
    const int bx = slot % 13;
    const int n0 = bx * 128, m0 = by * 128;

    const int tid = threadIdx.x;
    const int lane = tid & 63, wave = tid >> 6;
    const int lrow = lane & 15, lgrp = lane >> 4;
    const int wr = wave >> 1, wc = wave & 1;
    const int srow = tid >> 3, sseg = tid & 7;

    f32x4 acc[4][4];
    #pragma unroll
    for (int i = 0; i < 4; ++i)
        #pragma unroll
        for (int j = 0; j < 4; ++j) acc[i][j] = (f32x4)0.f;

    float4 pa[4], pb[4];
    #pragma unroll
    for (int i = 0; i < 4; ++i) {
        pa[i] = *(const float4*)(Abf  + (size_t)(m0 + srow + i * 32) * 512 + sseg * 8);
        pb[i] = *(const float4*)(Wcat + (size_t)(n0 + srow + i * 32) * 512 + sseg * 8);
    }

    for (int step = 0; step < 8; ++step) {
        #pragma unroll
        for (int i = 0; i < 4; ++i) {
            *(float4*)&sA[(srow + i * 32) * 72 + sseg * 8] = pa[i];
            *(float4*)&sB[(srow + i * 32) * 72 + sseg * 8] = pb[i];
        }
        __syncthreads();
        if (step < 7) {
            const int kt = (step + 1) * 64;
            #pragma unroll
            for (int i = 0; i < 4; ++i) {
                pa[i] = *(const float4*)(Abf  + (size_t)(m0 + srow + i * 32) * 512 + kt + sseg * 8);
                pb[i] = *(const float4*)(Wcat + (size_t)(n0 + srow + i * 32) * 512 + kt + sseg * 8);
            }
        }
        #pragma unroll
        for (int kk = 0; kk < 2; ++kk) {
            const int kb = kk * 32 + lgrp * 8;
            bf16x8 af[4], bfr[4];
            #pragma unroll
            for (int mi = 0; mi < 4; ++mi)
                af[mi] = *(const bf16x8*)&sA[(wr * 64 + mi * 16 + lrow) * 72 + kb];
            #pragma unroll
            for (int ni = 0; ni < 4; ++ni)
                bfr[ni] = *(const bf16x8*)&sB[(wc * 64 + ni * 16 + lrow) * 72 + kb];
            #pragma unroll
            for (int mi = 0; mi < 4; ++mi)
                #pragma unroll
                for (int ni = 0; ni < 4; ++ni)
                    acc[mi][ni] = MFMA16(af[mi], bfr[ni], acc[mi][ni]);
        }
        __syncthreads();
    }

    if (n0 < 1536) {
        // stage 128x128 bf16 tile in LDS (stride 136 keeps 16B alignment),
        // then write full contiguous 256B rows to global.
        short* stg = sAB;
        #pragma unroll
        for (int mi = 0; mi < 4; ++mi)
            #pragma unroll
            for (int ni = 0; ni < 4; ++ni)
                #pragma unroll
                for (int j = 0; j < 4; ++j) {
                    const int rl = wr * 64 + mi * 16 + lgrp * 4 + j;
                    const int cl = wc * 64 + ni * 16 + lrow;
                    stg[rl * 136 + cl] = f2bf(acc[mi][ni][j]);
                }
        __syncthreads();
        short* dst; int dstoff;
        if (n0 < 512)       { dst = Qbf; dstoff = n0; }
        else if (n0 < 1024) { dst = Kbf; dstoff = n0 - 512; }
        else                { dst = Vbf; dstoff = n0 - 1024; }
        #pragma unroll
        for (int it = 0; it < 8; ++it) {
            const int c8 = tid + it * 256;         // 0..2047
            const int row = c8 >> 4, co = (c8 & 15) * 8;
            *(bf16x8*)(dst + (size_t)(m0 + row) * 512 + dstoff + co) =
                *(const bf16x8*)&stg[row * 136 + co];
        }
    } else {
        // G tile: only cols 0..31 valid (fp32, tiny)
        #pragma unroll
        for (int mi = 0; mi < 4; ++mi)
            #pragma unroll
            for (int ni = 0; ni < 2; ++ni) {
                const int col = wc * 64 + ni * 16 + lrow;
                if (col < 32) {
                    #pragma unroll
                    for (int j = 0; j < 4; ++j) {
                        const int row = m0 + wr * 64 + mi * 16 + lgrp * 4 + j;
                        Graw[(size_t)row * 32 + col] = acc[mi][ni][j];
                    }
                }
            }
    }
}

// ---------------------------------------------------------------------------
// Kernel A: per-chunk state delta.  Grid 512 = (b,h,chunk).
// U_m = V^T @ Ksc_m  -> Ubuf (bf16), chunk decay R_m -> SRb.
// ---------------------------------------------------------------------------
__global__ __launch_bounds__(256) void chunk_delta(
    const short* __restrict__ Kbf, const short* __restrict__ Vbf,
    const float* __restrict__ Graw, const float* __restrict__ bg,
    const float* __restrict__ logit_alphas, const float2* __restrict__ rope,
    short* __restrict__ Ubuf, float* __restrict__ SRb)
{
    __shared__ __align__(16) short sK [64 * 72];
    __shared__ __align__(16) short sVT[64 * 72];       // VT[e][tau]
    __shared__ __align__(16) short sKscT[2][64 * 72];  // KscT[m][d][tau]
    __shared__ float sScal[64][8];
    __shared__ float sKs[2][64];

    const int tid  = threadIdx.x;
    const int wave = tid >> 6, lane = tid & 63;
    const int lrow = lane & 15, lgrp = lane >> 4;
    const int c  = blockIdx.x & 15;
    const int bh = blockIdx.x >> 4;
    const int h = bh & 7, b = bh >> 3;
    const int row0 = wave * 16;
    const int s0 = c * 64;

    if (tid < 64) {
        const int bs = b * S_ + s0 + tid;
        const float4 gv = *(const float4*)(Graw + (size_t)bs * 32 + h * 4);
        const float g0 = gv.x + bg[h * 4 + 0];
        const float g1 = gv.y + bg[h * 4 + 1];
        const float g2 = gv.z + bg[h * 4 + 2];
        const float g3 = gv.w + bg[h * 4 + 3];
        const float gf  = 1.f / (1.f + expf(-g0));
        const float gu  = 1.f / (1.f + expf(-g1));
        const float wm0 = 1.f / (1.f + expf(-(g2 - g3)));
        const float a0 = 1.f / (1.f + expf(-logit_alphas[h * 2 + 0]));
        const float a1 = 1.f / (1.f + expf(-logit_alphas[h * 2 + 1]));
        sScal[tid][0] = a0 * gf; sScal[tid][1] = a1 * gf;
        sScal[tid][2] = wm0 * gu; sScal[tid][3] = (1.f - wm0) * gu;
    }

    // load K (rope) + V (transposed), bf16 direct
    #pragma unroll
    for (int it = 0; it < 2; ++it) {
        const int i = tid + it * 256;             // 0..511
        const int r = i >> 3, c8 = (i & 7) * 8;
        const int s = s0 + r;
        const size_t g = ((size_t)(b * S_ + s)) * 512 + h * 64 + c8;
        bf16x8 k8 = *(const bf16x8*)(Kbf + g);
        bf16x8 v8 = *(const bf16x8*)(Vbf + g);
        bf16x8 ko;
        #pragma unroll
        for (int j = 0; j < 4; ++j) {
            const float2 t = rope[s * 32 + (c8 >> 1) + j];
            const float kx = bf2f(k8[2 * j]), ky = bf2f(k8[2 * j + 1]);
            ko[2 * j]     = f2bf(kx * t.x - ky * t.y);
            ko[2 * j + 1] = f2bf(kx * t.y + ky * t.x);
        }
        *(bf16x8*)&sK[r * 72 + c8] = ko;
        #pragma unroll
        for (int j = 0; j < 8; ++j) sVT[(c8 + j) * 72 + r] = v8[j];
    }
    __syncthreads();

    if (wave < 2) {
        const int m = wave;
        float pre = log2f(sScal[lane][m]);
        #pragma unroll
        for (int off = 1; off < 64; off <<= 1) {
            const float u = __shfl_up(pre, off);
            if (lane >= off) pre += u;
        }
        const float lR = __shfl(pre, 63);
        sKs[m][lane] = sScal[lane][2 + m] * exp2f(lR - pre);
        if (lane == 63) SRb[blockIdx.x * 2 + m] = exp2f(lR);
    }
    __syncthreads();

    {   // scaled-K transpose
        const int task = tid >> 1, halfd = tid & 1;
        const int m = task >> 6, tau = task & 63;
        const float ksc = sKs[m][tau];
        #pragma unroll
        for (int dd = halfd * 32; dd < halfd * 32 + 32; dd += 8) {
            bf16x8 kr = *(const bf16x8*)&sK[tau * 72 + dd];
            #pragma unroll
            for (int j = 0; j < 8; ++j)
                sKscT[m][(dd + j) * 72 + tau] = f2bf(bf2f(kr[j]) * ksc);
        }
    }
    __syncthreads();

    #pragma unroll
    for (int m = 0; m < 2; ++m) {
        f32x4 accU[4];
        #pragma unroll
        for (int db = 0; db < 4; ++db) accU[db] = (f32x4)0.f;
        #pragma unroll
        for (int kk = 0; kk < 2; ++kk) {
            const int kb = kk * 32 + lgrp * 8;
            bf16x8 a = *(const bf16x8*)&sVT[(row0 + lrow) * 72 + kb];
            #pragma unroll
            for (int db = 0; db < 4; ++db) {
                bf16x8 bb = *(const bf16x8*)&sKscT[m][(db * 16 + lrow) * 72 + kb];
                accU[db] = MFMA16(a, bb, accU[db]);
            }
        }
        short* ub = Ubuf + ((size_t)blockIdx.x * 2 + m) * 4096;
        #pragma unroll
        for (int db = 0; db < 4; ++db) {
            #pragma unroll
            for (int r = 0; r < 4; ++r) {
                const int e = row0 + lgrp * 4 + r;
                ub[e * 64 + db * 16 + lrow] = f2bf(accU[db][r]);
            }
        }
    }
}

// ---------------------------------------------------------------------------
// Kernel B: state prefix scan (bf16 in/out, fp32 running sum in registers).
// Thread per (bh,m,2 elems); replaces Ubuf[c] with the EXCLUSIVE prefix.
// ---------------------------------------------------------------------------
__global__ __launch_bounds__(256) void state_prefix(
    short* __restrict__ Ubuf, const float* __restrict__ SRb)
{
    const int idx = blockIdx.x * 256 + threadIdx.x;  // 0..131071
    const int ed2 = idx & 2047;
    const int m   = (idx >> 11) & 1;
    const int bh  = idx >> 12;
    float s0 = 0.f, s1 = 0.f;
    #pragma unroll
    for (int c = 0; c < 16; ++c) {
        const int bhc = bh * 16 + c;
        short* p = Ubuf + ((size_t)bhc * 2 + m) * 4096 + ed2 * 2;
        const float R = SRb[bhc * 2 + m];
        const short2 u = *(const short2*)p;
        const float u0 = bf2f(u.x), u1 = bf2f(u.y);
        *(short2*)p = make_short2(f2bf(s0), f2bf(s1));
        s0 = R * s0 + u0;
        s1 = R * s1 + u1;
    }
}

// ---------------------------------------------------------------------------
// Kernel C: full output.  O = P@V (intra) + (qs.Q) @ [S0;S1] (inter) -> Obf.
// ---------------------------------------------------------------------------
__global__ __launch_bounds__(256) void chunk_o(
    const short* __restrict__ Qbf, const short* __restrict__ Kbf,
    const short* __restrict__ Vbf, const float* __restrict__ Graw,
    const float* __restrict__ bg, const float* __restrict__ logit_alphas,
    const float2* __restrict__ rope, const short* __restrict__ Ubuf,
    short* __restrict__ Obf)
{
    __shared__ __align__(16) short sQ [64 * 72];
    __shared__ __align__(16) short sK [64 * 72];
    __shared__ __align__(16) short sVT[64 * 72];
    __shared__ __align__(16) short sP [64 * 72];
    __shared__ __align__(16) short sST[2][64 * 72];   // prefix state [m][e][d]
    __shared__ float sScal[64][8];
    __shared__ float sLc[2][64];
    __shared__ float sQs[2][64];

    const int tid  = threadIdx.x;
    const int wave = tid >> 6, lane = tid & 63;
    const int lrow = lane & 15, lgrp = lane >> 4;
    const int c  = blockIdx.x & 15;
    const int bh = blockIdx.x >> 4;
    const int h = bh & 7, b = bh >> 3;
    const int row0 = wave * 16;
    const int s0 = c * 64;

    if (tid < 64) {
        const int bs = b * S_ + s0 + tid;
        const float4 gv = *(const float4*)(Graw + (size_t)bs * 32 + h * 4);
        const float g0 = gv.x + bg[h * 4 + 0];
        const float g1 = gv.y + bg[h * 4 + 1];
        const float g2 = gv.z + bg[h * 4 + 2];
        const float g3 = gv.w + bg[h * 4 + 3];
        const float gf  = 1.f / (1.f + expf(-g0));
        const float gu  = 1.f / (1.f + expf(-g1));
        const float wm0 = 1.f / (1.f + expf(-(g2 - g3)));
        const float a0 = 1.f / (1.f + expf(-logit_alphas[h * 2 + 0]));
        const float a1 = 1.f / (1.f + expf(-logit_alphas[h * 2 + 1]));
        sScal[tid][0] = a0 * gf; sScal[tid][1] = a1 * gf;
        sScal[tid][2] = wm0 * gu; sScal[tid][3] = (1.f - wm0) * gu;
        sScal[tid][4] = wm0; sScal[tid][5] = 1.f - wm0;
    }

    // load Q,K (rope) + V (transposed)
    #pragma unroll
    for (int it = 0; it < 2; ++it) {
        const int i = tid + it * 256;
        const int r = i >> 3, c8 = (i & 7) * 8;
        const int s = s0 + r;
        const size_t g = ((size_t)(b * S_ + s)) * 512 + h * 64 + c8;
        bf16x8 q8 = *(const bf16x8*)(Qbf + g);
        bf16x8 k8 = *(const bf16x8*)(Kbf + g);
        bf16x8 v8 = *(const bf16x8*)(Vbf + g);
        bf16x8 qo, ko;
        #pragma unroll
        for (int j = 0; j < 4; ++j) {
            const float2 t = rope[s * 32 + (c8 >> 1) + j];
            const float qx = bf2f(q8[2 * j]), qy = bf2f(q8[2 * j + 1]);
            const float kx = bf2f(k8[2 * j]), ky = bf2f(k8[2 * j + 1]);
            qo[2 * j]     = f2bf(qx * t.x - qy * t.y);
            qo[2 * j + 1] = f2bf(qx * t.y + qy * t.x);
            ko[2 * j]     = f2bf(kx * t.x - ky * t.y);
            ko[2 * j + 1] = f2bf(kx * t.y + ky * t.x);
        }
        *(bf16x8*)&sQ[r * 72 + c8] = qo;
        *(bf16x8*)&sK[r * 72 + c8] = ko;
        #pragma unroll
        for (int j = 0; j < 8; ++j) sVT[(c8 + j) * 72 + r] = v8[j];
    }
    // load exclusive-prefix state (bf16, row-major [e][d])
    #pragma unroll
    for (int it = 0; it < 4; ++it) {
        const int c8 = tid + it * 256;            // 0..1023
        const int m = c8 >> 9, rem = c8 & 511;
        const int e = rem >> 3, d8 = (rem & 7) * 8;
        *(bf16x8*)&sST[m][e * 72 + d8] =
            *(const bf16x8*)(Ubuf + ((size_t)blockIdx.x * 2 + m) * 4096 + e * 64 + d8);
    }
    __syncthreads();

    if (wave < 2) {
        const int m = wave;
        float pre = log2f(sScal[lane][m]);
        #pragma unroll
        for (int off = 1; off < 64; off <<= 1) {
            const float u = __shfl_up(pre, off);
            if (lane >= off) pre += u;
        }
        sLc[m][lane] = pre;
        sQs[m][lane] = sScal[lane][4 + m] * exp2f(pre);
    }
    __syncthreads();

    // QK^T
    f32x4 accS[4], accO[4];
    #pragma unroll
    for (int cb = 0; cb < 4; ++cb) { accS[cb] = (f32x4)0.f; accO[cb] = (f32x4)0.f; }
    #pragma unroll
    for (int kk = 0; kk < 2; ++kk) {
        const int kb = kk * 32 + lgrp * 8;
        bf16x8 a = *(const bf16x8*)&sQ[(row0 + lrow) * 72 + kb];
        #pragma unroll
        for (int cb = 0; cb < 4; ++cb) {
            bf16x8 bb = *(const bf16x8*)&sK[(cb * 16 + lrow) * 72 + kb];
            accS[cb] = MFMA16(a, bb, accS[cb]);
        }
    }

    // O_inter = (qs-scaled Q) @ [S0;S1]
    #pragma unroll
    for (int kk = 0; kk < 4; ++kk) {
        const int k0 = kk * 32 + lgrp * 8;
        const int m = k0 >> 6, d0 = k0 & 63;
        const float qs = sQs[m][row0 + lrow];
        bf16x8 qr = *(const bf16x8*)&sQ[(row0 + lrow) * 72 + d0];
        bf16x8 a;
        #pragma unroll
        for (int j = 0; j < 8; ++j) a[j] = f2bf(bf2f(qr[j]) * qs);
        #pragma unroll
        for (int cb = 0; cb < 4; ++cb) {
            bf16x8 bb = *(const bf16x8*)&sST[m][(cb * 16 + lrow) * 72 + d0];
            accO[cb] = MFMA16(a, bb, accO[cb]);
        }
    }

    // P build (log-space decay ratios, causal mask, gates)
    #pragma unroll
    for (int r = 0; r < 4; ++r) {
        const int t = row0 + lgrp * 4 + r;
        const float wm0 = sScal[t][4], wm1 = sScal[t][5];
        const float lc0t = sLc[0][t],  lc1t = sLc[1][t];
        #pragma unroll
        for (int cb = 0; cb < 4; ++cb) {
            const int tau = cb * 16 + lrow;
            float p = 0.f;
            if (tau <= t) {
                const float c0 = wm0 * sScal[tau][2] * exp2f(lc0t - sLc[0][tau]);
                const float c1 = wm1 * sScal[tau][3] * exp2f(lc1t - sLc[1][tau]);
                p = accS[cb][r] * (c0 + c1);
            }
            sP[t * 72 + tau] = f2bf(p);
        }
    }

    // O_intra = P @ V (wave-local sP rows)
    #pragma unroll
    for (int kk = 0; kk < 2; ++kk) {
        const int kb = kk * 32 + lgrp * 8;
        bf16x8 a = *(const bf16x8*)&sP[(row0 + lrow) * 72 + kb];
        #pragma unroll
        for (int cb = 0; cb < 4; ++cb) {
            bf16x8 bb = *(const bf16x8*)&sVT[(cb * 16 + lrow) * 72 + kb];
            accO[cb] = MFMA16(a, bb, accO[cb]);
        }
    }

    #pragma unroll
    for (int cb = 0; cb < 4; ++cb) {
        #pragma unroll
        for (int r = 0; r < 4; ++r) {
            const int t = row0 + lgrp * 4 + r;
            Obf[((size_t)(b * S_ + s0 + t)) * D_ + h * HD_ + cb * 16 + lrow] = f2bf(accO[cb][r]);
        }
    }
}

// ---------------------------------------------------------------------------
// Kernel 4: MFMA output GEMM:  Y = Obf @ Wobf^T + bo + x  (residual fused)
// XCD-affine swizzle: 4 n-tiles of an m-panel on one XCD.
// ---------------------------------------------------------------------------
__global__ __launch_bounds__(256) void mfma_out(
    const short* __restrict__ Abf, const short* __restrict__ Wobf,
    const float* __restrict__ bo, const float* __restrict__ xres,
    float* __restrict__ Y)
{
    __shared__ __align__(16) short sA[128 * 72];
    __shared__ __align__(16) short sB[128 * 72];
    const int p = blockIdx.x;              // 0..127
    const int xcd = p & 7, slot = p >> 3;  // 16 slots = 4 m-panels x 4
    const int by = xcd + 8 * (slot >> 2);
    const int bx = slot & 3;
    const int n0 = bx * 128, m0 = by * 128;

    const int tid = threadIdx.x;
    const int lane = tid & 63, wave = tid >> 6;
    const int lrow = lane & 15, lgrp = lane >> 4;
    const int wr = wave >> 1, wc = wave & 1;
    const int srow = tid >> 3, sseg = tid & 7;

    f32x4 acc[4][4];
    #pragma unroll
    for (int i = 0; i < 4; ++i)
        #pragma unroll
        for (int j = 0; j < 4; ++j) acc[i][j] = (f32x4)0.f;

    float4 pa[4], pb[4];
    #pragma unroll
    for (int i = 0; i < 4; ++i) {
        pa[i] = *(const float4*)(Abf  + (size_t)(m0 + srow + i * 32) * 512 + sseg * 8);
        pb[i] = *(const float4*)(Wobf + (size_t)(n0 + srow + i * 32) * 512 + sseg * 8);
    }

    for (int step = 0; step < 8; ++step) {
        #pragma unroll
        for (int i = 0; i < 4; ++i) {
            *(float4*)&sA[(srow + i * 32) * 72 + sseg * 8] = pa[i];
            *(float4*)&sB[(srow + i * 32) * 72 + sseg * 8] = pb[i];
        }
        __syncthreads();
        if (step < 7) {
            const int kt = (step + 1) * 64;
            #pragma unroll
            for (int i = 0; i < 4; ++i) {
                pa[i] = *(const float4*)(Abf  + (size_t)(m0 + srow + i * 32) * 512 + kt + sseg * 8);
                pb[i] = *(const float4*)(Wobf + (size_t)(n0 + srow + i * 32) * 512 + kt + sseg * 8);
            }
        }
        #pragma unroll
        for (int kk = 0; kk < 2; ++kk) {
            const int kb = kk * 32 + lgrp * 8;
            bf16x8 af[4], bfr[4];
            #pragma unroll
            for (int mi = 0; mi < 4; ++mi)
                af[mi] = *(const bf16x8*)&sA[(wr * 64 + mi * 16 + lrow) * 72 + kb];
            #pragma unroll
            for (int ni = 0; ni < 4; ++ni)
                bfr[ni] = *(const bf16x8*)&sB[(wc * 64 + ni * 16 + lrow) * 72 + kb];
            #pragma unroll
            for (int mi = 0; mi < 4; ++mi)
                #pragma unroll
                for (int ni = 0; ni < 4; ++ni)
                    acc[mi][ni] = MFMA16(af[mi], bfr[ni], acc[mi][ni]);
        }
        __syncthreads();
    }

    #pragma unroll
    for (int mi = 0; mi < 4; ++mi) {
        #pragma unroll
        for (int ni = 0; ni < 4; ++ni) {
            const int col = n0 + wc * 64 + ni * 16 + lrow;
            const float bb = bo[col];
            #pragma unroll
            for (int j = 0; j < 4; ++j) {
                const int row = m0 + wr * 64 + mi * 16 + lgrp * 4 + j;
                Y[(size_t)row * 512 + col] = acc[mi][ni][j] + bb + xres[(size_t)row * 512 + col];
            }
        }
    }
}

// ---------------------------------------------------------------------------
// Kernel 5: LayerNorm over D=512. One wave per row; 8 elems per lane.
// ---------------------------------------------------------------------------
__global__ __launch_bounds__(256) void ln_kernel(
    const float* __restrict__ Y, const float* __restrict__ ln_w,
    const float* __restrict__ ln_b, float* __restrict__ out)
{
    const int wave = threadIdx.x >> 6;
    const int lane = threadIdx.x & 63;
    const int row = blockIdx.x * 4 + wave;   // 0..4095
    const float* yp = Y + (size_t)row * 512;

    float4 v0 = *(const float4*)(yp + lane * 8);
    float4 v1 = *(const float4*)(yp + lane * 8 + 4);
    float s  = v0.x + v0.y + v0.z + v0.w + v1.x + v1.y + v1.z + v1.w;
    float sq = v0.x*v0.x + v0.y*v0.y + v0.z*v0.z + v0.w*v0.w
             + v1.x*v1.x + v1.y*v1.y + v1.z*v1.z + v1.w*v1.w;
    #pragma unroll
    for (int off = 32; off; off >>= 1) {
        s  += __shfl_xor(s,  off);
        sq += __shfl_xor(sq, off);
    }
    const float mu  = s * (1.f / 512.f);
    const float var = sq * (1.f / 512.f) - mu * mu;
    const float inv = rsqrtf(var + EPS_);

    float4 w0 = *(const float4*)(ln_w + lane * 8);
    float4 w1 = *(const float4*)(ln_w + lane * 8 + 4);
    float4 b0 = *(const float4*)(ln_b + lane * 8);
    float4 b1 = *(const float4*)(ln_b + lane * 8 + 4);
    float4 o0, o1;
    o0.x = (v0.x - mu) * inv * w0.x + b0.x;
    o0.y = (v0.y - mu) * inv * w0.y + b0.y;
    o0.z = (v0.z - mu) * inv * w0.z + b0.z;
    o0.w = (v0.w - mu) * inv * w0.w + b0.w;
    o1.x = (v1.x - mu) * inv * w1.x + b1.x;
    o1.y = (v1.y - mu) * inv * w1.y + b1.y;
    o1.z = (v1.z - mu) * inv * w1.z + b1.z;
    o1.w = (v1.w - mu) * inv * w1.w + b1.w;
    *(float4*)(out + (size_t)row * 512 + lane * 8)     = o0;
    *(float4*)(out + (size_t)row * 512 + lane * 8 + 4) = o1;
}

// ---------------------------------------------------------------------------
extern "C" void kernel_launch(void* const* d_in, const int* in_sizes, int n_in,
                              void* d_out, int out_size, void* d_ws, size_t ws_size,
                              hipStream_t stream)
{
    const float* x   = (const float*)d_in[0];
    const float* Wq  = (const float*)d_in[1];
    const float* Wk  = (const float*)d_in[2];
    const float* Wv  = (const float*)d_in[3];
    const float* Wo  = (const float*)d_in[4];
    const float* bo  = (const float*)d_in[5];
    const float* Wg  = (const float*)d_in[6];
    const float* bg  = (const float*)d_in[7];
    const float* la  = (const float*)d_in[8];
    const float* lnw = (const float*)d_in[9];
    const float* lnb = (const float*)d_in[10];

    const size_t NQ = (size_t)B_ * S_ * D_;          // 2,097,152
    float* Graw = (float*)d_ws;                      // 131072 f32
    float* Ybuf = Graw + 131072;                     // 2,097,152 f32
    float* ROPE = Ybuf + NQ;                         // 65536 f32 (float2 x 32768)
    float* SRb  = ROPE + 65536;                      // 1024 f32
    short* xbf  = (short*)(SRb + 1024);              // 2,097,152
    short* Wcat = xbf + NQ;                          // 851,968
    short* Wobf = Wcat + (size_t)1664 * 512;         // 262,144
    short* Qbf  = Wobf + (size_t)512 * 512;          // 2,097,152
    short* Kbf  = Qbf + NQ;
    short* Vbf  = Kbf + NQ;
    short* Obf  = Vbf + NQ;
    short* Ubuf = Obf + NQ;                          // 512*2*4096 = 4,194,304

    // 0) dtype conversion / weight packing / rope table
    convert_inputs<<<1696, 256, 0, stream>>>(x, Wq, Wk, Wv, Wg, Wo, xbf, Wcat, Wobf,
                                             (float2*)ROPE);
    // 1) projections (MFMA, bf16 outputs)
    mfma_proj<<<416, 256, 0, stream>>>(xbf, Wcat, Qbf, Kbf, Vbf, Graw);
    // 2) per-chunk state deltas
    chunk_delta<<<512, 256, 0, stream>>>(Kbf, Vbf, Graw, bg, la,
                                         (const float2*)ROPE, Ubuf, SRb);
    // 3) state prefix scan (exclusive, bf16)
    state_prefix<<<512, 256, 0, stream>>>(Ubuf, SRb);
    // 4) full output (intra + inter fused)
    chunk_o<<<512, 256, 0, stream>>>(Qbf, Kbf, Vbf, Graw, bg, la,
                                     (const float2*)ROPE, Ubuf, Obf);
    // 5) output projection + residual (MFMA)
    mfma_out<<<128, 256, 0, stream>>>(Obf, Wobf, bo, x, Ybuf);
    // 6) layernorm
    ln_kernel<<<1024, 256, 0, stream>>>(Ybuf, lnw, lnb, (float*)d_out);
}

// Round 8
// 135.082 us; speedup vs baseline: 5.2928x; 1.2871x over previous
//
#include <hip/hip_runtime.h>
#include <hip/hip_bf16.h>
#include <math.h>

// Problem constants
#define B_  4
#define S_  1024
#define D_  512
#define H_  8
#define HD_ 64
#define EPS_ 1e-5f

typedef __attribute__((ext_vector_type(8))) short  bf16x8;
typedef __attribute__((ext_vector_type(4))) short  bf16x4;
typedef __attribute__((ext_vector_type(4))) float  f32x4;

#define MFMA16(a, b, c) __builtin_amdgcn_mfma_f32_16x16x32_bf16((a), (b), (c), 0, 0, 0)

// async global->LDS DMA, 16B per lane; LDS dest = wave-uniform base + lane*16
#define GLOAD16(gp, lp) __builtin_amdgcn_global_load_lds( \
    (const __attribute__((address_space(1))) unsigned int*)(gp), \
    (__attribute__((address_space(3))) unsigned int*)(lp), 16, 0, 0)

__device__ __forceinline__ float bf2f(short u) {
    union { unsigned int i; float f; } v;
    v.i = ((unsigned int)(unsigned short)u) << 16;
    return v.f;
}
__device__ __forceinline__ short f2bf(float f) {
    __hip_bfloat16 h = __float2bfloat16(f);
    return *reinterpret_cast<short*>(&h);
}

// ---------------------------------------------------------------------------
// Kernel 0: convert x -> bf16, pack [Wq;Wk;Wv;Wg] -> Wcat bf16 (1664x512,
// zero-padded), Wo -> bf16, build rope table {cos,sin}.
// ---------------------------------------------------------------------------
__global__ __launch_bounds__(256) void convert_inputs(
    const float* __restrict__ x,
    const float* __restrict__ Wq, const float* __restrict__ Wk,
    const float* __restrict__ Wv, const float* __restrict__ Wg,
    const float* __restrict__ Wo,
    short* __restrict__ xbf, short* __restrict__ Wcat, short* __restrict__ Wobf,
    float2* __restrict__ rope)
{
    const int id = blockIdx.x * 256 + threadIdx.x;   // 0..434175
    if (id < 262144) {                               // x: 2,097,152 elems
        const size_t e = (size_t)id * 8;
        float4 v0 = *(const float4*)(x + e);
        float4 v1 = *(const float4*)(x + e + 4);
        bf16x8 o = { f2bf(v0.x), f2bf(v0.y), f2bf(v0.z), f2bf(v0.w),
                     f2bf(v1.x), f2bf(v1.y), f2bf(v1.z), f2bf(v1.w) };
        *(bf16x8*)(xbf + e) = o;
    } else if (id < 368640) {                        // Wcat: 1664*512 elems
        const int i2 = id - 262144;
        const int row = i2 >> 6;
        const int c8 = (i2 & 63) * 8;
        const float* s = nullptr;
        if (row < 512)       s = Wq + (size_t)row * 512 + c8;
        else if (row < 1024) s = Wk + (size_t)(row - 512) * 512 + c8;
        else if (row < 1536) s = Wv + (size_t)(row - 1024) * 512 + c8;
        else if (row < 1568) s = Wg + (size_t)(row - 1536) * 512 + c8;
        bf16x8 o = (bf16x8)0;
        if (s) {
            float4 v0 = *(const float4*)(s);
            float4 v1 = *(const float4*)(s + 4);
            o = bf16x8{ f2bf(v0.x), f2bf(v0.y), f2bf(v0.z), f2bf(v0.w),
                        f2bf(v1.x), f2bf(v1.y), f2bf(v1.z), f2bf(v1.w) };
        }
        *(bf16x8*)(Wcat + (size_t)row * 512 + c8) = o;
    } else if (id < 401408) {                        // Wo: 262,144 elems
        const int i3 = id - 368640;
        const size_t e = (size_t)i3 * 8;
        float4 v0 = *(const float4*)(Wo + e);
        float4 v1 = *(const float4*)(Wo + e + 4);
        bf16x8 o = { f2bf(v0.x), f2bf(v0.y), f2bf(v0.z), f2bf(v0.w),
                     f2bf(v1.x), f2bf(v1.y), f2bf(v1.z), f2bf(v1.w) };
        *(bf16x8*)(Wobf + e) = o;
    } else {                                         // rope: 32768 entries
        const int i4 = id - 401408;
        const int s = i4 >> 5, i = i4 & 31;
        const float inv = exp2f(-(float)i * (13.287712379549449f / 32.0f));
        float sn, cs;
        sincosf((float)s * inv, &sn, &cs);
        rope[i4] = make_float2(cs, sn);
    }
}

// ---------------------------------------------------------------------------
// Kernel 1: MFMA projection GEMM via global_load_lds (m97 structure).
// Linear LDS [128][64] bf16, 2-barrier K-loop, XCD-affine swizzle.
// Epilogue: staged bf16 tile + fused RoPE for Q/K n-tiles, coalesced writes.
// ---------------------------------------------------------------------------
__global__ __launch_bounds__(256) void mfma_proj(
    const short* __restrict__ Abf, const short* __restrict__ Wcat,
    const float2* __restrict__ rope,
    short* __restrict__ Qbf, short* __restrict__ Kbf,
    short* __restrict__ Vbf, float* __restrict__ Graw)
{
    __shared__ __align__(16) short lds[17408];   // K-loop: 2x8192; epi: 128x136
    short* sA = lds;            // [128][64] linear
    short* sB = lds + 8192;

    const int p = blockIdx.x;              // 0..415
    const int xcd = p & 7, slot = p >> 3;  // 52 slots per XCD
    const int by = xcd + 8 * (slot / 13);
    const int bx = slot % 13;
    const int n0 = bx * 128, m0 = by * 128;

    const int tid = threadIdx.x;
    const int lane = tid & 63, wave = tid >> 6;
    const int lrow = lane & 15, lgrp = lane >> 4;
    const int wr = wave >> 1, wc = wave & 1;
    const int srl = lane >> 3;             // row within 8-row chunk
    const int scs = (lane & 7) * 8;        // col (shorts)

    f32x4 acc[4][4];
    #pragma unroll
    for (int i = 0; i < 4; ++i)
        #pragma unroll
        for (int j = 0; j < 4; ++j) acc[i][j] = (f32x4)0.f;

    for (int step = 0; step < 8; ++step) {
        const int kt = step * 64;
        #pragma unroll
        for (int i = 0; i < 4; ++i) {
            const int chunk = i * 4 + wave;           // 0..15
            const int r = chunk * 8 + srl;
            GLOAD16(Abf  + (size_t)(m0 + r) * 512 + kt + scs, sA + chunk * 512);
            GLOAD16(Wcat + (size_t)(n0 + r) * 512 + kt + scs, sB + chunk * 512);
        }
        __syncthreads();   // drains DMA (vmcnt 0) + LDS visible
        #pragma unroll
        for (int kk = 0; kk < 2; ++kk) {
            const int kb = kk * 32 + lgrp * 8;
            bf16x8 af[4], bfr[4];
            #pragma unroll
            for (int mi = 0; mi < 4; ++mi)
                af[mi] = *(const bf16x8*)&sA[(wr * 64 + mi * 16 + lrow) * 64 + kb];
            #pragma unroll
            for (int ni = 0; ni < 4; ++ni)
                bfr[ni] = *(const bf16x8*)&sB[(wc * 64 + ni * 16 + lrow) * 64 + kb];
            #pragma unroll
            for (int mi = 0; mi < 4; ++mi)
                #pragma unroll
                for (int ni = 0; ni < 4; ++ni)
                    acc[mi][ni] = MFMA16(af[mi], bfr[ni], acc[mi][ni]);
        }
        __syncthreads();   // reads done before next DMA overwrites
    }

    if (n0 < 1536) {
        // stage 128x128 bf16 tile (stride 136 -> 16B-aligned rows)
        short* stg = lds;
        #pragma unroll
        for (int mi = 0; mi < 4; ++mi)
            #pragma unroll
            for (int ni = 0; ni < 4; ++ni)
                #pragma unroll
                for (int j = 0; j < 4; ++j) {
                    const int rl = wr * 64 + mi * 16 + lgrp * 4 + j;
                    const int cl = wc * 64 + ni * 16 + lrow;
                    stg[rl * 136 + cl] = f2bf(acc[mi][ni][j]);
                }
        __syncthreads();
        short* dst; int dstoff; bool roped;
        if (n0 < 512)       { dst = Qbf; dstoff = n0;        roped = true;  }
        else if (n0 < 1024) { dst = Kbf; dstoff = n0 - 512;  roped = true;  }
        else                { dst = Vbf; dstoff = n0 - 1024; roped = false; }
        #pragma unroll
        for (int it = 0; it < 8; ++it) {
            const int c8 = tid + it * 256;         // 0..2047
            const int row = c8 >> 4, co = (c8 & 15) * 8;
            bf16x8 vv = *(const bf16x8*)&stg[row * 136 + co];
            if (roped) {
                const int s = (m0 + row) & (S_ - 1);
                const int ib = ((dstoff + co) & 63) >> 1;
                #pragma unroll
                for (int j = 0; j < 4; ++j) {
                    const float2 t = rope[s * 32 + ib + j];
                    const float xr = bf2f(vv[2 * j]), xi = bf2f(vv[2 * j + 1]);
                    vv[2 * j]     = f2bf(xr * t.x - xi * t.y);
                    vv[2 * j + 1] = f2bf(xr * t.y + xi * t.x);
                }
            }
            *(bf16x8*)(dst + (size_t)(m0 + row) * 512 + dstoff + co) = vv;
        }
    } else {
        // G tile: only cols 0..31 valid (fp32, tiny)
        #pragma unroll
        for (int mi = 0; mi < 4; ++mi)
            #pragma unroll
            for (int ni = 0; ni < 2; ++ni) {
                const int col = wc * 64 + ni * 16 + lrow;
                if (col < 32) {
                    #pragma unroll
                    for (int j = 0; j < 4; ++j) {
                        const int row = m0 + wr * 64 + mi * 16 + lgrp * 4 + j;
                        Graw[(size_t)row * 32 + col] = acc[mi][ni][j];
                    }
                }
            }
    }
}

// ---------------------------------------------------------------------------
// Kernel A: per-chunk state delta.  Grid 512 = (b,h,chunk).  K pre-roped.
// U_m = V^T @ Ksc_m  -> Ubuf (bf16, LDS-staged coalesced), R_m -> SRb.
// ---------------------------------------------------------------------------
__global__ __launch_bounds__(256) void chunk_delta(
    const short* __restrict__ Kbf, const short* __restrict__ Vbf,
    const float* __restrict__ Graw, const float* __restrict__ bg,
    const float* __restrict__ logit_alphas,
    short* __restrict__ Ubuf, float* __restrict__ SRb)
{
    __shared__ __align__(16) short sK [64 * 72];
    __shared__ __align__(16) short sVT[64 * 72];       // VT[e][tau]
    __shared__ __align__(16) short sKscT[2][64 * 72];  // KscT[m][d][tau]
    __shared__ float sScal[64][4];
    __shared__ float sKs[2][64];

    const int tid  = threadIdx.x;
    const int wave = tid >> 6, lane = tid & 63;
    const int lrow = lane & 15, lgrp = lane >> 4;
    const int c  = blockIdx.x & 15;
    const int bh = blockIdx.x >> 4;
    const int h = bh & 7, b = bh >> 3;
    const int row0 = wave * 16;
    const int s0 = c * 64;

    if (tid < 64) {
        const int bs = b * S_ + s0 + tid;
        const float4 gv = *(const float4*)(Graw + (size_t)bs * 32 + h * 4);
        const float g0 = gv.x + bg[h * 4 + 0];
        const float g1 = gv.y + bg[h * 4 + 1];
        const float g2 = gv.z + bg[h * 4 + 2];
        const float g3 = gv.w + bg[h * 4 + 3];
        const float gf  = 1.f / (1.f + expf(-g0));
        const float gu  = 1.f / (1.f + expf(-g1));
        const float wm0 = 1.f / (1.f + expf(-(g2 - g3)));
        const float a0 = 1.f / (1.f + expf(-logit_alphas[h * 2 + 0]));
        const float a1 = 1.f / (1.f + expf(-logit_alphas[h * 2 + 1]));
        sScal[tid][0] = a0 * gf; sScal[tid][1] = a1 * gf;
        sScal[tid][2] = wm0 * gu; sScal[tid][3] = (1.f - wm0) * gu;
    }

    // load K (pre-roped) + V (transposed)
    #pragma unroll
    for (int it = 0; it < 2; ++it) {
        const int i = tid + it * 256;             // 0..511
        const int r = i >> 3, c8 = (i & 7) * 8;
        const size_t g = ((size_t)(b * S_ + s0 + r)) * 512 + h * 64 + c8;
        bf16x8 k8 = *(const bf16x8*)(Kbf + g);
        bf16x8 v8 = *(const bf16x8*)(Vbf + g);
        *(bf16x8*)&sK[r * 72 + c8] = k8;
        #pragma unroll
        for (int j = 0; j < 8; ++j) sVT[(c8 + j) * 72 + r] = v8[j];
    }
    __syncthreads();

    if (wave < 2) {
        const int m = wave;
        float pre = log2f(sScal[lane][m]);
        #pragma unroll
        for (int off = 1; off < 64; off <<= 1) {
            const float u = __shfl_up(pre, off);
            if (lane >= off) pre += u;
        }
        const float lR = __shfl(pre, 63);
        sKs[m][lane] = sScal[lane][2 + m] * exp2f(lR - pre);
        if (lane == 63) SRb[blockIdx.x * 2 + m] = exp2f(lR);
    }
    __syncthreads();

    {   // scaled-K transpose
        const int task = tid >> 1, halfd = tid & 1;
        const int m = task >> 6, tau = task & 63;
        const float ksc = sKs[m][tau];
        #pragma unroll
        for (int dd = halfd * 32; dd < halfd * 32 + 32; dd += 8) {
            bf16x8 kr = *(const bf16x8*)&sK[tau * 72 + dd];
            #pragma unroll
            for (int j = 0; j < 8; ++j)
                sKscT[m][(dd + j) * 72 + tau] = f2bf(bf2f(kr[j]) * ksc);
        }
    }
    __syncthreads();

    #pragma unroll
    for (int m = 0; m < 2; ++m) {
        f32x4 accU[4];
        #pragma unroll
        for (int db = 0; db < 4; ++db) accU[db] = (f32x4)0.f;
        #pragma unroll
        for (int kk = 0; kk < 2; ++kk) {
            const int kb = kk * 32 + lgrp * 8;
            bf16x8 a = *(const bf16x8*)&sVT[(row0 + lrow) * 72 + kb];
            #pragma unroll
            for (int db = 0; db < 4; ++db) {
                bf16x8 bb = *(const bf16x8*)&sKscT[m][(db * 16 + lrow) * 72 + kb];
                accU[db] = MFMA16(a, bb, accU[db]);
            }
        }
        // stage U_m into sK (free after KscT build), then coalesced write
        __syncthreads();
        #pragma unroll
        for (int db = 0; db < 4; ++db)
            #pragma unroll
            for (int r = 0; r < 4; ++r) {
                const int e = row0 + lgrp * 4 + r;
                sK[e * 72 + db * 16 + lrow] = f2bf(accU[db][r]);
            }
        __syncthreads();
        short* ub = Ubuf + ((size_t)blockIdx.x * 2 + m) * 4096;
        #pragma unroll
        for (int it = 0; it < 2; ++it) {
            const int i = tid + it * 256;           // 0..511
            const int e = i >> 3, seg = (i & 7) * 8;
            *(bf16x8*)(ub + e * 64 + seg) = *(const bf16x8*)&sK[e * 72 + seg];
        }
    }
}

// ---------------------------------------------------------------------------
// Kernel B: state prefix scan (bf16 in/out, fp32 running sum in registers).
// ---------------------------------------------------------------------------
__global__ __launch_bounds__(256) void state_prefix(
    short* __restrict__ Ubuf, const float* __restrict__ SRb)
{
    const int idx = blockIdx.x * 256 + threadIdx.x;  // 0..131071
    const int ed2 = idx & 2047;
    const int m   = (idx >> 11) & 1;
    const int bh  = idx >> 12;
    float s0 = 0.f, s1 = 0.f;
    #pragma unroll
    for (int c = 0; c < 16; ++c) {
        const int bhc = bh * 16 + c;
        short* p = Ubuf + ((size_t)bhc * 2 + m) * 4096 + ed2 * 2;
        const float R = SRb[bhc * 2 + m];
        const short2 u = *(const short2*)p;
        const float u0 = bf2f(u.x), u1 = bf2f(u.y);
        *(short2*)p = make_short2(f2bf(s0), f2bf(s1));
        s0 = R * s0 + u0;
        s1 = R * s1 + u1;
    }
}

// ---------------------------------------------------------------------------
// Kernel C: full output.  O = P@V (intra) + (qs.Q) @ [S0;S1] (inter) -> Obf.
// Q/K pre-roped; output staged in LDS for coalesced bf16x8 writes.
// ---------------------------------------------------------------------------
__global__ __launch_bounds__(256) void chunk_o(
    const short* __restrict__ Qbf, const short* __restrict__ Kbf,
    const short* __restrict__ Vbf, const float* __restrict__ Graw,
    const float* __restrict__ bg, const float* __restrict__ logit_alphas,
    const short* __restrict__ Ubuf, short* __restrict__ Obf)
{
    __shared__ __align__(16) short sQ [64 * 72];
    __shared__ __align__(16) short sK [64 * 72];
    __shared__ __align__(16) short sVT[64 * 72];
    __shared__ __align__(16) short sP [64 * 72];
    __shared__ __align__(16) short sST[2][64 * 72];   // prefix state [m][e][d]
    __shared__ float sScal[64][6];
    __shared__ float sLc[2][64];
    __shared__ float sQs[2][64];

    const int tid  = threadIdx.x;
    const int wave = tid >> 6, lane = tid & 63;
    const int lrow = lane & 15, lgrp = lane >> 4;
    const int c  = blockIdx.x & 15;
    const int bh = blockIdx.x >> 4;
    const int h = bh & 7, b = bh >> 3;
    const int row0 = wave * 16;
    const int s0 = c * 64;

    if (tid < 64) {
        const int bs = b * S_ + s0 + tid;
        const float4 gv = *(const float4*)(Graw + (size_t)bs * 32 + h * 4);
        const float g0 = gv.x + bg[h * 4 + 0];
        const float g1 = gv.y + bg[h * 4 + 1];
        const float g2 = gv.z + bg[h * 4 + 2];
        const float g3 = gv.w + bg[h * 4 + 3];
        const float gf  = 1.f / (1.f + expf(-g0));
        const float gu  = 1.f / (1.f + expf(-g1));
        const float wm0 = 1.f / (1.f + expf(-(g2 - g3)));
        const float a0 = 1.f / (1.f + expf(-logit_alphas[h * 2 + 0]));
        const float a1 = 1.f / (1.f + expf(-logit_alphas[h * 2 + 1]));
        sScal[tid][0] = a0 * gf; sScal[tid][1] = a1 * gf;
        sScal[tid][2] = wm0 * gu; sScal[tid][3] = (1.f - wm0) * gu;
        sScal[tid][4] = wm0; sScal[tid][5] = 1.f - wm0;
    }

    // load Q,K (pre-roped) + V (transposed)
    #pragma unroll
    for (int it = 0; it < 2; ++it) {
        const int i = tid + it * 256;
        const int r = i >> 3, c8 = (i & 7) * 8;
        const size_t g = ((size_t)(b * S_ + s0 + r)) * 512 + h * 64 + c8;
        *(bf16x8*)&sQ[r * 72 + c8] = *(const bf16x8*)(Qbf + g);
        *(bf16x8*)&sK[r * 72 + c8] = *(const bf16x8*)(Kbf + g);
        bf16x8 v8 = *(const bf16x8*)(Vbf + g);
        #pragma unroll
        for (int j = 0; j < 8; ++j) sVT[(c8 + j) * 72 + r] = v8[j];
    }
    // load exclusive-prefix state (bf16, row-major [e][d])
    #pragma unroll
    for (int it = 0; it < 4; ++it) {
        const int c8 = tid + it * 256;            // 0..1023
        const int m = c8 >> 9, rem = c8 & 511;
        const int e = rem >> 3, d8 = (rem & 7) * 8;
        *(bf16x8*)&sST[m][e * 72 + d8] =
            *(const bf16x8*)(Ubuf + ((size_t)blockIdx.x * 2 + m) * 4096 + e * 64 + d8);
    }
    __syncthreads();

    if (wave < 2) {
        const int m = wave;
        float pre = log2f(sScal[lane][m]);
        #pragma unroll
        for (int off = 1; off < 64; off <<= 1) {
            const float u = __shfl_up(pre, off);
            if (lane >= off) pre += u;
        }
        sLc[m][lane] = pre;
        sQs[m][lane] = sScal[lane][4 + m] * exp2f(pre);
    }
    __syncthreads();

    // QK^T
    f32x4 accS[4], accO[4];
    #pragma unroll
    for (int cb = 0; cb < 4; ++cb) { accS[cb] = (f32x4)0.f; accO[cb] = (f32x4)0.f; }
    #pragma unroll
    for (int kk = 0; kk < 2; ++kk) {
        const int kb = kk * 32 + lgrp * 8;
        bf16x8 a = *(const bf16x8*)&sQ[(row0 + lrow) * 72 + kb];
        #pragma unroll
        for (int cb = 0; cb < 4; ++cb) {
            bf16x8 bb = *(const bf16x8*)&sK[(cb * 16 + lrow) * 72 + kb];
            accS[cb] = MFMA16(a, bb, accS[cb]);
        }
    }

    // O_inter = (qs-scaled Q) @ [S0;S1]
    #pragma unroll
    for (int kk = 0; kk < 4; ++kk) {
        const int k0 = kk * 32 + lgrp * 8;
        const int m = k0 >> 6, d0 = k0 & 63;
        const float qs = sQs[m][row0 + lrow];
        bf16x8 qr = *(const bf16x8*)&sQ[(row0 + lrow) * 72 + d0];
        bf16x8 a;
        #pragma unroll
        for (int j = 0; j < 8; ++j) a[j] = f2bf(bf2f(qr[j]) * qs);
        #pragma unroll
        for (int cb = 0; cb < 4; ++cb) {
            bf16x8 bb = *(const bf16x8*)&sST[m][(cb * 16 + lrow) * 72 + d0];
            accO[cb] = MFMA16(a, bb, accO[cb]);
        }
    }

    // P build (log-space decay ratios, causal mask, gates)
    #pragma unroll
    for (int r = 0; r < 4; ++r) {
        const int t = row0 + lgrp * 4 + r;
        const float wm0 = sScal[t][4], wm1 = sScal[t][5];
        const float lc0t = sLc[0][t],  lc1t = sLc[1][t];
        #pragma unroll
        for (int cb = 0; cb < 4; ++cb) {
            const int tau = cb * 16 + lrow;
            float p = 0.f;
            if (tau <= t) {
                const float c0 = wm0 * sScal[tau][2] * exp2f(lc0t - sLc[0][tau]);
                const float c1 = wm1 * sScal[tau][3] * exp2f(lc1t - sLc[1][tau]);
                p = accS[cb][r] * (c0 + c1);
            }
            sP[t * 72 + tau] = f2bf(p);
        }
    }

    // O_intra = P @ V (wave-local sP rows)
    #pragma unroll
    for (int kk = 0; kk < 2; ++kk) {
        const int kb = kk * 32 + lgrp * 8;
        bf16x8 a = *(const bf16x8*)&sP[(row0 + lrow) * 72 + kb];
        #pragma unroll
        for (int cb = 0; cb < 4; ++cb) {
            bf16x8 bb = *(const bf16x8*)&sVT[(cb * 16 + lrow) * 72 + kb];
            accO[cb] = MFMA16(a, bb, accO[cb]);
        }
    }

    // stage O (wave-local rows of sP) then coalesced bf16x8 writes
    #pragma unroll
    for (int cb = 0; cb < 4; ++cb)
        #pragma unroll
        for (int r = 0; r < 4; ++r) {
            const int t = row0 + lgrp * 4 + r;
            sP[t * 72 + cb * 16 + lrow] = f2bf(accO[cb][r]);
        }
    __syncthreads();
    #pragma unroll
    for (int it = 0; it < 2; ++it) {
        const int i = tid + it * 256;               // 0..511
        const int t = i >> 3, seg = (i & 7) * 8;
        *(bf16x8*)(Obf + ((size_t)(b * S_ + s0 + t)) * 512 + h * 64 + seg) =
            *(const bf16x8*)&sP[t * 72 + seg];
    }
}

// ---------------------------------------------------------------------------
// Kernel 4: MFMA output GEMM via global_load_lds:  Ybf = Obf@Wo^T + bo + x
// (bf16 output, staged coalesced writes).
// ---------------------------------------------------------------------------
__global__ __launch_bounds__(256) void mfma_out(
    const short* __restrict__ Abf, const short* __restrict__ Wobf,
    const float* __restrict__ bo, const float* __restrict__ xres,
    short* __restrict__ Ybf)
{
    __shared__ __align__(16) short lds[17408];
    short* sA = lds;
    short* sB = lds + 8192;

    const int p = blockIdx.x;              // 0..127
    const int xcd = p & 7, slot = p >> 3;  // 16 slots = 4 m-panels x 4
    const int by = xcd + 8 * (slot >> 2);
    const int bx = slot & 3;
    const int n0 = bx * 128, m0 = by * 128;

    const int tid = threadIdx.x;
    const int lane = tid & 63, wave = tid >> 6;
    const int lrow = lane & 15, lgrp = lane >> 4;
    const int wr = wave >> 1, wc = wave & 1;
    const int srl = lane >> 3;
    const int scs = (lane & 7) * 8;

    f32x4 acc[4][4];
    #pragma unroll
    for (int i = 0; i < 4; ++i)
        #pragma unroll
        for (int j = 0; j < 4; ++j) acc[i][j] = (f32x4)0.f;

    for (int step = 0; step < 8; ++step) {
        const int kt = step * 64;
        #pragma unroll
        for (int i = 0; i < 4; ++i) {
            const int chunk = i * 4 + wave;
            const int r = chunk * 8 + srl;
            GLOAD16(Abf  + (size_t)(m0 + r) * 512 + kt + scs, sA + chunk * 512);
            GLOAD16(Wobf + (size_t)(n0 + r) * 512 + kt + scs, sB + chunk * 512);
        }
        __syncthreads();
        #pragma unroll
        for (int kk = 0; kk < 2; ++kk) {
            const int kb = kk * 32 + lgrp * 8;
            bf16x8 af[4], bfr[4];
            #pragma unroll
            for (int mi = 0; mi < 4; ++mi)
                af[mi] = *(const bf16x8*)&sA[(wr * 64 + mi * 16 + lrow) * 64 + kb];
            #pragma unroll
            for (int ni = 0; ni < 4; ++ni)
                bfr[ni] = *(const bf16x8*)&sB[(wc * 64 + ni * 16 + lrow) * 64 + kb];
            #pragma unroll
            for (int mi = 0; mi < 4; ++mi)
                #pragma unroll
                for (int ni = 0; ni < 4; ++ni)
                    acc[mi][ni] = MFMA16(af[mi], bfr[ni], acc[mi][ni]);
        }
        __syncthreads();
    }

    // stage bf16 tile, then coalesced: y = acc + bo + x  (fp32 math)
    short* stg = lds;
    #pragma unroll
    for (int mi = 0; mi < 4; ++mi)
        #pragma unroll
        for (int ni = 0; ni < 4; ++ni)
            #pragma unroll
            for (int j = 0; j < 4; ++j) {
                const int rl = wr * 64 + mi * 16 + lgrp * 4 + j;
                const int cl = wc * 64 + ni * 16 + lrow;
                stg[rl * 136 + cl] = f2bf(acc[mi][ni][j]);
            }
    __syncthreads();
    #pragma unroll
    for (int it = 0; it < 8; ++it) {
        const int c8 = tid + it * 256;
        const int row = c8 >> 4, co = (c8 & 15) * 8;
        const size_t gbase = (size_t)(m0 + row) * 512 + n0 + co;
        bf16x8 a = *(const bf16x8*)&stg[row * 136 + co];
        float4 x0 = *(const float4*)(xres + gbase);
        float4 x1 = *(const float4*)(xres + gbase + 4);
        float4 b0 = *(const float4*)(bo + n0 + co);
        float4 b1 = *(const float4*)(bo + n0 + co + 4);
        bf16x8 y;
        y[0] = f2bf(bf2f(a[0]) + b0.x + x0.x);
        y[1] = f2bf(bf2f(a[1]) + b0.y + x0.y);
        y[2] = f2bf(bf2f(a[2]) + b0.z + x0.z);
        y[3] = f2bf(bf2f(a[3]) + b0.w + x0.w);
        y[4] = f2bf(bf2f(a[4]) + b1.x + x1.x);
        y[5] = f2bf(bf2f(a[5]) + b1.y + x1.y);
        y[6] = f2bf(bf2f(a[6]) + b1.z + x1.z);
        y[7] = f2bf(bf2f(a[7]) + b1.w + x1.w);
        *(bf16x8*)(Ybf + gbase) = y;
    }
}

// ---------------------------------------------------------------------------
// Kernel 5: LayerNorm over D=512 (bf16 input, fp32 output).
// ---------------------------------------------------------------------------
__global__ __launch_bounds__(256) void ln_kernel(
    const short* __restrict__ Ybf, const float* __restrict__ ln_w,
    const float* __restrict__ ln_b, float* __restrict__ out)
{
    const int wave = threadIdx.x >> 6;
    const int lane = threadIdx.x & 63;
    const int row = blockIdx.x * 4 + wave;   // 0..4095

    bf16x8 v8 = *(const bf16x8*)(Ybf + (size_t)row * 512 + lane * 8);
    float v[8];
    #pragma unroll
    for (int j = 0; j < 8; ++j) v[j] = bf2f(v8[j]);

    float s = 0.f, sq = 0.f;
    #pragma unroll
    for (int j = 0; j < 8; ++j) { s += v[j]; sq += v[j] * v[j]; }
    #pragma unroll
    for (int off = 32; off; off >>= 1) {
        s  += __shfl_xor(s,  off);
        sq += __shfl_xor(sq, off);
    }
    const float mu  = s * (1.f / 512.f);
    const float var = sq * (1.f / 512.f) - mu * mu;
    const float inv = rsqrtf(var + EPS_);

    float4 w0 = *(const float4*)(ln_w + lane * 8);
    float4 w1 = *(const float4*)(ln_w + lane * 8 + 4);
    float4 b0 = *(const float4*)(ln_b + lane * 8);
    float4 b1 = *(const float4*)(ln_b + lane * 8 + 4);
    float4 o0, o1;
    o0.x = (v[0] - mu) * inv * w0.x + b0.x;
    o0.y = (v[1] - mu) * inv * w0.y + b0.y;
    o0.z = (v[2] - mu) * inv * w0.z + b0.z;
    o0.w = (v[3] - mu) * inv * w0.w + b0.w;
    o1.x = (v[4] - mu) * inv * w1.x + b1.x;
    o1.y = (v[5] - mu) * inv * w1.y + b1.y;
    o1.z = (v[6] - mu) * inv * w1.z + b1.z;
    o1.w = (v[7] - mu) * inv * w1.w + b1.w;
    *(float4*)(out + (size_t)row * 512 + lane * 8)     = o0;
    *(float4*)(out + (size_t)row * 512 + lane * 8 + 4) = o1;
}

// ---------------------------------------------------------------------------
extern "C" void kernel_launch(void* const* d_in, const int* in_sizes, int n_in,
                              void* d_out, int out_size, void* d_ws, size_t ws_size,
                              hipStream_t stream)
{
    const float* x   = (const float*)d_in[0];
    const float* Wq  = (const float*)d_in[1];
    const float* Wk  = (const float*)d_in[2];
    const float* Wv  = (const float*)d_in[3];
    const float* Wo  = (const float*)d_in[4];
    const float* bo  = (const float*)d_in[5];
    const float* Wg  = (const float*)d_in[6];
    const float* bg  = (const float*)d_in[7];
    const float* la  = (const float*)d_in[8];
    const float* lnw = (const float*)d_in[9];
    const float* lnb = (const float*)d_in[10];

    const size_t NQ = (size_t)B_ * S_ * D_;          // 2,097,152
    float* Graw = (float*)d_ws;                      // 131072 f32
    float* ROPE = Graw + 131072;                     // 65536 f32 (float2 x 32768)
    float* SRb  = ROPE + 65536;                      // 1024 f32
    short* xbf  = (short*)(SRb + 1024);              // 2,097,152
    short* Wcat = xbf + NQ;                          // 851,968
    short* Wobf = Wcat + (size_t)1664 * 512;         // 262,144
    short* Qbf  = Wobf + (size_t)512 * 512;          // 2,097,152
    short* Kbf  = Qbf + NQ;
    short* Vbf  = Kbf + NQ;
    short* Obf  = Vbf + NQ;
    short* Ybf  = Obf + NQ;                          // 2,097,152 (bf16 Y)
    short* Ubuf = Ybf + NQ;                          // 512*2*4096 = 4,194,304

    // 0) dtype conversion / weight packing / rope table
    convert_inputs<<<1696, 256, 0, stream>>>(x, Wq, Wk, Wv, Wg, Wo, xbf, Wcat, Wobf,
                                             (float2*)ROPE);
    // 1) projections (MFMA, global_load_lds, RoPE fused into epilogue)
    mfma_proj<<<416, 256, 0, stream>>>(xbf, Wcat, (const float2*)ROPE,
                                       Qbf, Kbf, Vbf, Graw);
    // 2) per-chunk state deltas
    chunk_delta<<<512, 256, 0, stream>>>(Kbf, Vbf, Graw, bg, la, Ubuf, SRb);
    // 3) state prefix scan (exclusive, bf16)
    state_prefix<<<512, 256, 0, stream>>>(Ubuf, SRb);
    // 4) full output (intra + inter fused)
    chunk_o<<<512, 256, 0, stream>>>(Qbf, Kbf, Vbf, Graw, bg, la, Ubuf, Obf);
    // 5) output projection + residual (MFMA, bf16 Y)
    mfma_out<<<128, 256, 0, stream>>>(Obf, Wobf, bo, x, Ybf);
    // 6) layernorm
    ln_kernel<<<1024, 256, 0, stream>>>(Ybf, lnw, lnb, (float*)d_out);
}

// Round 9
// 131.105 us; speedup vs baseline: 5.4534x; 1.0303x over previous
//
#include <hip/hip_runtime.h>
#include <hip/hip_bf16.h>
#include <math.h>

// Problem constants
#define B_  4
#define S_  1024
#define D_  512
#define H_  8
#define HD_ 64
#define EPS_ 1e-5f

typedef __attribute__((ext_vector_type(8))) short  bf16x8;
typedef __attribute__((ext_vector_type(4))) short  bf16x4;
typedef __attribute__((ext_vector_type(4))) float  f32x4;

#define MFMA16(a, b, c) __builtin_amdgcn_mfma_f32_16x16x32_bf16((a), (b), (c), 0, 0, 0)

// async global->LDS DMA, 16B per lane; LDS dest = wave-uniform base + lane*16
#define GLOAD16(gp, lp) __builtin_amdgcn_global_load_lds( \
    (const __attribute__((address_space(1))) unsigned int*)(gp), \
    (__attribute__((address_space(3))) unsigned int*)(lp), 16, 0, 0)

__device__ __forceinline__ float bf2f(short u) {
    union { unsigned int i; float f; } v;
    v.i = ((unsigned int)(unsigned short)u) << 16;
    return v.f;
}
__device__ __forceinline__ short f2bf(float f) {
    __hip_bfloat16 h = __float2bfloat16(f);
    return *reinterpret_cast<short*>(&h);
}

// ---------------------------------------------------------------------------
// Kernel 0: convert x -> bf16, pack [Wq;Wk;Wv;Wg] -> Wcat bf16 (1664x512,
// zero-padded), Wo -> bf16, build rope table {cos,sin}.
// ---------------------------------------------------------------------------
__global__ __launch_bounds__(256) void convert_inputs(
    const float* __restrict__ x,
    const float* __restrict__ Wq, const float* __restrict__ Wk,
    const float* __restrict__ Wv, const float* __restrict__ Wg,
    const float* __restrict__ Wo,
    short* __restrict__ xbf, short* __restrict__ Wcat, short* __restrict__ Wobf,
    float2* __restrict__ rope)
{
    const int id = blockIdx.x * 256 + threadIdx.x;   // 0..434175
    if (id < 262144) {                               // x: 2,097,152 elems
        const size_t e = (size_t)id * 8;
        float4 v0 = *(const float4*)(x + e);
        float4 v1 = *(const float4*)(x + e + 4);
        bf16x8 o = { f2bf(v0.x), f2bf(v0.y), f2bf(v0.z), f2bf(v0.w),
                     f2bf(v1.x), f2bf(v1.y), f2bf(v1.z), f2bf(v1.w) };
        *(bf16x8*)(xbf + e) = o;
    } else if (id < 368640) {                        // Wcat: 1664*512 elems
        const int i2 = id - 262144;
        const int row = i2 >> 6;
        const int c8 = (i2 & 63) * 8;
        const float* s = nullptr;
        if (row < 512)       s = Wq + (size_t)row * 512 + c8;
        else if (row < 1024) s = Wk + (size_t)(row - 512) * 512 + c8;
        else if (row < 1536) s = Wv + (size_t)(row - 1024) * 512 + c8;
        else if (row < 1568) s = Wg + (size_t)(row - 1536) * 512 + c8;
        bf16x8 o = (bf16x8)0;
        if (s) {
            float4 v0 = *(const float4*)(s);
            float4 v1 = *(const float4*)(s + 4);
            o = bf16x8{ f2bf(v0.x), f2bf(v0.y), f2bf(v0.z), f2bf(v0.w),
                        f2bf(v1.x), f2bf(v1.y), f2bf(v1.z), f2bf(v1.w) };
        }
        *(bf16x8*)(Wcat + (size_t)row * 512 + c8) = o;
    } else if (id < 401408) {                        // Wo: 262,144 elems
        const int i3 = id - 368640;
        const size_t e = (size_t)i3 * 8;
        float4 v0 = *(const float4*)(Wo + e);
        float4 v1 = *(const float4*)(Wo + e + 4);
        bf16x8 o = { f2bf(v0.x), f2bf(v0.y), f2bf(v0.z), f2bf(v0.w),
                     f2bf(v1.x), f2bf(v1.y), f2bf(v1.z), f2bf(v1.w) };
        *(bf16x8*)(Wobf + e) = o;
    } else {                                         // rope: 32768 entries
        const int i4 = id - 401408;
        const int s = i4 >> 5, i = i4 & 31;
        const float inv = exp2f(-(float)i * (13.287712379549449f / 32.0f));
        float sn, cs;
        sincosf((float)s * inv, &sn, &cs);
        rope[i4] = make_float2(cs, sn);
    }
}

// ---------------------------------------------------------------------------
// Kernel 1: MFMA projection GEMM, double-buffered global_load_lds.
// One barrier per K-step: STAGE(next) issued BEFORE MFMA(cur); the end-of-step
// barrier (vmcnt0) lands after MFMA has covered the DMA latency.
// Epilogue: staged bf16 tile + fused RoPE for Q/K, coalesced writes.
// ---------------------------------------------------------------------------
__global__ __launch_bounds__(256) void mfma_proj(
    const short* __restrict__ Abf, const short* __restrict__ Wcat,
    const float2* __restrict__ rope,
    short* __restrict__ Qbf, short* __restrict__ Kbf,
    short* __restrict__ Vbf, float* __restrict__ Graw)
{
    __shared__ __align__(16) short lds[32768];   // 2 bufs x (A 8192 + B 8192)

    const int p = blockIdx.x;              // 0..415
    const int xcd = p & 7, slot = p >> 3;  // 52 slots per XCD
    const int by = xcd + 8 * (slot / 13);
    const int bx = slot % 13;
    const int n0 = bx * 128, m0 = by * 128;

    const int tid = threadIdx.x;
    const int lane = tid & 63, wave = tid >> 6;
    const int lrow = lane & 15, lgrp = lane >> 4;
    const int wr = wave >> 1, wc = wave & 1;
    const int srl = lane >> 3;             // row within 8-row chunk
    const int scs = (lane & 7) * 8;        // col (shorts)

    f32x4 acc[4][4];
    #pragma unroll
    for (int i = 0; i < 4; ++i)
        #pragma unroll
        for (int j = 0; j < 4; ++j) acc[i][j] = (f32x4)0.f;

    // STAGE: issue 8 DMA per wave into buffer `buf` for K-offset kt
    #define PROJ_STAGE(buf, kt)  {                                            \
        short* dA = lds + (buf) * 16384;                                      \
        short* dB = dA + 8192;                                                \
        _Pragma("unroll")                                                     \
        for (int i = 0; i < 4; ++i) {                                         \
            const int chunk = i * 4 + wave;                                   \
            const int r = chunk * 8 + srl;                                    \
            GLOAD16(Abf  + (size_t)(m0 + r) * 512 + (kt) + scs, dA + chunk * 512); \
            GLOAD16(Wcat + (size_t)(n0 + r) * 512 + (kt) + scs, dB + chunk * 512); \
        } }

    PROJ_STAGE(0, 0);
    __syncthreads();
    int cur = 0;
    for (int step = 0; step < 8; ++step) {
        if (step < 7) PROJ_STAGE(cur ^ 1, (step + 1) * 64);
        const short* sA = lds + cur * 16384;
        const short* sB = sA + 8192;
        #pragma unroll
        for (int kk = 0; kk < 2; ++kk) {
            const int kb = kk * 32 + lgrp * 8;
            bf16x8 af[4], bfr[4];
            #pragma unroll
            for (int mi = 0; mi < 4; ++mi)
                af[mi] = *(const bf16x8*)&sA[(wr * 64 + mi * 16 + lrow) * 64 + kb];
            #pragma unroll
            for (int ni = 0; ni < 4; ++ni)
                bfr[ni] = *(const bf16x8*)&sB[(wc * 64 + ni * 16 + lrow) * 64 + kb];
            #pragma unroll
            for (int mi = 0; mi < 4; ++mi)
                #pragma unroll
                for (int ni = 0; ni < 4; ++ni)
                    acc[mi][ni] = MFMA16(af[mi], bfr[ni], acc[mi][ni]);
        }
        __syncthreads();   // drains this step's reads + next step's DMA
        cur ^= 1;
    }
    #undef PROJ_STAGE

    if (n0 < 1536) {
        // stage 128x128 bf16 tile (stride 136 -> 16B-aligned rows)
        short* stg = lds;
        #pragma unroll
        for (int mi = 0; mi < 4; ++mi)
            #pragma unroll
            for (int ni = 0; ni < 4; ++ni)
                #pragma unroll
                for (int j = 0; j < 4; ++j) {
                    const int rl = wr * 64 + mi * 16 + lgrp * 4 + j;
                    const int cl = wc * 64 + ni * 16 + lrow;
                    stg[rl * 136 + cl] = f2bf(acc[mi][ni][j]);
                }
        __syncthreads();
        short* dst; int dstoff; bool roped;
        if (n0 < 512)       { dst = Qbf; dstoff = n0;        roped = true;  }
        else if (n0 < 1024) { dst = Kbf; dstoff = n0 - 512;  roped = true;  }
        else                { dst = Vbf; dstoff = n0 - 1024; roped = false; }
        #pragma unroll
        for (int it = 0; it < 8; ++it) {
            const int c8 = tid + it * 256;         // 0..2047
            const int row = c8 >> 4, co = (c8 & 15) * 8;
            bf16x8 vv = *(const bf16x8*)&stg[row * 136 + co];
            if (roped) {
                const int s = (m0 + row) & (S_ - 1);
                const int ib = ((dstoff + co) & 63) >> 1;
                #pragma unroll
                for (int j = 0; j < 4; ++j) {
                    const float2 t = rope[s * 32 + ib + j];
                    const float xr = bf2f(vv[2 * j]), xi = bf2f(vv[2 * j + 1]);
                    vv[2 * j]     = f2bf(xr * t.x - xi * t.y);
                    vv[2 * j + 1] = f2bf(xr * t.y + xi * t.x);
                }
            }
            *(bf16x8*)(dst + (size_t)(m0 + row) * 512 + dstoff + co) = vv;
        }
    } else {
        // G tile: only cols 0..31 valid (fp32, tiny)
        #pragma unroll
        for (int mi = 0; mi < 4; ++mi)
            #pragma unroll
            for (int ni = 0; ni < 2; ++ni) {
                const int col = wc * 64 + ni * 16 + lrow;
                if (col < 32) {
                    #pragma unroll
                    for (int j = 0; j < 4; ++j) {
                        const int row = m0 + wr * 64 + mi * 16 + lgrp * 4 + j;
                        Graw[(size_t)row * 32 + col] = acc[mi][ni][j];
                    }
                }
            }
    }
}

// ---------------------------------------------------------------------------
// Kernel A: per-chunk state delta.  Grid 512 = (b,h,chunk).  K pre-roped.
// U_m = V^T @ Ksc_m  -> Ubuf (bf16, LDS-staged coalesced), R_m -> SRb.
// ---------------------------------------------------------------------------
__global__ __launch_bounds__(256) void chunk_delta(
    const short* __restrict__ Kbf, const short* __restrict__ Vbf,
    const float* __restrict__ Graw, const float* __restrict__ bg,
    const float* __restrict__ logit_alphas,
    short* __restrict__ Ubuf, float* __restrict__ SRb)
{
    __shared__ __align__(16) short sK [64 * 72];
    __shared__ __align__(16) short sVT[64 * 72];       // VT[e][tau]
    __shared__ __align__(16) short sKscT[2][64 * 72];  // KscT[m][d][tau]
    __shared__ float sScal[64][4];
    __shared__ float sKs[2][64];

    const int tid  = threadIdx.x;
    const int wave = tid >> 6, lane = tid & 63;
    const int lrow = lane & 15, lgrp = lane >> 4;
    const int c  = blockIdx.x & 15;
    const int bh = blockIdx.x >> 4;
    const int h = bh & 7, b = bh >> 3;
    const int row0 = wave * 16;
    const int s0 = c * 64;

    if (tid < 64) {
        const int bs = b * S_ + s0 + tid;
        const float4 gv = *(const float4*)(Graw + (size_t)bs * 32 + h * 4);
        const float g0 = gv.x + bg[h * 4 + 0];
        const float g1 = gv.y + bg[h * 4 + 1];
        const float g2 = gv.z + bg[h * 4 + 2];
        const float g3 = gv.w + bg[h * 4 + 3];
        const float gf  = 1.f / (1.f + expf(-g0));
        const float gu  = 1.f / (1.f + expf(-g1));
        const float wm0 = 1.f / (1.f + expf(-(g2 - g3)));
        const float a0 = 1.f / (1.f + expf(-logit_alphas[h * 2 + 0]));
        const float a1 = 1.f / (1.f + expf(-logit_alphas[h * 2 + 1]));
        sScal[tid][0] = a0 * gf; sScal[tid][1] = a1 * gf;
        sScal[tid][2] = wm0 * gu; sScal[tid][3] = (1.f - wm0) * gu;
    }

    // load K (pre-roped) + V (transposed)
    #pragma unroll
    for (int it = 0; it < 2; ++it) {
        const int i = tid + it * 256;             // 0..511
        const int r = i >> 3, c8 = (i & 7) * 8;
        const size_t g = ((size_t)(b * S_ + s0 + r)) * 512 + h * 64 + c8;
        bf16x8 k8 = *(const bf16x8*)(Kbf + g);
        bf16x8 v8 = *(const bf16x8*)(Vbf + g);
        *(bf16x8*)&sK[r * 72 + c8] = k8;
        #pragma unroll
        for (int j = 0; j < 8; ++j) sVT[(c8 + j) * 72 + r] = v8[j];
    }
    __syncthreads();

    if (wave < 2) {
        const int m = wave;
        float pre = log2f(sScal[lane][m]);
        #pragma unroll
        for (int off = 1; off < 64; off <<= 1) {
            const float u = __shfl_up(pre, off);
            if (lane >= off) pre += u;
        }
        const float lR = __shfl(pre, 63);
        sKs[m][lane] = sScal[lane][2 + m] * exp2f(lR - pre);
        if (lane == 63) SRb[blockIdx.x * 2 + m] = exp2f(lR);
    }
    __syncthreads();

    {   // scaled-K transpose
        const int task = tid >> 1, halfd = tid & 1;
        const int m = task >> 6, tau = task & 63;
        const float ksc = sKs[m][tau];
        #pragma unroll
        for (int dd = halfd * 32; dd < halfd * 32 + 32; dd += 8) {
            bf16x8 kr = *(const bf16x8*)&sK[tau * 72 + dd];
            #pragma unroll
            for (int j = 0; j < 8; ++j)
                sKscT[m][(dd + j) * 72 + tau] = f2bf(bf2f(kr[j]) * ksc);
        }
    }
    __syncthreads();

    #pragma unroll
    for (int m = 0; m < 2; ++m) {
        f32x4 accU[4];
        #pragma unroll
        for (int db = 0; db < 4; ++db) accU[db] = (f32x4)0.f;
        #pragma unroll
        for (int kk = 0; kk < 2; ++kk) {
            const int kb = kk * 32 + lgrp * 8;
            bf16x8 a = *(const bf16x8*)&sVT[(row0 + lrow) * 72 + kb];
            #pragma unroll
            for (int db = 0; db < 4; ++db) {
                bf16x8 bb = *(const bf16x8*)&sKscT[m][(db * 16 + lrow) * 72 + kb];
                accU[db] = MFMA16(a, bb, accU[db]);
            }
        }
        // stage U_m into sK (free after KscT build), then coalesced write
        __syncthreads();
        #pragma unroll
        for (int db = 0; db < 4; ++db)
            #pragma unroll
            for (int r = 0; r < 4; ++r) {
                const int e = row0 + lgrp * 4 + r;
                sK[e * 72 + db * 16 + lrow] = f2bf(accU[db][r]);
            }
        __syncthreads();
        short* ub = Ubuf + ((size_t)blockIdx.x * 2 + m) * 4096;
        #pragma unroll
        for (int it = 0; it < 2; ++it) {
            const int i = tid + it * 256;           // 0..511
            const int e = i >> 3, seg = (i & 7) * 8;
            *(bf16x8*)(ub + e * 64 + seg) = *(const bf16x8*)&sK[e * 72 + seg];
        }
    }
}

// ---------------------------------------------------------------------------
// Kernel C: full output with in-register prefix scan.
// O = P@V (intra) + (qs.Q) @ [S0;S1] (inter) -> Obf.
// Prefix state computed locally: s = R_{c'} s + U_{c'} over c' < c (fp32).
// ---------------------------------------------------------------------------
__global__ __launch_bounds__(256) void chunk_o(
    const short* __restrict__ Qbf, const short* __restrict__ Kbf,
    const short* __restrict__ Vbf, const float* __restrict__ Graw,
    const float* __restrict__ bg, const float* __restrict__ logit_alphas,
    const short* __restrict__ Ubuf, const float* __restrict__ SRb,
    short* __restrict__ Obf)
{
    __shared__ __align__(16) short sQ [64 * 72];
    __shared__ __align__(16) short sK [64 * 72];
    __shared__ __align__(16) short sVT[64 * 72];
    __shared__ __align__(16) short sP [64 * 72];
    __shared__ __align__(16) short sST[2][64 * 72];   // prefix state [m][e][d]
    __shared__ float sScal[64][6];
    __shared__ float sLc[2][64];
    __shared__ float sQs[2][64];

    const int tid  = threadIdx.x;
    const int wave = tid >> 6, lane = tid & 63;
    const int lrow = lane & 15, lgrp = lane >> 4;
    const int c  = blockIdx.x & 15;
    const int bh = blockIdx.x >> 4;
    const int h = bh & 7, b = bh >> 3;
    const int row0 = wave * 16;
    const int s0 = c * 64;

    if (tid < 64) {
        const int bs = b * S_ + s0 + tid;
        const float4 gv = *(const float4*)(Graw + (size_t)bs * 32 + h * 4);
        const float g0 = gv.x + bg[h * 4 + 0];
        const float g1 = gv.y + bg[h * 4 + 1];
        const float g2 = gv.z + bg[h * 4 + 2];
        const float g3 = gv.w + bg[h * 4 + 3];
        const float gf  = 1.f / (1.f + expf(-g0));
        const float gu  = 1.f / (1.f + expf(-g1));
        const float wm0 = 1.f / (1.f + expf(-(g2 - g3)));
        const float a0 = 1.f / (1.f + expf(-logit_alphas[h * 2 + 0]));
        const float a1 = 1.f / (1.f + expf(-logit_alphas[h * 2 + 1]));
        sScal[tid][0] = a0 * gf; sScal[tid][1] = a1 * gf;
        sScal[tid][2] = wm0 * gu; sScal[tid][3] = (1.f - wm0) * gu;
        sScal[tid][4] = wm0; sScal[tid][5] = 1.f - wm0;
    }

    // ---- in-register exclusive prefix over previous chunks ----
    // thread t owns elems i = g*2048 + t*8 + j  (g=0..3, j=0..7);
    // m = i>>12, e = (i>>6)&63, d = i&63.  fp32 accumulation, same order
    // as the old state_prefix kernel.
    float sp[4][8];
    #pragma unroll
    for (int g = 0; g < 4; ++g)
        #pragma unroll
        for (int j = 0; j < 8; ++j) sp[g][j] = 0.f;
    for (int cp = 0; cp < c; ++cp) {
        const int bhc = bh * 16 + cp;
        const float R0 = SRb[bhc * 2 + 0];
        const float R1 = SRb[bhc * 2 + 1];
        const short* ub = Ubuf + (size_t)bhc * 8192;
        #pragma unroll
        for (int g = 0; g < 4; ++g) {
            bf16x8 u = *(const bf16x8*)(ub + g * 2048 + tid * 8);
            const float R = (g < 2) ? R0 : R1;
            #pragma unroll
            for (int j = 0; j < 8; ++j) sp[g][j] = fmaf(R, sp[g][j], bf2f(u[j]));
        }
    }
    #pragma unroll
    for (int g = 0; g < 4; ++g) {
        const int i = g * 2048 + tid * 8;
        const int m = i >> 12, e = (i >> 6) & 63, d = i & 63;
        bf16x8 o;
        #pragma unroll
        for (int j = 0; j < 8; ++j) o[j] = f2bf(sp[g][j]);
        *(bf16x8*)&sST[m][e * 72 + d] = o;
    }

    // load Q,K (pre-roped) + V (transposed)
    #pragma unroll
    for (int it = 0; it < 2; ++it) {
        const int i = tid + it * 256;
        const int r = i >> 3, c8 = (i & 7) * 8;
        const size_t g = ((size_t)(b * S_ + s0 + r)) * 512 + h * 64 + c8;
        *(bf16x8*)&sQ[r * 72 + c8] = *(const bf16x8*)(Qbf + g);
        *(bf16x8*)&sK[r * 72 + c8] = *(const bf16x8*)(Kbf + g);
        bf16x8 v8 = *(const bf16x8*)(Vbf + g);
        #pragma unroll
        for (int j = 0; j < 8; ++j) sVT[(c8 + j) * 72 + r] = v8[j];
    }
    __syncthreads();

    if (wave < 2) {
        const int m = wave;
        float pre = log2f(sScal[lane][m]);
        #pragma unroll
        for (int off = 1; off < 64; off <<= 1) {
            const float u = __shfl_up(pre, off);
            if (lane >= off) pre += u;
        }
        sLc[m][lane] = pre;
        sQs[m][lane] = sScal[lane][4 + m] * exp2f(pre);
    }
    __syncthreads();

    // QK^T
    f32x4 accS[4], accO[4];
    #pragma unroll
    for (int cb = 0; cb < 4; ++cb) { accS[cb] = (f32x4)0.f; accO[cb] = (f32x4)0.f; }
    #pragma unroll
    for (int kk = 0; kk < 2; ++kk) {
        const int kb = kk * 32 + lgrp * 8;
        bf16x8 a = *(const bf16x8*)&sQ[(row0 + lrow) * 72 + kb];
        #pragma unroll
        for (int cb = 0; cb < 4; ++cb) {
            bf16x8 bb = *(const bf16x8*)&sK[(cb * 16 + lrow) * 72 + kb];
            accS[cb] = MFMA16(a, bb, accS[cb]);
        }
    }

    // O_inter = (qs-scaled Q) @ [S0;S1]
    #pragma unroll
    for (int kk = 0; kk < 4; ++kk) {
        const int k0 = kk * 32 + lgrp * 8;
        const int m = k0 >> 6, d0 = k0 & 63;
        const float qs = sQs[m][row0 + lrow];
        bf16x8 qr = *(const bf16x8*)&sQ[(row0 + lrow) * 72 + d0];
        bf16x8 a;
        #pragma unroll
        for (int j = 0; j < 8; ++j) a[j] = f2bf(bf2f(qr[j]) * qs);
        #pragma unroll
        for (int cb = 0; cb < 4; ++cb) {
            bf16x8 bb = *(const bf16x8*)&sST[m][(cb * 16 + lrow) * 72 + d0];
            accO[cb] = MFMA16(a, bb, accO[cb]);
        }
    }

    // P build (log-space decay ratios, causal mask, gates)
    #pragma unroll
    for (int r = 0; r < 4; ++r) {
        const int t = row0 + lgrp * 4 + r;
        const float wm0 = sScal[t][4], wm1 = sScal[t][5];
        const float lc0t = sLc[0][t],  lc1t = sLc[1][t];
        #pragma unroll
        for (int cb = 0; cb < 4; ++cb) {
            const int tau = cb * 16 + lrow;
            float p = 0.f;
            if (tau <= t) {
                const float c0 = wm0 * sScal[tau][2] * exp2f(lc0t - sLc[0][tau]);
                const float c1 = wm1 * sScal[tau][3] * exp2f(lc1t - sLc[1][tau]);
                p = accS[cb][r] * (c0 + c1);
            }
            sP[t * 72 + tau] = f2bf(p);
        }
    }

    // O_intra = P @ V (wave-local sP rows)
    #pragma unroll
    for (int kk = 0; kk < 2; ++kk) {
        const int kb = kk * 32 + lgrp * 8;
        bf16x8 a = *(const bf16x8*)&sP[(row0 + lrow) * 72 + kb];
        #pragma unroll
        for (int cb = 0; cb < 4; ++cb) {
            bf16x8 bb = *(const bf16x8*)&sVT[(cb * 16 + lrow) * 72 + kb];
            accO[cb] = MFMA16(a, bb, accO[cb]);
        }
    }

    // stage O (wave-local rows of sP) then coalesced bf16x8 writes
    #pragma unroll
    for (int cb = 0; cb < 4; ++cb)
        #pragma unroll
        for (int r = 0; r < 4; ++r) {
            const int t = row0 + lgrp * 4 + r;
            sP[t * 72 + cb * 16 + lrow] = f2bf(accO[cb][r]);
        }
    __syncthreads();
    #pragma unroll
    for (int it = 0; it < 2; ++it) {
        const int i = tid + it * 256;               // 0..511
        const int t = i >> 3, seg = (i & 7) * 8;
        *(bf16x8*)(Obf + ((size_t)(b * S_ + s0 + t)) * 512 + h * 64 + seg) =
            *(const bf16x8*)&sP[t * 72 + seg];
    }
}

// ---------------------------------------------------------------------------
// Kernel 4: MFMA output GEMM, 128x64 tile, grid 256 (full chip), dbuf DMA.
// Ybf = Obf @ Wo^T + bo + x  (bf16 output, staged coalesced writes).
// ---------------------------------------------------------------------------
__global__ __launch_bounds__(256) void mfma_out(
    const short* __restrict__ Abf, const short* __restrict__ Wobf,
    const float* __restrict__ bo, const float* __restrict__ xres,
    short* __restrict__ Ybf)
{
    __shared__ __align__(16) short lds[24576];   // 2 bufs x (A 8192 + B 4096)

    const int p = blockIdx.x;              // 0..255
    const int xcd = p & 7, slot = p >> 3;  // 32 slots = 4 m-panels x 8 n
    const int by = xcd + 8 * (slot >> 3);  // 0..31
    const int bx = slot & 7;               // 0..7
    const int n0 = bx * 64, m0 = by * 128;

    const int tid = threadIdx.x;
    const int lane = tid & 63, wave = tid >> 6;
    const int lrow = lane & 15, lgrp = lane >> 4;
    const int wr = wave >> 1, wc = wave & 1;
    const int srl = lane >> 3;
    const int scs = (lane & 7) * 8;

    f32x4 acc[4][2];
    #pragma unroll
    for (int i = 0; i < 4; ++i)
        #pragma unroll
        for (int j = 0; j < 2; ++j) acc[i][j] = (f32x4)0.f;

    #define OUT_STAGE(buf, kt)  {                                             \
        short* dA = lds + (buf) * 12288;                                      \
        short* dB = dA + 8192;                                                \
        _Pragma("unroll")                                                     \
        for (int i = 0; i < 4; ++i) {                                         \
            const int chunk = i * 4 + wave;                                   \
            const int r = chunk * 8 + srl;                                    \
            GLOAD16(Abf + (size_t)(m0 + r) * 512 + (kt) + scs, dA + chunk * 512); \
        }                                                                     \
        _Pragma("unroll")                                                     \
        for (int i = 0; i < 2; ++i) {                                         \
            const int chunk = i * 4 + wave;                                   \
            const int r = chunk * 8 + srl;                                    \
            GLOAD16(Wobf + (size_t)(n0 + r) * 512 + (kt) + scs, dB + chunk * 512); \
        } }

    OUT_STAGE(0, 0);
    __syncthreads();
    int cur = 0;
    for (int step = 0; step < 8; ++step) {
        if (step < 7) OUT_STAGE(cur ^ 1, (step + 1) * 64);
        const short* sA = lds + cur * 12288;
        const short* sB = sA + 8192;
        #pragma unroll
        for (int kk = 0; kk < 2; ++kk) {
            const int kb = kk * 32 + lgrp * 8;
            bf16x8 af[4], bfr[2];
            #pragma unroll
            for (int mi = 0; mi < 4; ++mi)
                af[mi] = *(const bf16x8*)&sA[(wr * 64 + mi * 16 + lrow) * 64 + kb];
            #pragma unroll
            for (int ni = 0; ni < 2; ++ni)
                bfr[ni] = *(const bf16x8*)&sB[(wc * 32 + ni * 16 + lrow) * 64 + kb];
            #pragma unroll
            for (int mi = 0; mi < 4; ++mi)
                #pragma unroll
                for (int ni = 0; ni < 2; ++ni)
                    acc[mi][ni] = MFMA16(af[mi], bfr[ni], acc[mi][ni]);
        }
        __syncthreads();
        cur ^= 1;
    }
    #undef OUT_STAGE

    // stage bf16 tile (128 x 64, stride 80 shorts = 160B, 16B-aligned)
    short* stg = lds;
    #pragma unroll
    for (int mi = 0; mi < 4; ++mi)
        #pragma unroll
        for (int ni = 0; ni < 2; ++ni)
            #pragma unroll
            for (int j = 0; j < 4; ++j) {
                const int rl = wr * 64 + mi * 16 + lgrp * 4 + j;
                const int cl = wc * 32 + ni * 16 + lrow;
                stg[rl * 80 + cl] = f2bf(acc[mi][ni][j]);
            }
    __syncthreads();
    #pragma unroll
    for (int it = 0; it < 4; ++it) {
        const int u = tid + it * 256;              // 0..1023
        const int row = u >> 3, seg = (u & 7) * 8;
        const size_t gbase = (size_t)(m0 + row) * 512 + n0 + seg;
        bf16x8 a = *(const bf16x8*)&stg[row * 80 + seg];
        float4 x0 = *(const float4*)(xres + gbase);
        float4 x1 = *(const float4*)(xres + gbase + 4);
        float4 b0 = *(const float4*)(bo + n0 + seg);
        float4 b1 = *(const float4*)(bo + n0 + seg + 4);
        bf16x8 y;
        y[0] = f2bf(bf2f(a[0]) + b0.x + x0.x);
        y[1] = f2bf(bf2f(a[1]) + b0.y + x0.y);
        y[2] = f2bf(bf2f(a[2]) + b0.z + x0.z);
        y[3] = f2bf(bf2f(a[3]) + b0.w + x0.w);
        y[4] = f2bf(bf2f(a[4]) + b1.x + x1.x);
        y[5] = f2bf(bf2f(a[5]) + b1.y + x1.y);
        y[6] = f2bf(bf2f(a[6]) + b1.z + x1.z);
        y[7] = f2bf(bf2f(a[7]) + b1.w + x1.w);
        *(bf16x8*)(Ybf + gbase) = y;
    }
}

// ---------------------------------------------------------------------------
// Kernel 5: LayerNorm over D=512 (bf16 input, fp32 output).
// ---------------------------------------------------------------------------
__global__ __launch_bounds__(256) void ln_kernel(
    const short* __restrict__ Ybf, const float* __restrict__ ln_w,
    const float* __restrict__ ln_b, float* __restrict__ out)
{
    const int wave = threadIdx.x >> 6;
    const int lane = threadIdx.x & 63;
    const int row = blockIdx.x * 4 + wave;   // 0..4095

    bf16x8 v8 = *(const bf16x8*)(Ybf + (size_t)row * 512 + lane * 8);
    float v[8];
    #pragma unroll
    for (int j = 0; j < 8; ++j) v[j] = bf2f(v8[j]);

    float s = 0.f, sq = 0.f;
    #pragma unroll
    for (int j = 0; j < 8; ++j) { s += v[j]; sq += v[j] * v[j]; }
    #pragma unroll
    for (int off = 32; off; off >>= 1) {
        s  += __shfl_xor(s,  off);
        sq += __shfl_xor(sq, off);
    }
    const float mu  = s * (1.f / 512.f);
    const float var = sq * (1.f / 512.f) - mu * mu;
    const float inv = rsqrtf(var + EPS_);

    float4 w0 = *(const float4*)(ln_w + lane * 8);
    float4 w1 = *(const float4*)(ln_w + lane * 8 + 4);
    float4 b0 = *(const float4*)(ln_b + lane * 8);
    float4 b1 = *(const float4*)(ln_b + lane * 8 + 4);
    float4 o0, o1;
    o0.x = (v[0] - mu) * inv * w0.x + b0.x;
    o0.y = (v[1] - mu) * inv * w0.y + b0.y;
    o0.z = (v[2] - mu) * inv * w0.z + b0.z;
    o0.w = (v[3] - mu) * inv * w0.w + b0.w;
    o1.x = (v[4] - mu) * inv * w1.x + b1.x;
    o1.y = (v[5] - mu) * inv * w1.y + b1.y;
    o1.z = (v[6] - mu) * inv * w1.z + b1.z;
    o1.w = (v[7] - mu) * inv * w1.w + b1.w;
    *(float4*)(out + (size_t)row * 512 + lane * 8)     = o0;
    *(float4*)(out + (size_t)row * 512 + lane * 8 + 4) = o1;
}

// ---------------------------------------------------------------------------
extern "C" void kernel_launch(void* const* d_in, const int* in_sizes, int n_in,
                              void* d_out, int out_size, void* d_ws, size_t ws_size,
                              hipStream_t stream)
{
    const float* x   = (const float*)d_in[0];
    const float* Wq  = (const float*)d_in[1];
    const float* Wk  = (const float*)d_in[2];
    const float* Wv  = (const float*)d_in[3];
    const float* Wo  = (const float*)d_in[4];
    const float* bo  = (const float*)d_in[5];
    const float* Wg  = (const float*)d_in[6];
    const float* bg  = (const float*)d_in[7];
    const float* la  = (const float*)d_in[8];
    const float* lnw = (const float*)d_in[9];
    const float* lnb = (const float*)d_in[10];

    const size_t NQ = (size_t)B_ * S_ * D_;          // 2,097,152
    float* Graw = (float*)d_ws;                      // 131072 f32
    float* ROPE = Graw + 131072;                     // 65536 f32 (float2 x 32768)
    float* SRb  = ROPE + 65536;                      // 1024 f32
    short* xbf  = (short*)(SRb + 1024);              // 2,097,152
    short* Wcat = xbf + NQ;                          // 851,968
    short* Wobf = Wcat + (size_t)1664 * 512;         // 262,144
    short* Qbf  = Wobf + (size_t)512 * 512;          // 2,097,152
    short* Kbf  = Qbf + NQ;
    short* Vbf  = Kbf + NQ;
    short* Obf  = Vbf + NQ;
    short* Ybf  = Obf + NQ;                          // 2,097,152 (bf16 Y)
    short* Ubuf = Ybf + NQ;                          // 512*2*4096 = 4,194,304

    // 0) dtype conversion / weight packing / rope table
    convert_inputs<<<1696, 256, 0, stream>>>(x, Wq, Wk, Wv, Wg, Wo, xbf, Wcat, Wobf,
                                             (float2*)ROPE);
    // 1) projections (MFMA, dbuf global_load_lds, RoPE fused into epilogue)
    mfma_proj<<<416, 256, 0, stream>>>(xbf, Wcat, (const float2*)ROPE,
                                       Qbf, Kbf, Vbf, Graw);
    // 2) per-chunk state deltas
    chunk_delta<<<512, 256, 0, stream>>>(Kbf, Vbf, Graw, bg, la, Ubuf, SRb);
    // 3) full output (prefix + intra + inter fused)
    chunk_o<<<512, 256, 0, stream>>>(Qbf, Kbf, Vbf, Graw, bg, la, Ubuf, SRb, Obf);
    // 4) output projection + residual (MFMA, bf16 Y, grid 256)
    mfma_out<<<256, 256, 0, stream>>>(Obf, Wobf, bo, x, Ybf);
    // 5) layernorm
    ln_kernel<<<1024, 256, 0, stream>>>(Ybf, lnw, lnb, (float*)d_out);
}